// Round 5
// baseline (993.595 us; speedup 1.0000x reference)
//
#include <hip/hip_runtime.h>

#define DEV static __device__ __forceinline__

// ---------------------------------------------------------------------------
// Static device workspace
// ---------------------------------------------------------------------------
__device__ float    g_stats[2576];     // 5 layers x 512 (sum, sumsq, scale, shift)
__device__ unsigned g_cnt[16];
__device__ float    g_y1[2097152];     // (2,32,32^3)
__device__ float    g_m1[65536];       // (2,32^3)
__device__ float    g_y2[524288];      // (2,64,16^3)   split-K accum
__device__ float    g_m2[8192];        // (2,16^3)
__device__ float    g_y3[131072];      // (2,128,8^3)   split-K accum
__device__ float    g_m3[1024];        // (2,8^3)
__device__ float    g_t1[1048576];     // (2,128,16^3)  split-K accum
__device__ float    g_mt1[8192];       // (2,16^3)
__device__ float    g_mt2[65536];      // (2,32^3)
__device__ float    g_t2[4194304];     // (2,64,32^3)

// ---------------------------------------------------------------------------
// zero: stats/cnt + all split-K accumulation buffers. grid 4096 x 256.
// ---------------------------------------------------------------------------
__global__ __launch_bounds__(256)
void zero_ws_kernel() {
    int idx = blockIdx.x * 256 + threadIdx.x;
    if (idx < 524288)  g_y2[idx] = 0.f;
    if (idx < 131072)  g_y3[idx] = 0.f;
    if (idx < 1048576) g_t1[idx] = 0.f;
    if (idx < 2576)    g_stats[idx] = 0.f;
    if (idx < 16)      g_cnt[idx] = 0u;
}

// ---------------------------------------------------------------------------
// mask dilation kernels
// ---------------------------------------------------------------------------
DEV void mask_down_body(const float* mprev, float* mout, unsigned* cnt,
                        int logDin, int logDo) {
    int Din = 1 << logDin, Do = 1 << logDo;
    int idx = blockIdx.x * 256 + threadIdx.x;
    int b = idx >> (3 * logDo), v = idx & ((1 << (3 * logDo)) - 1);
    int od = v >> (2 * logDo), rem = v & ((1 << (2 * logDo)) - 1);
    int oh = rem >> logDo, ow = rem & (Do - 1);
    const float* mp = mprev + ((size_t)b << (3 * logDin));
    float acc = 0.f;
    for (int kd = 0; kd < 4; kd++) {
        int id = 2 * od - 1 + kd;
        if ((unsigned)id >= (unsigned)Din) continue;
        for (int kh = 0; kh < 4; kh++) {
            int ih = 2 * oh - 1 + kh;
            if ((unsigned)ih >= (unsigned)Din) continue;
            const float* row = mp + ((size_t)id * Din + ih) * Din;
            for (int kw = 0; kw < 4; kw++) {
                int iw = 2 * ow - 1 + kw;
                if ((unsigned)iw < (unsigned)Din) acc += row[iw];
            }
        }
    }
    float mv = acc > 0.f ? 1.f : 0.f;
    mout[idx] = mv;
    if (mv > 0.f) atomicAdd(cnt, 1u);
}

DEV void mask_up_body(const float* mprev, float* mout, unsigned* cnt,
                      int logDin, int logDo) {
    int Din = 1 << logDin, Do = 1 << logDo;
    int idx = blockIdx.x * 256 + threadIdx.x;
    int b = idx >> (3 * logDo), v = idx & ((1 << (3 * logDo)) - 1);
    int od = v >> (2 * logDo), rem = v & ((1 << (2 * logDo)) - 1);
    int oh = rem >> logDo, ow = rem & (Do - 1);
    const float* mp = mprev + ((size_t)b << (3 * logDin));
    float acc = 0.f;
    for (int kd = 0; kd < 4; kd++) {
        int u = od + kd - 2; if (u < 0 || (u & 1)) continue;
        int id = u >> 1; if (id >= Din) continue;
        for (int kh = 0; kh < 4; kh++) {
            int uh = oh + kh - 2; if (uh < 0 || (uh & 1)) continue;
            int ih = uh >> 1; if (ih >= Din) continue;
            const float* row = mp + ((size_t)id * Din + ih) * Din;
            for (int kw = 0; kw < 4; kw++) {
                int uw = ow + kw - 2; if (uw < 0 || (uw & 1)) continue;
                int iw = uw >> 1; if (iw >= Din) continue;
                acc += row[iw];
            }
        }
    }
    float mv = acc > 0.f ? 1.f : 0.f;
    mout[idx] = mv;
    if (mv > 0.f) atomicAdd(cnt, 1u);
}

__global__ __launch_bounds__(256)
void mask1_kernel(const float* __restrict__ mask) {
    int idx = blockIdx.x * 256 + threadIdx.x;      // 2*32^3
    int b = idx >> 15, v = idx & 0x7FFF;
    int od = v >> 10, rem = v & 1023;
    int oh = rem >> 5, ow = rem & 31;
    const float* mp = mask + ((size_t)b << 18);
    float acc = 0.f;
    for (int kd = 0; kd < 4; kd++) {
        int id = 2 * od - 1 + kd;
        if ((unsigned)id >= 64u) continue;
        for (int kh = 0; kh < 4; kh++) {
            int ih = 2 * oh - 1 + kh;
            if ((unsigned)ih >= 64u) continue;
            const float* row = mp + ((size_t)id * 64 + ih) * 64;
            for (int kw = 0; kw < 4; kw++) {
                int iw = 2 * ow - 1 + kw;
                if ((unsigned)iw < 64u && row[iw] > 0.5f) acc += 1.f;
            }
        }
    }
    float mv = acc > 0.f ? 1.f : 0.f;
    g_m1[idx] = mv;
    if (mv > 0.f) atomicAdd(&g_cnt[0], 1u);
}

__global__ __launch_bounds__(256) void mask2_kernel() { mask_down_body(g_m1, g_m2, &g_cnt[1], 5, 4); }
__global__ __launch_bounds__(256) void mask3_kernel() { mask_down_body(g_m2, g_m3, &g_cnt[2], 4, 3); }
__global__ __launch_bounds__(256) void mask4_kernel() { mask_up_body(g_m3, g_mt1, &g_cnt[3], 3, 4); }
__global__ __launch_bounds__(256) void mask5_kernel() { mask_up_body(g_mt1, g_mt2, &g_cnt[4], 4, 5); }

// ---------------------------------------------------------------------------
// implicit-GEMM conv body.
// MODE: 0 = down conv (k4 s2 p1), 1 = transpose conv (parity = blockIdx.z&7),
//       2 = final 1x1x1 dense, 3 = down conv fused with mask*feat prep.
// SPLITK>1: K split across blockIdx.z (MODE1: z>>3); raw partials atomicAdd
// into y; bias/mask/leaky/stats deferred to post_kernel.
// Staging index j = e*256+tid -> lane-consecutive LDS writes (conflict-free).
// ---------------------------------------------------------------------------
template<int MODE, int MT, int NT, int CIN, int COUT, int LOGDI, int LOGDO, int SPLITK>
DEV void gemm_body(const float* __restrict__ x, const float* __restrict__ rawm,
                   const float* __restrict__ w, const float* __restrict__ bias,
                   const float* __restrict__ m2, float* __restrict__ y,
                   float* __restrict__ stats) {
    constexpr int KT = 32;
    constexpr int K  = (MODE == 1) ? CIN * 8 : ((MODE == 2) ? CIN : CIN * 64);
    constexpr int KSEG = K / SPLITK;
    constexpr int MR = MT / 16, VR = NT / 16;
    constexpr int EA = KT * MT / 256, EB = KT * NT / 256;
    constexpr int LMT = (MT == 64) ? 6 : 5, LNT = (NT == 64) ? 6 : 5;
    constexpr int Din = 1 << LOGDI, Do = 1 << LOGDO;

    __shared__ float As[KT * MT];
    __shared__ float Bs[KT * NT];

    const int tid = threadIdx.x, tc = tid & 15, tv = tid >> 4;
    const int bx = blockIdx.x, by = blockIdx.y;
    int pd = 0, ph = 0, pw = 0, ks = 0;
    if constexpr (MODE == 1) {
        int z = blockIdx.z;
        pd = (z >> 2) & 1; ph = (z >> 1) & 1; pw = z & 1; ks = z >> 3;
    } else if constexpr (SPLITK > 1) {
        ks = blockIdx.z;
    }

    float acc[MR][VR];
#pragma unroll
    for (int r = 0; r < MR; r++)
#pragma unroll
        for (int c = 0; c < VR; c++) acc[r][c] = 0.f;

    const int kbeg = ks * KSEG, kend = kbeg + KSEG;
    for (int kt = kbeg; kt < kend; kt += KT) {
        __syncthreads();
        // ---- stage A: weights [KT][MT], lane-consecutive writes
#pragma unroll
        for (int e = 0; e < EA; e++) {
            int j = e * 256 + tid;
            int kk = j >> LMT, m = j & (MT - 1);
            int kg = kt + kk;
            int co = by * MT + m;
            float val;
            if constexpr (MODE == 1) {
                int ci = kg >> 3, t = kg & 7;
                int td = (t >> 2) & 1, th = (t >> 1) & 1, tw = t & 1;
                int kd = 3 - pd - 2 * td, kh = 3 - ph - 2 * th, kw = 3 - pw - 2 * tw;
                val = w[((size_t)co * CIN + ci) * 64 + kd * 16 + kh * 4 + kw];
            } else if constexpr (MODE == 2) {
                val = w[co * CIN + kg];
            } else {
                val = w[(size_t)co * (CIN * 64) + kg];
            }
            As[j] = val;
        }
        // ---- stage B: im2col gather [KT][NT], lane-consecutive writes
#pragma unroll
        for (int e = 0; e < EB; e++) {
            int j = e * 256 + tid;
            int kk = j >> LNT, n = j & (NT - 1);
            int kg = kt + kk;
            int vg = bx * NT + n;
            float val = 0.f;
            if constexpr (MODE == 1) {
                int b = vg >> (3 * LOGDI), v = vg & ((1 << (3 * LOGDI)) - 1);
                int odp = v >> (2 * LOGDI), ohp = (v >> LOGDI) & (Din - 1), owp = v & (Din - 1);
                int ci = kg >> 3, t = kg & 7;
                int id = odp + pd + ((t >> 2) & 1) - 1;
                int ih = ohp + ph + ((t >> 1) & 1) - 1;
                int iw = owp + pw + (t & 1) - 1;
                if ((unsigned)id < (unsigned)Din && (unsigned)ih < (unsigned)Din &&
                    (unsigned)iw < (unsigned)Din)
                    val = x[(((size_t)(b * CIN + ci)) << (3 * LOGDI)) +
                            (id << (2 * LOGDI)) + (ih << LOGDI) + iw];
            } else if constexpr (MODE == 2) {
                int b = vg >> 15, v = vg & 32767;
                val = x[(((size_t)(b * CIN + kg)) << 15) + v];
            } else {
                int b = vg >> (3 * LOGDO), v = vg & ((1 << (3 * LOGDO)) - 1);
                int od = v >> (2 * LOGDO), oh = (v >> LOGDO) & (Do - 1), ow = v & (Do - 1);
                int ci = kg >> 6;
                int id = 2 * od - 1 + ((kg >> 4) & 3);
                int ih = 2 * oh - 1 + ((kg >> 2) & 3);
                int iw = 2 * ow - 1 + (kg & 3);
                if ((unsigned)id < (unsigned)Din && (unsigned)ih < (unsigned)Din &&
                    (unsigned)iw < (unsigned)Din) {
                    int off = (id << (2 * LOGDI)) + (ih << LOGDI) + iw;
                    if constexpr (MODE == 3) {
                        if (rawm[((size_t)b << (3 * LOGDI)) + off] > 0.5f)
                            val = x[(((size_t)(b * CIN + ci)) << (3 * LOGDI)) + off];
                    } else {
                        val = x[(((size_t)(b * CIN + ci)) << (3 * LOGDI)) + off];
                    }
                }
            }
            Bs[j] = val;
        }
        __syncthreads();
        // ---- compute
#pragma unroll
        for (int kk = 0; kk < KT; kk++) {
            float a[MR], bb[VR];
            if constexpr (MR == 4) {
                float4 t4 = *(const float4*)&As[kk * MT + tc * 4];
                a[0] = t4.x; a[1] = t4.y; a[2] = t4.z; a[3] = t4.w;
            } else {
                float2 t2 = *(const float2*)&As[kk * MT + tc * 2];
                a[0] = t2.x; a[1] = t2.y;
            }
            if constexpr (VR == 4) {
                float4 t4 = *(const float4*)&Bs[kk * NT + tv * 4];
                bb[0] = t4.x; bb[1] = t4.y; bb[2] = t4.z; bb[3] = t4.w;
            } else {
                float2 t2 = *(const float2*)&Bs[kk * NT + tv * 2];
                bb[0] = t2.x; bb[1] = t2.y;
            }
#pragma unroll
            for (int r = 0; r < MR; r++)
#pragma unroll
                for (int c = 0; c < VR; c++) acc[r][c] = fmaf(a[r], bb[c], acc[r][c]);
        }
    }

    // ---- epilogue
    if constexpr (MODE == 2) {
#pragma unroll
        for (int r = 0; r < MR; r++) {
            int co = by * MT + tc * MR + r;
            float bv = bias[co];
#pragma unroll
            for (int c = 0; c < VR; c++) {
                int vg = bx * NT + tv * VR + c;
                int b = vg >> 15, v = vg & 32767;
                y[(((size_t)(b * COUT + co)) << 15) + v] = acc[r][c] + bv;
            }
        }
    } else if constexpr (SPLITK > 1) {
        // raw partial sums; bias/mask/leaky/stats in post_kernel
#pragma unroll
        for (int r = 0; r < MR; r++) {
            int co = by * MT + tc * MR + r;
#pragma unroll
            for (int c = 0; c < VR; c++) {
                int vg = bx * NT + tv * VR + c;
                int b, off;
                if constexpr (MODE == 1) {
                    b = vg >> (3 * LOGDI); int v = vg & ((1 << (3 * LOGDI)) - 1);
                    int odp = v >> (2 * LOGDI), ohp = (v >> LOGDI) & (Din - 1), owp = v & (Din - 1);
                    int od = 2 * odp + pd, oh = 2 * ohp + ph, ow = 2 * owp + pw;
                    off = (od << (2 * LOGDO)) + (oh << LOGDO) + ow;
                } else {
                    b = vg >> (3 * LOGDO); off = vg & ((1 << (3 * LOGDO)) - 1);
                }
                atomicAdd(&y[(((size_t)(b * COUT + co)) << (3 * LOGDO)) + off], acc[r][c]);
            }
        }
    } else {
        float s[MR], s2[MR];
#pragma unroll
        for (int r = 0; r < MR; r++) { s[r] = 0.f; s2[r] = 0.f; }
#pragma unroll
        for (int r = 0; r < MR; r++) {
            int co = by * MT + tc * MR + r;
            float bv = bias[co];
#pragma unroll
            for (int c = 0; c < VR; c++) {
                int vg = bx * NT + tv * VR + c;
                int b, off;
                if constexpr (MODE == 1) {
                    b = vg >> (3 * LOGDI); int v = vg & ((1 << (3 * LOGDI)) - 1);
                    int odp = v >> (2 * LOGDI), ohp = (v >> LOGDI) & (Din - 1), owp = v & (Din - 1);
                    int od = 2 * odp + pd, oh = 2 * ohp + ph, ow = 2 * owp + pw;
                    off = (od << (2 * LOGDO)) + (oh << LOGDO) + ow;
                } else {
                    b = vg >> (3 * LOGDO); off = vg & ((1 << (3 * LOGDO)) - 1);
                }
                float mv = m2[((size_t)b << (3 * LOGDO)) + off];
                float yv = (acc[r][c] + bv) * mv;
                yv = yv >= 0.f ? yv : 0.01f * yv;
                y[(((size_t)(b * COUT + co)) << (3 * LOGDO)) + off] = yv;
                s[r] += yv; s2[r] += yv * yv;
            }
        }
        __syncthreads();
#pragma unroll
        for (int r = 0; r < MR; r++) {
            As[tv * MT + tc * MR + r] = s[r];
            Bs[tv * MT + tc * MR + r] = s2[r];
        }
        __syncthreads();
        if (tid < MT) {
            float S = 0.f, S2 = 0.f;
#pragma unroll
            for (int t = 0; t < 16; t++) { S += As[t * MT + tid]; S2 += Bs[t * MT + tid]; }
            int co = by * MT + tid;
            atomicAdd(&stats[co], S);
            atomicAdd(&stats[128 + co], S2);
        }
    }
}

// ---------------------------------------------------------------------------
// post pass for split-K layers: bias + mask + LeakyReLU + stats.
// One block spans 256 consecutive voxels of a single (b,co).
// ---------------------------------------------------------------------------
template<int COUT, int LOGDO>
DEV void post_body(const float* __restrict__ bias, const float* __restrict__ m2,
                   float* __restrict__ y, float* __restrict__ stats) {
    int idx = blockIdx.x * 256 + threadIdx.x;
    constexpr int Dvox = 1 << (3 * LOGDO);
    int v = idx & (Dvox - 1);
    int co = (idx >> (3 * LOGDO)) & (COUT - 1);
    int b = idx >> (3 * LOGDO + (COUT == 128 ? 7 : (COUT == 64 ? 6 : 5)));
    float mv = m2[((size_t)b << (3 * LOGDO)) + v];
    float yv = (y[idx] + bias[co]) * mv;
    yv = yv >= 0.f ? yv : 0.01f * yv;
    y[idx] = yv;
    float s = yv, s2 = yv * yv;
#pragma unroll
    for (int off = 32; off; off >>= 1) {
        s += __shfl_down(s, off, 64);
        s2 += __shfl_down(s2, off, 64);
    }
    __shared__ float red[8];
    int lane = threadIdx.x & 63, wv = threadIdx.x >> 6;
    if (!lane) { red[wv] = s; red[4 + wv] = s2; }
    __syncthreads();
    if (!threadIdx.x) {
        atomicAdd(&stats[co],       red[0] + red[1] + red[2] + red[3]);
        atomicAdd(&stats[128 + co], red[4] + red[5] + red[6] + red[7]);
    }
}

__global__ __launch_bounds__(256) void post2_kernel(const float* b) { post_body<64, 4>(b, g_m2, g_y2, g_stats + 512); }
__global__ __launch_bounds__(256) void post3_kernel(const float* b) { post_body<128, 3>(b, g_m3, g_y3, g_stats + 1024); }
__global__ __launch_bounds__(256) void post4_kernel(const float* b) { post_body<128, 4>(b, g_mt1, g_t1, g_stats + 1536); }

// ---------------------------------------------------------------------------
// conv wrappers
// ---------------------------------------------------------------------------
__global__ __launch_bounds__(256)
void conv1_kernel(const float* feat, const float* mask, const float* w, const float* b)
{ gemm_body<3, 32, 64, 4, 32, 6, 5, 1>(feat, mask, w, b, g_m1, g_y1, g_stats); }

__global__ __launch_bounds__(256)
void conv2_kernel(const float* w, const float* b)
{ gemm_body<0, 32, 64, 32, 64, 5, 4, 2>(g_y1, nullptr, w, b, g_m2, g_y2, g_stats + 512); }

__global__ __launch_bounds__(256)
void conv3_kernel(const float* w, const float* b)
{ gemm_body<0, 64, 32, 64, 128, 4, 3, 8>(g_y2, nullptr, w, b, g_m3, g_y3, g_stats + 1024); }

__global__ __launch_bounds__(256)
void conv4_kernel(const float* w, const float* b)
{ gemm_body<1, 64, 64, 128, 128, 3, 4, 4>(g_y3, nullptr, w, b, g_mt1, g_t1, g_stats + 1536); }

__global__ __launch_bounds__(256)
void conv5_kernel(const float* w, const float* b)
{ gemm_body<1, 64, 64, 128, 64, 4, 5, 1>(g_t1, nullptr, w, b, g_mt2, g_t2, g_stats + 2048); }

__global__ __launch_bounds__(256)
void final_kernel(const float* fw, const float* fb, float* out)
{ gemm_body<2, 32, 64, 64, 32, 5, 5, 1>(g_t2, nullptr, fw, fb, nullptr, out, nullptr); }

// ---------------------------------------------------------------------------
// stats finalize + BN apply
// ---------------------------------------------------------------------------
DEV void finalize_body(float* stats, const unsigned* cnt,
                       const float* g, const float* be, int C) {
    int c = threadIdx.x;
    if (c >= C) return;
    unsigned cu = *cnt;
    float n = (float)(cu < 1u ? 1u : cu);
    float mean = stats[c] / n;
    float var = fmaxf(stats[128 + c] / n - mean * mean, 0.f);
    float rstd = rsqrtf(var + 1e-5f);
    float sc = g[c] * rstd;
    stats[256 + c] = sc;
    stats[384 + c] = be[c] - mean * sc;
}

__global__ void fin1_kernel(const float* g, const float* be) { finalize_body(g_stats + 0,    &g_cnt[0], g, be, 32); }
__global__ void fin2_kernel(const float* g, const float* be) { finalize_body(g_stats + 512,  &g_cnt[1], g, be, 64); }
__global__ void fin3_kernel(const float* g, const float* be) { finalize_body(g_stats + 1024, &g_cnt[2], g, be, 128); }
__global__ void fin4_kernel(const float* g, const float* be) { finalize_body(g_stats + 1536, &g_cnt[3], g, be, 128); }
__global__ void fin5_kernel(const float* g, const float* be) { finalize_body(g_stats + 2048, &g_cnt[4], g, be, 64); }

DEV void bn_body(float* y, const float* stats, const float* m2, int logC, int logDvox) {
    int idx = blockIdx.x * 256 + threadIdx.x;
    int v = idx & ((1 << logDvox) - 1);
    int c = (idx >> logDvox) & ((1 << logC) - 1);
    int b = idx >> (logDvox + logC);
    float mv = m2[((size_t)b << logDvox) + v];
    y[idx] = (y[idx] * stats[256 + c] + stats[384 + c]) * mv;
}

__global__ __launch_bounds__(256) void bn1_kernel() { bn_body(g_y1, g_stats + 0,    g_m1, 5, 15); }
__global__ __launch_bounds__(256) void bn2_kernel() { bn_body(g_y2, g_stats + 512,  g_m2, 6, 12); }
__global__ __launch_bounds__(256) void bn3_kernel() { bn_body(g_y3, g_stats + 1024, g_m3, 7, 9); }
__global__ __launch_bounds__(256) void bn4_kernel() { bn_body(g_t1, g_stats + 1536, g_mt1, 7, 12); }
__global__ __launch_bounds__(256) void bn5_kernel() { bn_body(g_t2, g_stats + 2048, g_mt2, 6, 15); }

// ---------------------------------------------------------------------------

extern "C" void kernel_launch(void* const* d_in, const int* in_sizes, int n_in,
                              void* d_out, int out_size, void* d_ws, size_t ws_size,
                              hipStream_t stream) {
    (void)in_sizes; (void)n_in; (void)out_size; (void)d_ws; (void)ws_size;
    const float* feat = (const float*)d_in[0];
    const float* mask = (const float*)d_in[1];
    const float* w1  = (const float*)d_in[2];
    const float* b1  = (const float*)d_in[3];
    const float* g1  = (const float*)d_in[4];
    const float* be1 = (const float*)d_in[5];
    const float* w2  = (const float*)d_in[6];
    const float* b2  = (const float*)d_in[7];
    const float* g2  = (const float*)d_in[8];
    const float* be2 = (const float*)d_in[9];
    const float* w3  = (const float*)d_in[10];
    const float* b3  = (const float*)d_in[11];
    const float* g3  = (const float*)d_in[12];
    const float* be3 = (const float*)d_in[13];
    const float* tw1 = (const float*)d_in[14];
    const float* tb1 = (const float*)d_in[15];
    const float* tg1 = (const float*)d_in[16];
    const float* tbe1= (const float*)d_in[17];
    const float* tw2 = (const float*)d_in[18];
    const float* tb2 = (const float*)d_in[19];
    const float* tg2 = (const float*)d_in[20];
    const float* tbe2= (const float*)d_in[21];
    const float* fw  = (const float*)d_in[22];
    const float* fb  = (const float*)d_in[23];

    zero_ws_kernel<<<4096, 256, 0, stream>>>();

    // block 1: 4->32, 64^3 -> 32^3   (N=65536, M=32, K=256)
    mask1_kernel<<<256, 256, 0, stream>>>(mask);
    conv1_kernel<<<dim3(1024, 1), 256, 0, stream>>>(feat, mask, w1, b1);
    fin1_kernel<<<1, 128, 0, stream>>>(g1, be1);
    bn1_kernel<<<8192, 256, 0, stream>>>();

    // block 2: 32->64, 32^3 -> 16^3  (N=8192, M=64, K=2048, split-K 2)
    mask2_kernel<<<32, 256, 0, stream>>>();
    conv2_kernel<<<dim3(128, 2, 2), 256, 0, stream>>>(w2, b2);
    post2_kernel<<<2048, 256, 0, stream>>>(b2);
    fin2_kernel<<<1, 128, 0, stream>>>(g2, be2);
    bn2_kernel<<<2048, 256, 0, stream>>>();

    // block 3: 64->128, 16^3 -> 8^3  (N=1024, M=128, K=4096, split-K 8)
    mask3_kernel<<<4, 256, 0, stream>>>();
    conv3_kernel<<<dim3(32, 2, 8), 256, 0, stream>>>(w3, b3);
    post3_kernel<<<512, 256, 0, stream>>>(b3);
    fin3_kernel<<<1, 128, 0, stream>>>(g3, be3);
    bn3_kernel<<<512, 256, 0, stream>>>();

    // up block 1: 128->128, 8^3 -> 16^3  (per-parity N=1024, K=1024, split-K 4)
    mask4_kernel<<<32, 256, 0, stream>>>();
    conv4_kernel<<<dim3(16, 2, 32), 256, 0, stream>>>(tw1, tb1);
    post4_kernel<<<4096, 256, 0, stream>>>(tb1);
    fin4_kernel<<<1, 128, 0, stream>>>(tg1, tbe1);
    bn4_kernel<<<4096, 256, 0, stream>>>();

    // up block 2: 128->64, 16^3 -> 32^3  (per-parity N=8192, K=1024)
    mask5_kernel<<<256, 256, 0, stream>>>();
    conv5_kernel<<<dim3(128, 1, 8), 256, 0, stream>>>(tw2, tb2);
    fin5_kernel<<<1, 128, 0, stream>>>(tg2, tbe2);
    bn5_kernel<<<16384, 256, 0, stream>>>();

    // final dense 1x1x1 conv 64->32 @ 32^3  (N=65536, M=32, K=64)
    final_kernel<<<dim3(1024, 1), 256, 0, stream>>>(fw, fb, (float*)d_out);
}

// Round 6
// 589.377 us; speedup vs baseline: 1.6858x; 1.6858x over previous
//
#include <hip/hip_runtime.h>
#include <hip/hip_bf16.h>

#define DEV static __device__ __forceinline__

typedef unsigned short ushort;
typedef __attribute__((ext_vector_type(8))) short short8;
typedef __attribute__((ext_vector_type(8))) ushort ushort8;
typedef __attribute__((ext_vector_type(4))) float accv;

DEV ushort f2bf(float f) {
    __hip_bfloat16 h = __float2bfloat16(f);   // RNE
    return reinterpret_cast<ushort&>(h);
}

// ---------------------------------------------------------------------------
// Static device workspace
// ---------------------------------------------------------------------------
__device__ float    g_stats[2576];     // 5 layers x 512 (sum, sumsq, scale, shift)
__device__ unsigned g_cnt[16];
__device__ float    g_y1[2097152];     // (2,32,32^3) fp32 conv1 out
__device__ ushort   g_y1b[2097152];    // bf16 after BN (conv2 input)
__device__ float    g_m1[65536];
__device__ float    g_y2[524288];      // split-K accum fp32
__device__ ushort   g_y2b[524288];     // bf16 after BN (conv3 input)
__device__ float    g_m2[8192];
__device__ float    g_y3[131072];      // split-K accum
__device__ ushort   g_y3b[131072];     // bf16 (conv4 input)
__device__ float    g_m3[1024];
__device__ float    g_t1[1048576];     // split-K accum
__device__ ushort   g_t1b[1048576];    // bf16 (conv5 input)
__device__ float    g_mt1[8192];
__device__ float    g_mt2[65536];
__device__ float    g_t2[4194304];     // conv5 raw out -> post5 -> bn5 (fp32)

// ---------------------------------------------------------------------------
__global__ __launch_bounds__(256)
void zero_ws_kernel() {
    int idx = blockIdx.x * 256 + threadIdx.x;
    if (idx < 524288)  g_y2[idx] = 0.f;
    if (idx < 131072)  g_y3[idx] = 0.f;
    if (idx < 1048576) g_t1[idx] = 0.f;
    if (idx < 2576)    g_stats[idx] = 0.f;
    if (idx < 16)      g_cnt[idx] = 0u;
}

// ---------------------------------------------------------------------------
// mask dilation kernels (unchanged, verified)
// ---------------------------------------------------------------------------
DEV void mask_down_body(const float* mprev, float* mout, unsigned* cnt,
                        int logDin, int logDo) {
    int Din = 1 << logDin, Do = 1 << logDo;
    int idx = blockIdx.x * 256 + threadIdx.x;
    int b = idx >> (3 * logDo), v = idx & ((1 << (3 * logDo)) - 1);
    int od = v >> (2 * logDo), rem = v & ((1 << (2 * logDo)) - 1);
    int oh = rem >> logDo, ow = rem & (Do - 1);
    const float* mp = mprev + ((size_t)b << (3 * logDin));
    float acc = 0.f;
    for (int kd = 0; kd < 4; kd++) {
        int id = 2 * od - 1 + kd;
        if ((unsigned)id >= (unsigned)Din) continue;
        for (int kh = 0; kh < 4; kh++) {
            int ih = 2 * oh - 1 + kh;
            if ((unsigned)ih >= (unsigned)Din) continue;
            const float* row = mp + ((size_t)id * Din + ih) * Din;
            for (int kw = 0; kw < 4; kw++) {
                int iw = 2 * ow - 1 + kw;
                if ((unsigned)iw < (unsigned)Din) acc += row[iw];
            }
        }
    }
    float mv = acc > 0.f ? 1.f : 0.f;
    mout[idx] = mv;
    if (mv > 0.f) atomicAdd(cnt, 1u);
}

DEV void mask_up_body(const float* mprev, float* mout, unsigned* cnt,
                      int logDin, int logDo) {
    int Din = 1 << logDin, Do = 1 << logDo;
    int idx = blockIdx.x * 256 + threadIdx.x;
    int b = idx >> (3 * logDo), v = idx & ((1 << (3 * logDo)) - 1);
    int od = v >> (2 * logDo), rem = v & ((1 << (2 * logDo)) - 1);
    int oh = rem >> logDo, ow = rem & (Do - 1);
    const float* mp = mprev + ((size_t)b << (3 * logDin));
    float acc = 0.f;
    for (int kd = 0; kd < 4; kd++) {
        int u = od + kd - 2; if (u < 0 || (u & 1)) continue;
        int id = u >> 1; if (id >= Din) continue;
        for (int kh = 0; kh < 4; kh++) {
            int uh = oh + kh - 2; if (uh < 0 || (uh & 1)) continue;
            int ih = uh >> 1; if (ih >= Din) continue;
            const float* row = mp + ((size_t)id * Din + ih) * Din;
            for (int kw = 0; kw < 4; kw++) {
                int uw = ow + kw - 2; if (uw < 0 || (uw & 1)) continue;
                int iw = uw >> 1; if (iw >= Din) continue;
                acc += row[iw];
            }
        }
    }
    float mv = acc > 0.f ? 1.f : 0.f;
    mout[idx] = mv;
    if (mv > 0.f) atomicAdd(cnt, 1u);
}

__global__ __launch_bounds__(256)
void mask1_kernel(const float* __restrict__ mask) {
    int idx = blockIdx.x * 256 + threadIdx.x;
    int b = idx >> 15, v = idx & 0x7FFF;
    int od = v >> 10, rem = v & 1023;
    int oh = rem >> 5, ow = rem & 31;
    const float* mp = mask + ((size_t)b << 18);
    float acc = 0.f;
    for (int kd = 0; kd < 4; kd++) {
        int id = 2 * od - 1 + kd;
        if ((unsigned)id >= 64u) continue;
        for (int kh = 0; kh < 4; kh++) {
            int ih = 2 * oh - 1 + kh;
            if ((unsigned)ih >= 64u) continue;
            const float* row = mp + ((size_t)id * 64 + ih) * 64;
            for (int kw = 0; kw < 4; kw++) {
                int iw = 2 * ow - 1 + kw;
                if ((unsigned)iw < 64u && row[iw] > 0.5f) acc += 1.f;
            }
        }
    }
    float mv = acc > 0.f ? 1.f : 0.f;
    g_m1[idx] = mv;
    if (mv > 0.f) atomicAdd(&g_cnt[0], 1u);
}

__global__ __launch_bounds__(256) void mask2_kernel() { mask_down_body(g_m1, g_m2, &g_cnt[1], 5, 4); }
__global__ __launch_bounds__(256) void mask3_kernel() { mask_down_body(g_m2, g_m3, &g_cnt[2], 4, 3); }
__global__ __launch_bounds__(256) void mask4_kernel() { mask_up_body(g_m3, g_mt1, &g_cnt[3], 3, 4); }
__global__ __launch_bounds__(256) void mask5_kernel() { mask_up_body(g_mt1, g_mt2, &g_cnt[4], 4, 5); }

// ---------------------------------------------------------------------------
// bf16 MFMA implicit-GEMM.
// MODE 0 = down conv (k4 s2 p1), MODE 1 = transpose conv (parity = z&7).
// Block 256 = 4 waves tiled 2x2 over (M,N). MFMA 16x16x32 bf16.
// A: [MT][48] bf16 in LDS (K-octet contiguous); B: [NT][48].
// Fragment layouts (m89/m91): A[m=lane&15][k=quad*8+j], B[k=quad*8+j][n=lane&15],
// D row=quad*4+r, col=lane&15.
// SPLITK>1: raw partials atomicAdd into y (post kernel finishes); else store.
// ---------------------------------------------------------------------------
template<int MODE, int MT, int NT, int CIN, int COUT, int LOGDI, int LOGDO, int SPLITK>
DEV void mfma_gemm_body(const ushort* __restrict__ xb, const float* __restrict__ w,
                        float* __restrict__ y) {
    constexpr int KT = 32;
    constexpr int K  = (MODE == 1) ? CIN * 8 : CIN * 64;
    constexpr int KSEG = K / SPLITK;
    constexpr int LDA = 48;
    constexpr int MTW = MT / 32, NTW = NT / 32;      // tiles per wave (2x2 waves)
    constexpr int AR = MT * 4 / 256, BR = NT * 4 / 256;
    constexpr int LAM = (MT == 128) ? 7 : 6, LBN = (NT == 128) ? 7 : 6;
    constexpr int Din = 1 << LOGDI, Do = 1 << LOGDO;

    __shared__ __align__(16) ushort As[MT * LDA];
    __shared__ __align__(16) ushort Bs[NT * LDA];

    const int tid = threadIdx.x;
    const int bx = blockIdx.x, by = blockIdx.y;
    int pd = 0, ph = 0, pw = 0, ks = 0;
    if constexpr (MODE == 1) {
        int z = blockIdx.z;
        pd = (z >> 2) & 1; ph = (z >> 1) & 1; pw = z & 1; ks = z >> 3;
    } else {
        ks = blockIdx.z;
    }

    const int wv = tid >> 6, lane = tid & 63;
    const int mw = wv & 1, nw = wv >> 1;
    const int lr = lane & 15, quad = lane >> 4;

    accv acc[MTW][NTW];
#pragma unroll
    for (int mt = 0; mt < MTW; mt++)
#pragma unroll
        for (int nt = 0; nt < NTW; nt++) acc[mt][nt] = (accv){0.f, 0.f, 0.f, 0.f};

    const int kbeg = ks * KSEG, kend = kbeg + KSEG;
    for (int kt = kbeg; kt < kend; kt += KT) {
        __syncthreads();
        // ---- stage A (weights fp32 -> bf16), one K-octet per slot
#pragma unroll
        for (int r = 0; r < AR; r++) {
            int slot = r * 256 + tid;
            int m = slot & (MT - 1), oct = slot >> LAM;
            int co = by * MT + m;
            int kg0 = kt + oct * 8;
            ushort pk[8];
            if constexpr (MODE == 0) {
                const float* wp = w + (size_t)co * (CIN * 64) + kg0;
#pragma unroll
                for (int j = 0; j < 8; j++) pk[j] = f2bf(wp[j]);
            } else {
                int ci = kg0 >> 3;
                const float* wp = w + ((size_t)co * CIN + ci) * 64;
#pragma unroll
                for (int j = 0; j < 8; j++) {
                    int td = (j >> 2) & 1, th = (j >> 1) & 1, tw = j & 1;
                    pk[j] = f2bf(wp[(3 - pd - 2 * td) * 16 + (3 - ph - 2 * th) * 4 + (3 - pw - 2 * tw)]);
                }
            }
            *(ushort8*)&As[m * LDA + oct * 8] =
                (ushort8){pk[0], pk[1], pk[2], pk[3], pk[4], pk[5], pk[6], pk[7]};
        }
        // ---- stage B (bf16 activations, im2col), one K-octet per slot
#pragma unroll
        for (int r = 0; r < BR; r++) {
            int slot = r * 256 + tid;
            int n = slot & (NT - 1), oct = slot >> LBN;
            int vg = bx * NT + n;
            int kg0 = kt + oct * 8;
            ushort pk[8];
            if constexpr (MODE == 0) {
                int b = vg >> (3 * LOGDO), v = vg & ((1 << (3 * LOGDO)) - 1);
                int od = v >> (2 * LOGDO), oh = (v >> LOGDO) & (Do - 1), ow = v & (Do - 1);
                int ci = kg0 >> 6;
                const ushort* xp = xb + ((size_t)(b * CIN + ci) << (3 * LOGDI));
#pragma unroll
                for (int j = 0; j < 8; j++) {
                    int kg = kg0 + j;
                    int id = 2 * od - 1 + ((kg >> 4) & 3);
                    int ih = 2 * oh - 1 + ((kg >> 2) & 3);
                    int iw = 2 * ow - 1 + (kg & 3);
                    ushort val = 0;
                    if ((unsigned)id < (unsigned)Din && (unsigned)ih < (unsigned)Din &&
                        (unsigned)iw < (unsigned)Din)
                        val = xp[(id << (2 * LOGDI)) + (ih << LOGDI) + iw];
                    pk[j] = val;
                }
            } else {
                int b = vg >> (3 * LOGDI), v = vg & ((1 << (3 * LOGDI)) - 1);
                int odp = v >> (2 * LOGDI), ohp = (v >> LOGDI) & (Din - 1), owp = v & (Din - 1);
                int ci = kg0 >> 3;
                const ushort* xp = xb + ((size_t)(b * CIN + ci) << (3 * LOGDI));
#pragma unroll
                for (int j = 0; j < 8; j++) {
                    int td = (j >> 2) & 1, th = (j >> 1) & 1, tw = j & 1;
                    int id = odp + pd + td - 1;
                    int ih = ohp + ph + th - 1;
                    int iw = owp + pw + tw - 1;
                    ushort val = 0;
                    if ((unsigned)id < (unsigned)Din && (unsigned)ih < (unsigned)Din &&
                        (unsigned)iw < (unsigned)Din)
                        val = xp[(id << (2 * LOGDI)) + (ih << LOGDI) + iw];
                    pk[j] = val;
                }
            }
            *(ushort8*)&Bs[n * LDA + oct * 8] =
                (ushort8){pk[0], pk[1], pk[2], pk[3], pk[4], pk[5], pk[6], pk[7]};
        }
        __syncthreads();
        // ---- compute: one MFMA consumes the full KT=32 slice
        short8 af[MTW], bfr[NTW];
#pragma unroll
        for (int mt = 0; mt < MTW; mt++)
            af[mt] = *(const short8*)&As[((mw * MTW + mt) * 16 + lr) * LDA + quad * 8];
#pragma unroll
        for (int nt = 0; nt < NTW; nt++)
            bfr[nt] = *(const short8*)&Bs[((nw * NTW + nt) * 16 + lr) * LDA + quad * 8];
#pragma unroll
        for (int mt = 0; mt < MTW; mt++)
#pragma unroll
            for (int nt = 0; nt < NTW; nt++)
                acc[mt][nt] = __builtin_amdgcn_mfma_f32_16x16x32_bf16(
                    af[mt], bfr[nt], acc[mt][nt], 0, 0, 0);
    }

    // ---- epilogue: raw values (post kernel applies bias/mask/leaky/stats)
#pragma unroll
    for (int mt = 0; mt < MTW; mt++) {
#pragma unroll
        for (int nt = 0; nt < NTW; nt++) {
#pragma unroll
            for (int r = 0; r < 4; r++) {
                int co = by * MT + (mw * MTW + mt) * 16 + quad * 4 + r;
                int vg = bx * NT + (nw * NTW + nt) * 16 + lr;
                int b; size_t idx;
                if constexpr (MODE == 1) {
                    b = vg >> (3 * LOGDI);
                    int v = vg & ((1 << (3 * LOGDI)) - 1);
                    int odp = v >> (2 * LOGDI), ohp = (v >> LOGDI) & (Din - 1), owp = v & (Din - 1);
                    int od = 2 * odp + pd, oh = 2 * ohp + ph, ow = 2 * owp + pw;
                    idx = (((size_t)(b * COUT + co)) << (3 * LOGDO)) +
                          (od << (2 * LOGDO)) + (oh << LOGDO) + ow;
                } else {
                    b = vg >> (3 * LOGDO);
                    int off = vg & ((1 << (3 * LOGDO)) - 1);
                    idx = (((size_t)(b * COUT + co)) << (3 * LOGDO)) + off;
                }
                float val = acc[mt][nt][r];
                if constexpr (SPLITK > 1) atomicAdd(&y[idx], val);
                else y[idx] = val;
            }
        }
    }
}

__global__ __launch_bounds__(256)
void conv2_kernel(const float* w) { mfma_gemm_body<0, 64, 128, 32, 64, 5, 4, 4>(g_y1b, w, g_y2); }
__global__ __launch_bounds__(256)
void conv3_kernel(const float* w) { mfma_gemm_body<0, 128, 64, 64, 128, 4, 3, 16>(g_y2b, w, g_y3); }
__global__ __launch_bounds__(256)
void conv4_kernel(const float* w) { mfma_gemm_body<1, 128, 128, 128, 128, 3, 4, 4>(g_y3b, w, g_t1); }
__global__ __launch_bounds__(256)
void conv5_kernel(const float* w) { mfma_gemm_body<1, 64, 128, 128, 64, 4, 5, 1>(g_t1b, w, g_t2); }

// ---------------------------------------------------------------------------
// fp32 implicit-GEMM (conv1 fused prep, final 1x1x1) — verified round-4/5 code
// ---------------------------------------------------------------------------
template<int MODE, int MT, int NT, int CIN, int COUT, int LOGDI, int LOGDO>
DEV void gemm_body(const float* __restrict__ x, const float* __restrict__ rawm,
                   const float* __restrict__ w, const float* __restrict__ bias,
                   const float* __restrict__ m2, float* __restrict__ y,
                   float* __restrict__ stats) {
    constexpr int KT = 32;
    constexpr int K  = (MODE == 2) ? CIN : CIN * 64;
    constexpr int MR = MT / 16, VR = NT / 16;
    constexpr int EA = KT * MT / 256, EB = KT * NT / 256;
    constexpr int LMT = (MT == 64) ? 6 : 5, LNT = (NT == 64) ? 6 : 5;
    constexpr int Din = 1 << LOGDI, Do = 1 << LOGDO;

    __shared__ float As[KT * MT];
    __shared__ float Bs[KT * NT];

    const int tid = threadIdx.x, tc = tid & 15, tv = tid >> 4;
    const int bx = blockIdx.x, by = blockIdx.y;

    float acc[MR][VR];
#pragma unroll
    for (int r = 0; r < MR; r++)
#pragma unroll
        for (int c = 0; c < VR; c++) acc[r][c] = 0.f;

    for (int kt = 0; kt < K; kt += KT) {
        __syncthreads();
#pragma unroll
        for (int e = 0; e < EA; e++) {
            int j = tid * EA + e;          // per-thread contiguous (round-4 pattern)
            int kk = j >> LMT, m = j & (MT - 1);
            int kg = kt + kk;
            int co = by * MT + m;
            float val;
            if constexpr (MODE == 2) val = w[co * CIN + kg];
            else val = w[(size_t)co * (CIN * 64) + kg];
            As[kk * MT + m] = val;
        }
#pragma unroll
        for (int e = 0; e < EB; e++) {
            int j = tid * EB + e;
            int kk = j >> LNT, n = j & (NT - 1);
            int kg = kt + kk;
            int vg = bx * NT + n;
            float val = 0.f;
            if constexpr (MODE == 2) {
                int b = vg >> 15, v = vg & 32767;
                val = x[(((size_t)(b * CIN + kg)) << 15) + v];
            } else {
                int b = vg >> (3 * LOGDO), v = vg & ((1 << (3 * LOGDO)) - 1);
                int od = v >> (2 * LOGDO), oh = (v >> LOGDO) & (Do - 1), ow = v & (Do - 1);
                int ci = kg >> 6;
                int id = 2 * od - 1 + ((kg >> 4) & 3);
                int ih = 2 * oh - 1 + ((kg >> 2) & 3);
                int iw = 2 * ow - 1 + (kg & 3);
                if ((unsigned)id < (unsigned)Din && (unsigned)ih < (unsigned)Din &&
                    (unsigned)iw < (unsigned)Din) {
                    int off = (id << (2 * LOGDI)) + (ih << LOGDI) + iw;
                    if (rawm[((size_t)b << (3 * LOGDI)) + off] > 0.5f)
                        val = x[(((size_t)(b * CIN + ci)) << (3 * LOGDI)) + off];
                }
            }
            Bs[kk * NT + n] = val;
        }
        __syncthreads();
#pragma unroll
        for (int kk = 0; kk < KT; kk++) {
            float a[MR], bb[VR];
            if constexpr (MR == 4) {
                float4 t4 = *(const float4*)&As[kk * MT + tc * 4];
                a[0] = t4.x; a[1] = t4.y; a[2] = t4.z; a[3] = t4.w;
            } else {
                float2 t2 = *(const float2*)&As[kk * MT + tc * 2];
                a[0] = t2.x; a[1] = t2.y;
            }
            if constexpr (VR == 4) {
                float4 t4 = *(const float4*)&Bs[kk * NT + tv * 4];
                bb[0] = t4.x; bb[1] = t4.y; bb[2] = t4.z; bb[3] = t4.w;
            } else {
                float2 t2 = *(const float2*)&Bs[kk * NT + tv * 2];
                bb[0] = t2.x; bb[1] = t2.y;
            }
#pragma unroll
            for (int r = 0; r < MR; r++)
#pragma unroll
                for (int c = 0; c < VR; c++) acc[r][c] = fmaf(a[r], bb[c], acc[r][c]);
        }
    }

    if constexpr (MODE == 2) {
#pragma unroll
        for (int r = 0; r < MR; r++) {
            int co = by * MT + tc * MR + r;
            float bv = bias[co];
#pragma unroll
            for (int c = 0; c < VR; c++) {
                int vg = bx * NT + tv * VR + c;
                int b = vg >> 15, v = vg & 32767;
                y[(((size_t)(b * COUT + co)) << 15) + v] = acc[r][c] + bv;
            }
        }
    } else {
        float s[MR], s2[MR];
#pragma unroll
        for (int r = 0; r < MR; r++) { s[r] = 0.f; s2[r] = 0.f; }
#pragma unroll
        for (int r = 0; r < MR; r++) {
            int co = by * MT + tc * MR + r;
            float bv = bias[co];
#pragma unroll
            for (int c = 0; c < VR; c++) {
                int vg = bx * NT + tv * VR + c;
                int b = vg >> (3 * LOGDO), off = vg & ((1 << (3 * LOGDO)) - 1);
                float mv = m2[((size_t)b << (3 * LOGDO)) + off];
                float yv = (acc[r][c] + bv) * mv;
                yv = yv >= 0.f ? yv : 0.01f * yv;
                y[(((size_t)(b * COUT + co)) << (3 * LOGDO)) + off] = yv;
                s[r] += yv; s2[r] += yv * yv;
            }
        }
        __syncthreads();
#pragma unroll
        for (int r = 0; r < MR; r++) {
            As[tv * MT + tc * MR + r] = s[r];
            Bs[tv * MT + tc * MR + r] = s2[r];
        }
        __syncthreads();
        if (tid < MT) {
            float S = 0.f, S2 = 0.f;
#pragma unroll
            for (int t = 0; t < 16; t++) { S += As[t * MT + tid]; S2 += Bs[t * MT + tid]; }
            int co = by * MT + tid;
            atomicAdd(&stats[co], S);
            atomicAdd(&stats[128 + co], S2);
        }
    }
}

__global__ __launch_bounds__(256)
void conv1_kernel(const float* feat, const float* mask, const float* w, const float* b)
{ gemm_body<3, 32, 64, 4, 32, 6, 5>(feat, mask, w, b, g_m1, g_y1, g_stats); }

__global__ __launch_bounds__(256)
void final_kernel(const float* fw, const float* fb, float* out)
{ gemm_body<2, 32, 64, 64, 32, 5, 5>(g_t2, nullptr, fw, fb, nullptr, out, nullptr); }

// ---------------------------------------------------------------------------
// post: bias + mask + LeakyReLU + stats (for MFMA layers)
// ---------------------------------------------------------------------------
template<int COUT, int LOGDO>
DEV void post_body(const float* __restrict__ bias, const float* __restrict__ m2,
                   float* __restrict__ y, float* __restrict__ stats) {
    int idx = blockIdx.x * 256 + threadIdx.x;
    constexpr int Dvox = 1 << (3 * LOGDO);
    int v = idx & (Dvox - 1);
    int co = (idx >> (3 * LOGDO)) & (COUT - 1);
    int b = idx >> (3 * LOGDO + (COUT == 128 ? 7 : (COUT == 64 ? 6 : 5)));
    float mv = m2[((size_t)b << (3 * LOGDO)) + v];
    float yv = (y[idx] + bias[co]) * mv;
    yv = yv >= 0.f ? yv : 0.01f * yv;
    y[idx] = yv;
    float s = yv, s2 = yv * yv;
#pragma unroll
    for (int off = 32; off; off >>= 1) {
        s += __shfl_down(s, off, 64);
        s2 += __shfl_down(s2, off, 64);
    }
    __shared__ float red[8];
    int lane = threadIdx.x & 63, wv = threadIdx.x >> 6;
    if (!lane) { red[wv] = s; red[4 + wv] = s2; }
    __syncthreads();
    if (!threadIdx.x) {
        atomicAdd(&stats[co],       red[0] + red[1] + red[2] + red[3]);
        atomicAdd(&stats[128 + co], red[4] + red[5] + red[6] + red[7]);
    }
}

__global__ __launch_bounds__(256) void post2_kernel(const float* b) { post_body<64, 4>(b, g_m2, g_y2, g_stats + 512); }
__global__ __launch_bounds__(256) void post3_kernel(const float* b) { post_body<128, 3>(b, g_m3, g_y3, g_stats + 1024); }
__global__ __launch_bounds__(256) void post4_kernel(const float* b) { post_body<128, 4>(b, g_mt1, g_t1, g_stats + 1536); }
__global__ __launch_bounds__(256) void post5_kernel(const float* b) { post_body<64, 5>(b, g_mt2, g_t2, g_stats + 2048); }

// ---------------------------------------------------------------------------
// stats finalize + BN apply
// ---------------------------------------------------------------------------
DEV void finalize_body(float* stats, const unsigned* cnt,
                       const float* g, const float* be, int C) {
    int c = threadIdx.x;
    if (c >= C) return;
    unsigned cu = *cnt;
    float n = (float)(cu < 1u ? 1u : cu);
    float mean = stats[c] / n;
    float var = fmaxf(stats[128 + c] / n - mean * mean, 0.f);
    float rstd = rsqrtf(var + 1e-5f);
    float sc = g[c] * rstd;
    stats[256 + c] = sc;
    stats[384 + c] = be[c] - mean * sc;
}

__global__ void fin1_kernel(const float* g, const float* be) { finalize_body(g_stats + 0,    &g_cnt[0], g, be, 32); }
__global__ void fin2_kernel(const float* g, const float* be) { finalize_body(g_stats + 512,  &g_cnt[1], g, be, 64); }
__global__ void fin3_kernel(const float* g, const float* be) { finalize_body(g_stats + 1024, &g_cnt[2], g, be, 128); }
__global__ void fin4_kernel(const float* g, const float* be) { finalize_body(g_stats + 1536, &g_cnt[3], g, be, 128); }
__global__ void fin5_kernel(const float* g, const float* be) { finalize_body(g_stats + 2048, &g_cnt[4], g, be, 64); }

// BN apply writing bf16 copy (input to next MFMA conv)
DEV void bn_bf_body(const float* y, ushort* out, const float* stats,
                    const float* m2, int logC, int logDvox) {
    int idx = blockIdx.x * 256 + threadIdx.x;
    int v = idx & ((1 << logDvox) - 1);
    int c = (idx >> logDvox) & ((1 << logC) - 1);
    int b = idx >> (logDvox + logC);
    float mv = m2[((size_t)b << logDvox) + v];
    out[idx] = f2bf((y[idx] * stats[256 + c] + stats[384 + c]) * mv);
}

__global__ __launch_bounds__(256) void bn1_kernel() { bn_bf_body(g_y1, g_y1b, g_stats + 0,    g_m1, 5, 15); }
__global__ __launch_bounds__(256) void bn2_kernel() { bn_bf_body(g_y2, g_y2b, g_stats + 512,  g_m2, 6, 12); }
__global__ __launch_bounds__(256) void bn3_kernel() { bn_bf_body(g_y3, g_y3b, g_stats + 1024, g_m3, 7, 9); }
__global__ __launch_bounds__(256) void bn4_kernel() { bn_bf_body(g_t1, g_t1b, g_stats + 1536, g_mt1, 7, 12); }

// BN apply in-place fp32 (t2 -> final conv)
__global__ __launch_bounds__(256)
void bn5_kernel() {
    int idx = blockIdx.x * 256 + threadIdx.x;
    int v = idx & 32767;
    int c = (idx >> 15) & 63;
    int b = idx >> 21;
    float mv = g_mt2[((size_t)b << 15) + v];
    g_t2[idx] = (g_t2[idx] * g_stats[2048 + 256 + c] + g_stats[2048 + 384 + c]) * mv;
}

// ---------------------------------------------------------------------------

extern "C" void kernel_launch(void* const* d_in, const int* in_sizes, int n_in,
                              void* d_out, int out_size, void* d_ws, size_t ws_size,
                              hipStream_t stream) {
    (void)in_sizes; (void)n_in; (void)out_size; (void)d_ws; (void)ws_size;
    const float* feat = (const float*)d_in[0];
    const float* mask = (const float*)d_in[1];
    const float* w1  = (const float*)d_in[2];
    const float* b1  = (const float*)d_in[3];
    const float* g1  = (const float*)d_in[4];
    const float* be1 = (const float*)d_in[5];
    const float* w2  = (const float*)d_in[6];
    const float* b2  = (const float*)d_in[7];
    const float* g2  = (const float*)d_in[8];
    const float* be2 = (const float*)d_in[9];
    const float* w3  = (const float*)d_in[10];
    const float* b3  = (const float*)d_in[11];
    const float* g3  = (const float*)d_in[12];
    const float* be3 = (const float*)d_in[13];
    const float* tw1 = (const float*)d_in[14];
    const float* tb1 = (const float*)d_in[15];
    const float* tg1 = (const float*)d_in[16];
    const float* tbe1= (const float*)d_in[17];
    const float* tw2 = (const float*)d_in[18];
    const float* tb2 = (const float*)d_in[19];
    const float* tg2 = (const float*)d_in[20];
    const float* tbe2= (const float*)d_in[21];
    const float* fw  = (const float*)d_in[22];
    const float* fb  = (const float*)d_in[23];

    zero_ws_kernel<<<4096, 256, 0, stream>>>();

    // block 1 (fp32): 4->32, 64^3 -> 32^3
    mask1_kernel<<<256, 256, 0, stream>>>(mask);
    conv1_kernel<<<dim3(1024, 1), 256, 0, stream>>>(feat, mask, w1, b1);
    fin1_kernel<<<1, 128, 0, stream>>>(g1, be1);
    bn1_kernel<<<8192, 256, 0, stream>>>();

    // block 2 (bf16 MFMA): 32->64, 32^3 -> 16^3, K=2048 split 4
    mask2_kernel<<<32, 256, 0, stream>>>();
    conv2_kernel<<<dim3(64, 1, 4), 256, 0, stream>>>(w2);
    post2_kernel<<<2048, 256, 0, stream>>>(b2);
    fin2_kernel<<<1, 128, 0, stream>>>(g2, be2);
    bn2_kernel<<<2048, 256, 0, stream>>>();

    // block 3 (bf16 MFMA): 64->128, 16^3 -> 8^3, K=4096 split 16
    mask3_kernel<<<4, 256, 0, stream>>>();
    conv3_kernel<<<dim3(16, 1, 16), 256, 0, stream>>>(w3);
    post3_kernel<<<512, 256, 0, stream>>>(b3);
    fin3_kernel<<<1, 128, 0, stream>>>(g3, be3);
    bn3_kernel<<<512, 256, 0, stream>>>();

    // up block 1 (bf16 MFMA): 128->128, 8^3 -> 16^3, 8 parity x split 4
    mask4_kernel<<<32, 256, 0, stream>>>();
    conv4_kernel<<<dim3(8, 1, 32), 256, 0, stream>>>(tw1);
    post4_kernel<<<4096, 256, 0, stream>>>(tb1);
    fin4_kernel<<<1, 128, 0, stream>>>(tg1, tbe1);
    bn4_kernel<<<4096, 256, 0, stream>>>();

    // up block 2 (bf16 MFMA): 128->64, 16^3 -> 32^3, 8 parity, direct store
    mask5_kernel<<<256, 256, 0, stream>>>();
    conv5_kernel<<<dim3(64, 1, 8), 256, 0, stream>>>(tw2);
    post5_kernel<<<16384, 256, 0, stream>>>(tb2);
    fin5_kernel<<<1, 128, 0, stream>>>(tg2, tbe2);
    bn5_kernel<<<16384, 256, 0, stream>>>();

    // final dense 1x1x1 conv 64->32 @ 32^3 (fp32)
    final_kernel<<<dim3(1024, 1), 256, 0, stream>>>(fw, fb, (float*)d_out);
}

// Round 7
// 476.439 us; speedup vs baseline: 2.0855x; 1.2370x over previous
//
#include <hip/hip_runtime.h>
#include <hip/hip_bf16.h>

#define DEV static __device__ __forceinline__

typedef unsigned short ushort;
typedef __attribute__((ext_vector_type(8))) short short8;
typedef __attribute__((ext_vector_type(8))) ushort ushort8;
typedef __attribute__((ext_vector_type(4))) float accv;

DEV ushort f2bf(float f) {
    __hip_bfloat16 h = __float2bfloat16(f);   // RNE
    return reinterpret_cast<ushort&>(h);
}

// ---------------------------------------------------------------------------
// Static device workspace
// ---------------------------------------------------------------------------
__device__ float    g_stats[2576];
__device__ unsigned g_cnt[16];
__device__ float    g_y1[2097152];                    // (2,32,32^3) fp32 NCV
__device__ __align__(16) ushort g_y1b[2097152];       // (2,32^3,32) bf16 VC
__device__ float    g_m1[65536];
__device__ float    g_y2[524288];                     // fp32 NCV (post2 out)
__device__ __align__(16) ushort g_y2b[524288];        // (2,16^3,64) bf16 VC
__device__ float    g_m2[8192];
__device__ float    g_y3[131072];
__device__ __align__(16) ushort g_y3b[131072];        // (2,8^3,128) bf16 VC
__device__ float    g_m3[1024];
__device__ float    g_t1[1048576];
__device__ __align__(16) ushort g_t1b[1048576];       // (2,16^3,128) bf16 VC
__device__ float    g_mt1[8192];
__device__ float    g_mt2[65536];
__device__ float    g_t2[4194304];                    // conv5 out fp32 NCV
// split-K partial buffers (no atomics)
__device__ float    g_p2[2097152];                    // 4 x 524288
__device__ float    g_p3[2097152];                    // 16 x 131072
__device__ float    g_p4[4194304];                    // 4 x 1048576
// K-major bf16 weights
__device__ __align__(16) ushort g_wb2[131072];        // [64co][2048k]
__device__ __align__(16) ushort g_wb3[524288];        // [128co][4096k]
__device__ __align__(16) ushort g_wb4[1048576];       // [8p][128co][1024k]
__device__ __align__(16) ushort g_wb5[524288];        // [8p][64co][1024k]

// ---------------------------------------------------------------------------
__global__ void zero_stats_kernel() {
    for (int i = threadIdx.x; i < 2576; i += 256) g_stats[i] = 0.f;
    if (threadIdx.x < 16) g_cnt[threadIdx.x] = 0u;
}

// ---------------------------------------------------------------------------
// weight pre-transpose: K-major bf16.  down: k = tap*CIN+ci.
// up: per-parity, tap t=(td,th,tw), kd=3-pd-2td (verified round-6 mapping).
// ---------------------------------------------------------------------------
template<int CIN, int COUT>
DEV void prep_down(const float* w, ushort* wb) {
    int idx = blockIdx.x * 256 + threadIdx.x;          // COUT*CIN*64
    int co = idx / (CIN * 64), r = idx % (CIN * 64);
    int ci = r >> 6, tap = r & 63;
    wb[(size_t)co * (CIN * 64) + tap * CIN + ci] = f2bf(w[idx]);
}
template<int CIN, int COUT>
DEV void prep_up(const float* w, ushort* wb) {
    int idx = blockIdx.x * 256 + threadIdx.x;          // COUT*CIN*64
    int co = idx / (CIN * 64), r = idx % (CIN * 64);
    int ci = r >> 6, t64 = r & 63;
    int kd = t64 >> 4, kh = (t64 >> 2) & 3, kw = t64 & 3;
    int pd = (3 - kd) & 1, td = (3 - kd) >> 1;
    int ph = (3 - kh) & 1, th = (3 - kh) >> 1;
    int pw = (3 - kw) & 1, tw = (3 - kw) >> 1;
    int parity = pd * 4 + ph * 2 + pw, t = td * 4 + th * 2 + tw;
    wb[(((size_t)parity * COUT + co) * 8 + t) * CIN + ci] = f2bf(w[idx]);
}

__global__ __launch_bounds__(256) void prep2_kernel(const float* w) { prep_down<32, 64>(w, g_wb2); }
__global__ __launch_bounds__(256) void prep3_kernel(const float* w) { prep_down<64, 128>(w, g_wb3); }
__global__ __launch_bounds__(256) void prep4_kernel(const float* w) { prep_up<128, 128>(w, g_wb4); }
__global__ __launch_bounds__(256) void prep5_kernel(const float* w) { prep_up<128, 64>(w, g_wb5); }

// ---------------------------------------------------------------------------
// mask dilation kernels (verified)
// ---------------------------------------------------------------------------
DEV void mask_down_body(const float* mprev, float* mout, unsigned* cnt,
                        int logDin, int logDo) {
    int Din = 1 << logDin, Do = 1 << logDo;
    int idx = blockIdx.x * 256 + threadIdx.x;
    int b = idx >> (3 * logDo), v = idx & ((1 << (3 * logDo)) - 1);
    int od = v >> (2 * logDo), rem = v & ((1 << (2 * logDo)) - 1);
    int oh = rem >> logDo, ow = rem & (Do - 1);
    const float* mp = mprev + ((size_t)b << (3 * logDin));
    float acc = 0.f;
    for (int kd = 0; kd < 4; kd++) {
        int id = 2 * od - 1 + kd;
        if ((unsigned)id >= (unsigned)Din) continue;
        for (int kh = 0; kh < 4; kh++) {
            int ih = 2 * oh - 1 + kh;
            if ((unsigned)ih >= (unsigned)Din) continue;
            const float* row = mp + ((size_t)id * Din + ih) * Din;
            for (int kw = 0; kw < 4; kw++) {
                int iw = 2 * ow - 1 + kw;
                if ((unsigned)iw < (unsigned)Din) acc += row[iw];
            }
        }
    }
    float mv = acc > 0.f ? 1.f : 0.f;
    mout[idx] = mv;
    if (mv > 0.f) atomicAdd(cnt, 1u);
}

DEV void mask_up_body(const float* mprev, float* mout, unsigned* cnt,
                      int logDin, int logDo) {
    int Din = 1 << logDin, Do = 1 << logDo;
    int idx = blockIdx.x * 256 + threadIdx.x;
    int b = idx >> (3 * logDo), v = idx & ((1 << (3 * logDo)) - 1);
    int od = v >> (2 * logDo), rem = v & ((1 << (2 * logDo)) - 1);
    int oh = rem >> logDo, ow = rem & (Do - 1);
    const float* mp = mprev + ((size_t)b << (3 * logDin));
    float acc = 0.f;
    for (int kd = 0; kd < 4; kd++) {
        int u = od + kd - 2; if (u < 0 || (u & 1)) continue;
        int id = u >> 1; if (id >= Din) continue;
        for (int kh = 0; kh < 4; kh++) {
            int uh = oh + kh - 2; if (uh < 0 || (uh & 1)) continue;
            int ih = uh >> 1; if (ih >= Din) continue;
            const float* row = mp + ((size_t)id * Din + ih) * Din;
            for (int kw = 0; kw < 4; kw++) {
                int uw = ow + kw - 2; if (uw < 0 || (uw & 1)) continue;
                int iw = uw >> 1; if (iw >= Din) continue;
                acc += row[iw];
            }
        }
    }
    float mv = acc > 0.f ? 1.f : 0.f;
    mout[idx] = mv;
    if (mv > 0.f) atomicAdd(cnt, 1u);
}

__global__ __launch_bounds__(256)
void mask1_kernel(const float* __restrict__ mask) {
    int idx = blockIdx.x * 256 + threadIdx.x;
    int b = idx >> 15, v = idx & 0x7FFF;
    int od = v >> 10, rem = v & 1023;
    int oh = rem >> 5, ow = rem & 31;
    const float* mp = mask + ((size_t)b << 18);
    float acc = 0.f;
    for (int kd = 0; kd < 4; kd++) {
        int id = 2 * od - 1 + kd;
        if ((unsigned)id >= 64u) continue;
        for (int kh = 0; kh < 4; kh++) {
            int ih = 2 * oh - 1 + kh;
            if ((unsigned)ih >= 64u) continue;
            const float* row = mp + ((size_t)id * 64 + ih) * 64;
            for (int kw = 0; kw < 4; kw++) {
                int iw = 2 * ow - 1 + kw;
                if ((unsigned)iw < 64u && row[iw] > 0.5f) acc += 1.f;
            }
        }
    }
    float mv = acc > 0.f ? 1.f : 0.f;
    g_m1[idx] = mv;
    if (mv > 0.f) atomicAdd(&g_cnt[0], 1u);
}

__global__ __launch_bounds__(256) void mask2_kernel() { mask_down_body(g_m1, g_m2, &g_cnt[1], 5, 4); }
__global__ __launch_bounds__(256) void mask3_kernel() { mask_down_body(g_m2, g_m3, &g_cnt[2], 4, 3); }
__global__ __launch_bounds__(256) void mask4_kernel() { mask_up_body(g_m3, g_mt1, &g_cnt[3], 3, 4); }
__global__ __launch_bounds__(256) void mask5_kernel() { mask_up_body(g_mt1, g_mt2, &g_cnt[4], 4, 5); }

// ---------------------------------------------------------------------------
// bf16 MFMA implicit-GEMM, K-major weights + channel-last activations.
// k = tap*CIN + ci. A-octet & B-octet are single 16B loads.
// MODE 0 = down conv; MODE 1 = tconv (parity = z&7, ks = z>>3).
// SPLITK>1: each split writes its own partial buffer slice (no atomics).
// ---------------------------------------------------------------------------
template<int MODE, int MT, int NT, int CIN, int COUT, int LOGDI, int LOGDO, int SPLITK>
DEV void mfma_gemm_body(const ushort* __restrict__ xb, const ushort* __restrict__ wb,
                        float* __restrict__ y) {
    constexpr int KT = 32;
    constexpr int K  = (MODE == 1) ? CIN * 8 : CIN * 64;
    constexpr int KSEG = K / SPLITK;
    constexpr int LDA = 40;                       // ushorts; 80B rows (5x16B)
    constexpr int MTW = MT / 32, NTW = NT / 32;
    constexpr int AR = MT * 4 / 256, BR = NT * 4 / 256;
    constexpr int LCIN = (CIN == 32) ? 5 : ((CIN == 64) ? 6 : 7);
    constexpr int Din = 1 << LOGDI, Do = 1 << LOGDO;
    constexpr int DvoxI = 1 << (3 * LOGDI), DvoxO = 1 << (3 * LOGDO);

    __shared__ __align__(16) ushort As[MT * LDA];
    __shared__ __align__(16) ushort Bs[NT * LDA];

    const int tid = threadIdx.x;
    const int bx = blockIdx.x;
    int pd = 0, ph = 0, pw = 0, ks = 0;
    const ushort* wp = wb;
    if constexpr (MODE == 1) {
        int z = blockIdx.z;
        pd = (z >> 2) & 1; ph = (z >> 1) & 1; pw = z & 1; ks = z >> 3;
        wp = wb + (size_t)(z & 7) * COUT * CIN * 8;
    } else {
        ks = blockIdx.z;
    }

    const int wv = tid >> 6, lane = tid & 63;
    const int mw = wv & 1, nw = wv >> 1;
    const int lr = lane & 15, quad = lane >> 4;

    accv acc[MTW][NTW];
#pragma unroll
    for (int mt = 0; mt < MTW; mt++)
#pragma unroll
        for (int nt = 0; nt < NTW; nt++) acc[mt][nt] = (accv){0.f, 0.f, 0.f, 0.f};

    const int kbeg = ks * KSEG, kend = kbeg + KSEG;
    for (int kt = kbeg; kt < kend; kt += KT) {
        __syncthreads();
        // ---- stage A: one 16B load per slot
#pragma unroll
        for (int r = 0; r < AR; r++) {
            int slot = r * 256 + tid;
            int m = slot >> 2, oct = slot & 3;
            int kg0 = kt + oct * 8;
            *(ushort8*)&As[m * LDA + oct * 8] =
                *(const ushort8*)&wp[(size_t)m * K + kg0];
        }
        // ---- stage B: one bounds check + one 16B load per slot
#pragma unroll
        for (int r = 0; r < BR; r++) {
            int slot = r * 256 + tid;
            int n = slot >> 2, oct = slot & 3;
            int vg = bx * NT + n;
            int kg0 = kt + oct * 8;
            int tap = kg0 >> LCIN, ci0 = kg0 & (CIN - 1);
            ushort8 v = (ushort8){0, 0, 0, 0, 0, 0, 0, 0};
            int b, id, ih, iw;
            if constexpr (MODE == 0) {
                b = vg >> (3 * LOGDO);
                int vv = vg & (DvoxO - 1);
                int od = vv >> (2 * LOGDO), oh = (vv >> LOGDO) & (Do - 1), ow = vv & (Do - 1);
                id = 2 * od - 1 + (tap >> 4);
                ih = 2 * oh - 1 + ((tap >> 2) & 3);
                iw = 2 * ow - 1 + (tap & 3);
            } else {
                b = vg >> (3 * LOGDI);
                int vv = vg & (DvoxI - 1);
                int odp = vv >> (2 * LOGDI), ohp = (vv >> LOGDI) & (Din - 1), owp = vv & (Din - 1);
                id = odp + pd + ((tap >> 2) & 1) - 1;
                ih = ohp + ph + ((tap >> 1) & 1) - 1;
                iw = owp + pw + (tap & 1) - 1;
            }
            if ((unsigned)id < (unsigned)Din && (unsigned)ih < (unsigned)Din &&
                (unsigned)iw < (unsigned)Din)
                v = *(const ushort8*)&xb[((size_t)b * DvoxI +
                                          (id << (2 * LOGDI)) + (ih << LOGDI) + iw) * CIN + ci0];
            *(ushort8*)&Bs[n * LDA + oct * 8] = v;
        }
        __syncthreads();
        // ---- compute
        short8 af[MTW], bfr[NTW];
#pragma unroll
        for (int mt = 0; mt < MTW; mt++)
            af[mt] = *(const short8*)&As[((mw * MTW + mt) * 16 + lr) * LDA + quad * 8];
#pragma unroll
        for (int nt = 0; nt < NTW; nt++)
            bfr[nt] = *(const short8*)&Bs[((nw * NTW + nt) * 16 + lr) * LDA + quad * 8];
#pragma unroll
        for (int mt = 0; mt < MTW; mt++)
#pragma unroll
            for (int nt = 0; nt < NTW; nt++)
                acc[mt][nt] = __builtin_amdgcn_mfma_f32_16x16x32_bf16(
                    af[mt], bfr[nt], acc[mt][nt], 0, 0, 0);
    }

    // ---- epilogue: direct stores into this split's partial slice
    float* yp = y + (size_t)ks * (2 * COUT * DvoxO);
#pragma unroll
    for (int mt = 0; mt < MTW; mt++) {
#pragma unroll
        for (int nt = 0; nt < NTW; nt++) {
#pragma unroll
            for (int r = 0; r < 4; r++) {
                int co = (mw * MTW + mt) * 16 + quad * 4 + r;
                int vg = bx * NT + (nw * NTW + nt) * 16 + lr;
                size_t idx;
                if constexpr (MODE == 1) {
                    int b = vg >> (3 * LOGDI);
                    int vv = vg & (DvoxI - 1);
                    int odp = vv >> (2 * LOGDI), ohp = (vv >> LOGDI) & (Din - 1), owp = vv & (Din - 1);
                    int od = 2 * odp + pd, oh = 2 * ohp + ph, ow = 2 * owp + pw;
                    idx = (((size_t)(b * COUT + co)) << (3 * LOGDO)) +
                          (od << (2 * LOGDO)) + (oh << LOGDO) + ow;
                } else {
                    int b = vg >> (3 * LOGDO);
                    int off = vg & (DvoxO - 1);
                    idx = (((size_t)(b * COUT + co)) << (3 * LOGDO)) + off;
                }
                yp[idx] = acc[mt][nt][r];
            }
        }
    }
}

__global__ __launch_bounds__(256)
void conv2_kernel() { mfma_gemm_body<0, 64, 128, 32, 64, 5, 4, 4>(g_y1b, g_wb2, g_p2); }
__global__ __launch_bounds__(256)
void conv3_kernel() { mfma_gemm_body<0, 128, 64, 64, 128, 4, 3, 16>(g_y2b, g_wb3, g_p3); }
__global__ __launch_bounds__(256)
void conv4_kernel() { mfma_gemm_body<1, 128, 128, 128, 128, 3, 4, 4>(g_y3b, g_wb4, g_p4); }
__global__ __launch_bounds__(256)
void conv5_kernel() { mfma_gemm_body<1, 64, 128, 128, 64, 4, 5, 1>(g_t1b, g_wb5, g_t2); }

// ---------------------------------------------------------------------------
// fp32 implicit-GEMM (conv1 fused prep, final 1x1x1) — verified
// ---------------------------------------------------------------------------
template<int MODE, int MT, int NT, int CIN, int COUT, int LOGDI, int LOGDO>
DEV void gemm_body(const float* __restrict__ x, const float* __restrict__ rawm,
                   const float* __restrict__ w, const float* __restrict__ bias,
                   const float* __restrict__ m2, float* __restrict__ y,
                   float* __restrict__ stats) {
    constexpr int KT = 32;
    constexpr int K  = (MODE == 2) ? CIN : CIN * 64;
    constexpr int MR = MT / 16, VR = NT / 16;
    constexpr int EA = KT * MT / 256, EB = KT * NT / 256;
    constexpr int LMT = (MT == 64) ? 6 : 5, LNT = (NT == 64) ? 6 : 5;
    constexpr int Din = 1 << LOGDI, Do = 1 << LOGDO;

    __shared__ float As[KT * MT];
    __shared__ float Bs[KT * NT];

    const int tid = threadIdx.x, tc = tid & 15, tv = tid >> 4;
    const int bx = blockIdx.x, by = blockIdx.y;

    float acc[MR][VR];
#pragma unroll
    for (int r = 0; r < MR; r++)
#pragma unroll
        for (int c = 0; c < VR; c++) acc[r][c] = 0.f;

    for (int kt = 0; kt < K; kt += KT) {
        __syncthreads();
#pragma unroll
        for (int e = 0; e < EA; e++) {
            int j = tid * EA + e;
            int kk = j >> LMT, m = j & (MT - 1);
            int kg = kt + kk;
            int co = by * MT + m;
            float val;
            if constexpr (MODE == 2) val = w[co * CIN + kg];
            else val = w[(size_t)co * (CIN * 64) + kg];
            As[kk * MT + m] = val;
        }
#pragma unroll
        for (int e = 0; e < EB; e++) {
            int j = tid * EB + e;
            int kk = j >> LNT, n = j & (NT - 1);
            int kg = kt + kk;
            int vg = bx * NT + n;
            float val = 0.f;
            if constexpr (MODE == 2) {
                int b = vg >> 15, v = vg & 32767;
                val = x[(((size_t)(b * CIN + kg)) << 15) + v];
            } else {
                int b = vg >> (3 * LOGDO), v = vg & ((1 << (3 * LOGDO)) - 1);
                int od = v >> (2 * LOGDO), oh = (v >> LOGDO) & (Do - 1), ow = v & (Do - 1);
                int ci = kg >> 6;
                int id = 2 * od - 1 + ((kg >> 4) & 3);
                int ih = 2 * oh - 1 + ((kg >> 2) & 3);
                int iw = 2 * ow - 1 + (kg & 3);
                if ((unsigned)id < (unsigned)Din && (unsigned)ih < (unsigned)Din &&
                    (unsigned)iw < (unsigned)Din) {
                    int off = (id << (2 * LOGDI)) + (ih << LOGDI) + iw;
                    if (rawm[((size_t)b << (3 * LOGDI)) + off] > 0.5f)
                        val = x[(((size_t)(b * CIN + ci)) << (3 * LOGDI)) + off];
                }
            }
            Bs[kk * NT + n] = val;
        }
        __syncthreads();
#pragma unroll
        for (int kk = 0; kk < KT; kk++) {
            float a[MR], bb[VR];
            if constexpr (MR == 4) {
                float4 t4 = *(const float4*)&As[kk * MT + tc * 4];
                a[0] = t4.x; a[1] = t4.y; a[2] = t4.z; a[3] = t4.w;
            } else {
                float2 t2 = *(const float2*)&As[kk * MT + tc * 2];
                a[0] = t2.x; a[1] = t2.y;
            }
            if constexpr (VR == 4) {
                float4 t4 = *(const float4*)&Bs[kk * NT + tv * 4];
                bb[0] = t4.x; bb[1] = t4.y; bb[2] = t4.z; bb[3] = t4.w;
            } else {
                float2 t2 = *(const float2*)&Bs[kk * NT + tv * 2];
                bb[0] = t2.x; bb[1] = t2.y;
            }
#pragma unroll
            for (int r = 0; r < MR; r++)
#pragma unroll
                for (int c = 0; c < VR; c++) acc[r][c] = fmaf(a[r], bb[c], acc[r][c]);
        }
    }

    if constexpr (MODE == 2) {
#pragma unroll
        for (int r = 0; r < MR; r++) {
            int co = by * MT + tc * MR + r;
            float bv = bias[co];
#pragma unroll
            for (int c = 0; c < VR; c++) {
                int vg = bx * NT + tv * VR + c;
                int b = vg >> 15, v = vg & 32767;
                y[(((size_t)(b * COUT + co)) << 15) + v] = acc[r][c] + bv;
            }
        }
    } else {
        float s[MR], s2[MR];
#pragma unroll
        for (int r = 0; r < MR; r++) { s[r] = 0.f; s2[r] = 0.f; }
#pragma unroll
        for (int r = 0; r < MR; r++) {
            int co = by * MT + tc * MR + r;
            float bv = bias[co];
#pragma unroll
            for (int c = 0; c < VR; c++) {
                int vg = bx * NT + tv * VR + c;
                int b = vg >> (3 * LOGDO), off = vg & ((1 << (3 * LOGDO)) - 1);
                float mv = m2[((size_t)b << (3 * LOGDO)) + off];
                float yv = (acc[r][c] + bv) * mv;
                yv = yv >= 0.f ? yv : 0.01f * yv;
                y[(((size_t)(b * COUT + co)) << (3 * LOGDO)) + off] = yv;
                s[r] += yv; s2[r] += yv * yv;
            }
        }
        __syncthreads();
#pragma unroll
        for (int r = 0; r < MR; r++) {
            As[tv * MT + tc * MR + r] = s[r];
            Bs[tv * MT + tc * MR + r] = s2[r];
        }
        __syncthreads();
        if (tid < MT) {
            float S = 0.f, S2 = 0.f;
#pragma unroll
            for (int t = 0; t < 16; t++) { S += As[t * MT + tid]; S2 += Bs[t * MT + tid]; }
            int co = by * MT + tid;
            atomicAdd(&stats[co], S);
            atomicAdd(&stats[128 + co], S2);
        }
    }
}

__global__ __launch_bounds__(256)
void conv1_kernel(const float* feat, const float* mask, const float* w, const float* b)
{ gemm_body<3, 32, 64, 4, 32, 6, 5>(feat, mask, w, b, g_m1, g_y1, g_stats); }

__global__ __launch_bounds__(256)
void final_kernel(const float* fw, const float* fb, float* out)
{ gemm_body<2, 32, 64, 64, 32, 5, 5>(g_t2, nullptr, fw, fb, nullptr, out, nullptr); }

// ---------------------------------------------------------------------------
// post: sum SPLITK partials + bias + mask + LeakyReLU + stats -> fp32 NCV
// ---------------------------------------------------------------------------
template<int COUT, int LOGDO, int SPLITK>
DEV void post_body(const float* __restrict__ bias, const float* __restrict__ m2,
                   const float* __restrict__ p, float* __restrict__ y,
                   float* __restrict__ stats) {
    int idx = blockIdx.x * 256 + threadIdx.x;
    constexpr int Dvox = 1 << (3 * LOGDO);
    constexpr size_t STR = (size_t)2 * COUT * Dvox;
    int v = idx & (Dvox - 1);
    int co = (idx >> (3 * LOGDO)) & (COUT - 1);
    int b = idx >> (3 * LOGDO + (COUT == 128 ? 7 : (COUT == 64 ? 6 : 5)));
    float sum = 0.f;
#pragma unroll
    for (int s = 0; s < SPLITK; s++) sum += p[s * STR + idx];
    float mv = m2[((size_t)b << (3 * LOGDO)) + v];
    float yv = (sum + bias[co]) * mv;
    yv = yv >= 0.f ? yv : 0.01f * yv;
    y[idx] = yv;
    float s = yv, s2 = yv * yv;
#pragma unroll
    for (int off = 32; off; off >>= 1) {
        s += __shfl_down(s, off, 64);
        s2 += __shfl_down(s2, off, 64);
    }
    __shared__ float red[8];
    int lane = threadIdx.x & 63, wvi = threadIdx.x >> 6;
    if (!lane) { red[wvi] = s; red[4 + wvi] = s2; }
    __syncthreads();
    if (!threadIdx.x) {
        atomicAdd(&stats[co],       red[0] + red[1] + red[2] + red[3]);
        atomicAdd(&stats[128 + co], red[4] + red[5] + red[6] + red[7]);
    }
}

__global__ __launch_bounds__(256) void post2_kernel(const float* b) { post_body<64, 4, 4>(b, g_m2, g_p2, g_y2, g_stats + 512); }
__global__ __launch_bounds__(256) void post3_kernel(const float* b) { post_body<128, 3, 16>(b, g_m3, g_p3, g_y3, g_stats + 1024); }
__global__ __launch_bounds__(256) void post4_kernel(const float* b) { post_body<128, 4, 4>(b, g_mt1, g_p4, g_t1, g_stats + 1536); }
__global__ __launch_bounds__(256) void post5_kernel(const float* b) { post_body<64, 5, 1>(b, g_mt2, g_t2, g_t2, g_stats + 2048); }

// ---------------------------------------------------------------------------
// stats finalize + BN apply
// ---------------------------------------------------------------------------
DEV void finalize_body(float* stats, const unsigned* cnt,
                       const float* g, const float* be, int C) {
    int c = threadIdx.x;
    if (c >= C) return;
    unsigned cu = *cnt;
    float n = (float)(cu < 1u ? 1u : cu);
    float mean = stats[c] / n;
    float var = fmaxf(stats[128 + c] / n - mean * mean, 0.f);
    float rstd = rsqrtf(var + 1e-5f);
    float sc = g[c] * rstd;
    stats[256 + c] = sc;
    stats[384 + c] = be[c] - mean * sc;
}

__global__ void fin1_kernel(const float* g, const float* be) { finalize_body(g_stats + 0,    &g_cnt[0], g, be, 32); }
__global__ void fin2_kernel(const float* g, const float* be) { finalize_body(g_stats + 512,  &g_cnt[1], g, be, 64); }
__global__ void fin3_kernel(const float* g, const float* be) { finalize_body(g_stats + 1024, &g_cnt[2], g, be, 128); }
__global__ void fin4_kernel(const float* g, const float* be) { finalize_body(g_stats + 1536, &g_cnt[3], g, be, 128); }
__global__ void fin5_kernel(const float* g, const float* be) { finalize_body(g_stats + 2048, &g_cnt[4], g, be, 64); }

// BN apply fp32 NCV -> bf16 channel-last [b][vox][c]
DEV void bn_cl_body(const float* y, ushort* out, const float* stats,
                    const float* m2, int logC, int logDvox) {
    int idx = blockIdx.x * 256 + threadIdx.x;
    int c = idx & ((1 << logC) - 1);
    int vox = (idx >> logC) & ((1 << logDvox) - 1);
    int b = idx >> (logC + logDvox);
    float mv = m2[((size_t)b << logDvox) + vox];
    float val = y[(((size_t)(b << logC) + c) << logDvox) + vox];
    out[idx] = f2bf((val * stats[256 + c] + stats[384 + c]) * mv);
}

__global__ __launch_bounds__(256) void bn1_kernel() { bn_cl_body(g_y1, g_y1b, g_stats + 0,    g_m1, 5, 15); }
__global__ __launch_bounds__(256) void bn2_kernel() { bn_cl_body(g_y2, g_y2b, g_stats + 512,  g_m2, 6, 12); }
__global__ __launch_bounds__(256) void bn3_kernel() { bn_cl_body(g_y3, g_y3b, g_stats + 1024, g_m3, 7, 9); }
__global__ __launch_bounds__(256) void bn4_kernel() { bn_cl_body(g_t1, g_t1b, g_stats + 1536, g_mt1, 7, 12); }

// BN apply in-place fp32 NCV (t2 -> final conv)
__global__ __launch_bounds__(256)
void bn5_kernel() {
    int idx = blockIdx.x * 256 + threadIdx.x;
    int v = idx & 32767;
    int c = (idx >> 15) & 63;
    int b = idx >> 21;
    float mv = g_mt2[((size_t)b << 15) + v];
    g_t2[idx] = (g_t2[idx] * g_stats[2048 + 256 + c] + g_stats[2048 + 384 + c]) * mv;
}

// ---------------------------------------------------------------------------

extern "C" void kernel_launch(void* const* d_in, const int* in_sizes, int n_in,
                              void* d_out, int out_size, void* d_ws, size_t ws_size,
                              hipStream_t stream) {
    (void)in_sizes; (void)n_in; (void)out_size; (void)d_ws; (void)ws_size;
    const float* feat = (const float*)d_in[0];
    const float* mask = (const float*)d_in[1];
    const float* w1  = (const float*)d_in[2];
    const float* b1  = (const float*)d_in[3];
    const float* g1  = (const float*)d_in[4];
    const float* be1 = (const float*)d_in[5];
    const float* w2  = (const float*)d_in[6];
    const float* b2  = (const float*)d_in[7];
    const float* g2  = (const float*)d_in[8];
    const float* be2 = (const float*)d_in[9];
    const float* w3  = (const float*)d_in[10];
    const float* b3  = (const float*)d_in[11];
    const float* g3  = (const float*)d_in[12];
    const float* be3 = (const float*)d_in[13];
    const float* tw1 = (const float*)d_in[14];
    const float* tb1 = (const float*)d_in[15];
    const float* tg1 = (const float*)d_in[16];
    const float* tbe1= (const float*)d_in[17];
    const float* tw2 = (const float*)d_in[18];
    const float* tb2 = (const float*)d_in[19];
    const float* tg2 = (const float*)d_in[20];
    const float* tbe2= (const float*)d_in[21];
    const float* fw  = (const float*)d_in[22];
    const float* fb  = (const float*)d_in[23];

    zero_stats_kernel<<<1, 256, 0, stream>>>();
    prep2_kernel<<<512, 256, 0, stream>>>(w2);
    prep3_kernel<<<2048, 256, 0, stream>>>(w3);
    prep4_kernel<<<4096, 256, 0, stream>>>(tw1);
    prep5_kernel<<<2048, 256, 0, stream>>>(tw2);

    // block 1 (fp32): 4->32, 64^3 -> 32^3
    mask1_kernel<<<256, 256, 0, stream>>>(mask);
    conv1_kernel<<<dim3(1024, 1), 256, 0, stream>>>(feat, mask, w1, b1);
    fin1_kernel<<<1, 128, 0, stream>>>(g1, be1);
    bn1_kernel<<<8192, 256, 0, stream>>>();

    // block 2 (MFMA): 32->64, 32^3 -> 16^3, K=2048 split 4
    mask2_kernel<<<32, 256, 0, stream>>>();
    conv2_kernel<<<dim3(64, 1, 4), 256, 0, stream>>>();
    post2_kernel<<<2048, 256, 0, stream>>>(b2);
    fin2_kernel<<<1, 128, 0, stream>>>(g2, be2);
    bn2_kernel<<<2048, 256, 0, stream>>>();

    // block 3 (MFMA): 64->128, 16^3 -> 8^3, K=4096 split 16
    mask3_kernel<<<4, 256, 0, stream>>>();
    conv3_kernel<<<dim3(16, 1, 16), 256, 0, stream>>>();
    post3_kernel<<<512, 256, 0, stream>>>(b3);
    fin3_kernel<<<1, 128, 0, stream>>>(g3, be3);
    bn3_kernel<<<512, 256, 0, stream>>>();

    // up block 1 (MFMA): 128->128, 8^3 -> 16^3, parity 8 x split 4
    mask4_kernel<<<32, 256, 0, stream>>>();
    conv4_kernel<<<dim3(8, 1, 32), 256, 0, stream>>>();
    post4_kernel<<<4096, 256, 0, stream>>>(tb1);
    fin4_kernel<<<1, 128, 0, stream>>>(tg1, tbe1);
    bn4_kernel<<<4096, 256, 0, stream>>>();

    // up block 2 (MFMA): 128->64, 16^3 -> 32^3, parity 8, direct store
    mask5_kernel<<<256, 256, 0, stream>>>();
    conv5_kernel<<<dim3(64, 1, 8), 256, 0, stream>>>();
    post5_kernel<<<16384, 256, 0, stream>>>(tb2);
    fin5_kernel<<<1, 128, 0, stream>>>(tg2, tbe2);
    bn5_kernel<<<16384, 256, 0, stream>>>();

    // final dense 1x1x1 conv 64->32 @ 32^3 (fp32)
    final_kernel<<<dim3(1024, 1), 256, 0, stream>>>(fw, fb, (float*)d_out);
}

// Round 8
// 350.885 us; speedup vs baseline: 2.8317x; 1.3578x over previous
//
#include <hip/hip_runtime.h>
#include <hip/hip_bf16.h>

#define DEV static __device__ __forceinline__

typedef unsigned short ushort;
typedef __attribute__((ext_vector_type(8))) short short8;
typedef __attribute__((ext_vector_type(8))) ushort ushort8;
typedef __attribute__((ext_vector_type(4))) float accv;

DEV ushort f2bf(float f) {
    __hip_bfloat16 h = __float2bfloat16(f);   // RNE
    return reinterpret_cast<ushort&>(h);
}

// ---------------------------------------------------------------------------
// Static device workspace
// ---------------------------------------------------------------------------
__device__ float    g_stats[2576];                    // per-layer scale/shift etc.
__device__ float    g_sred[5 * 128 * 32];             // padded reduction: [l][co][32]
                                                      // [0]=sum [1]=sumsq [2]=maskcnt
__device__ float    g_y1[2097152];                    // (2,32,32^3) fp32 NCV
__device__ __align__(16) ushort g_y1b[2097152];       // (2,32^3,32) bf16 VC
__device__ float    g_m1[65536];
__device__ float    g_y2[524288];
__device__ __align__(16) ushort g_y2b[524288];        // (2,16^3,64) bf16 VC
__device__ float    g_m2[8192];
__device__ float    g_y3[131072];
__device__ __align__(16) ushort g_y3b[131072];        // (2,8^3,128) bf16 VC
__device__ float    g_m3[1024];
__device__ float    g_t1[1048576];
__device__ __align__(16) ushort g_t1b[1048576];       // (2,16^3,128) bf16 VC
__device__ float    g_mt1[8192];
__device__ float    g_mt2[65536];
__device__ float    g_t2[4194304];                    // conv5 out fp32 NCV
// split-K partial buffers
__device__ float    g_p2[2097152];                    // 4 x 524288
__device__ float    g_p3[2097152];                    // 16 x 131072
__device__ float    g_p4[4194304];                    // 4 x 1048576
// K-major bf16 weights
__device__ __align__(16) ushort g_wb2[131072];
__device__ __align__(16) ushort g_wb3[524288];
__device__ __align__(16) ushort g_wb4[1048576];
__device__ __align__(16) ushort g_wb5[524288];

// ---------------------------------------------------------------------------
__global__ __launch_bounds__(256)
void zero_red_kernel() {                               // grid 80
    int idx = blockIdx.x * 256 + threadIdx.x;
    if (idx < 20480) g_sred[idx] = 0.f;
    if (idx < 2576)  g_stats[idx] = 0.f;
}

// ---------------------------------------------------------------------------
// weight pre-transpose: K-major bf16 (verified round-7)
// ---------------------------------------------------------------------------
template<int CIN, int COUT>
DEV void prep_down(const float* w, ushort* wb) {
    int idx = blockIdx.x * 256 + threadIdx.x;
    int co = idx / (CIN * 64), r = idx % (CIN * 64);
    int ci = r >> 6, tap = r & 63;
    wb[(size_t)co * (CIN * 64) + tap * CIN + ci] = f2bf(w[idx]);
}
template<int CIN, int COUT>
DEV void prep_up(const float* w, ushort* wb) {
    int idx = blockIdx.x * 256 + threadIdx.x;
    int co = idx / (CIN * 64), r = idx % (CIN * 64);
    int ci = r >> 6, t64 = r & 63;
    int kd = t64 >> 4, kh = (t64 >> 2) & 3, kw = t64 & 3;
    int pd = (3 - kd) & 1, td = (3 - kd) >> 1;
    int ph = (3 - kh) & 1, th = (3 - kh) >> 1;
    int pw = (3 - kw) & 1, tw = (3 - kw) >> 1;
    int parity = pd * 4 + ph * 2 + pw, t = td * 4 + th * 2 + tw;
    wb[(((size_t)parity * COUT + co) * 8 + t) * CIN + ci] = f2bf(w[idx]);
}

__global__ __launch_bounds__(256) void prep2_kernel(const float* w) { prep_down<32, 64>(w, g_wb2); }
__global__ __launch_bounds__(256) void prep3_kernel(const float* w) { prep_down<64, 128>(w, g_wb3); }
__global__ __launch_bounds__(256) void prep4_kernel(const float* w) { prep_up<128, 128>(w, g_wb4); }
__global__ __launch_bounds__(256) void prep5_kernel(const float* w) { prep_up<128, 64>(w, g_wb5); }

// ---------------------------------------------------------------------------
// mask dilation kernels — no atomics (counts come from post/stats passes)
// ---------------------------------------------------------------------------
DEV void mask_down_body(const float* mprev, float* mout, int logDin, int logDo) {
    int Din = 1 << logDin, Do = 1 << logDo;
    int idx = blockIdx.x * 256 + threadIdx.x;
    int b = idx >> (3 * logDo), v = idx & ((1 << (3 * logDo)) - 1);
    int od = v >> (2 * logDo), rem = v & ((1 << (2 * logDo)) - 1);
    int oh = rem >> logDo, ow = rem & (Do - 1);
    const float* mp = mprev + ((size_t)b << (3 * logDin));
    float acc = 0.f;
    for (int kd = 0; kd < 4; kd++) {
        int id = 2 * od - 1 + kd;
        if ((unsigned)id >= (unsigned)Din) continue;
        for (int kh = 0; kh < 4; kh++) {
            int ih = 2 * oh - 1 + kh;
            if ((unsigned)ih >= (unsigned)Din) continue;
            const float* row = mp + ((size_t)id * Din + ih) * Din;
            for (int kw = 0; kw < 4; kw++) {
                int iw = 2 * ow - 1 + kw;
                if ((unsigned)iw < (unsigned)Din) acc += row[iw];
            }
        }
    }
    mout[idx] = acc > 0.f ? 1.f : 0.f;
}

DEV void mask_up_body(const float* mprev, float* mout, int logDin, int logDo) {
    int Din = 1 << logDin, Do = 1 << logDo;
    int idx = blockIdx.x * 256 + threadIdx.x;
    int b = idx >> (3 * logDo), v = idx & ((1 << (3 * logDo)) - 1);
    int od = v >> (2 * logDo), rem = v & ((1 << (2 * logDo)) - 1);
    int oh = rem >> logDo, ow = rem & (Do - 1);
    const float* mp = mprev + ((size_t)b << (3 * logDin));
    float acc = 0.f;
    for (int kd = 0; kd < 4; kd++) {
        int u = od + kd - 2; if (u < 0 || (u & 1)) continue;
        int id = u >> 1; if (id >= Din) continue;
        for (int kh = 0; kh < 4; kh++) {
            int uh = oh + kh - 2; if (uh < 0 || (uh & 1)) continue;
            int ih = uh >> 1; if (ih >= Din) continue;
            const float* row = mp + ((size_t)id * Din + ih) * Din;
            for (int kw = 0; kw < 4; kw++) {
                int uw = ow + kw - 2; if (uw < 0 || (uw & 1)) continue;
                int iw = uw >> 1; if (iw >= Din) continue;
                acc += row[iw];
            }
        }
    }
    mout[idx] = acc > 0.f ? 1.f : 0.f;
}

__global__ __launch_bounds__(256)
void mask1_kernel(const float* __restrict__ mask) {
    int idx = blockIdx.x * 256 + threadIdx.x;
    int b = idx >> 15, v = idx & 0x7FFF;
    int od = v >> 10, rem = v & 1023;
    int oh = rem >> 5, ow = rem & 31;
    const float* mp = mask + ((size_t)b << 18);
    float acc = 0.f;
    for (int kd = 0; kd < 4; kd++) {
        int id = 2 * od - 1 + kd;
        if ((unsigned)id >= 64u) continue;
        for (int kh = 0; kh < 4; kh++) {
            int ih = 2 * oh - 1 + kh;
            if ((unsigned)ih >= 64u) continue;
            const float* row = mp + ((size_t)id * 64 + ih) * 64;
            for (int kw = 0; kw < 4; kw++) {
                int iw = 2 * ow - 1 + kw;
                if ((unsigned)iw < 64u && row[iw] > 0.5f) acc += 1.f;
            }
        }
    }
    g_m1[idx] = acc > 0.f ? 1.f : 0.f;
}

__global__ __launch_bounds__(256) void mask2_kernel() { mask_down_body(g_m1, g_m2, 5, 4); }
__global__ __launch_bounds__(256) void mask3_kernel() { mask_down_body(g_m2, g_m3, 4, 3); }
__global__ __launch_bounds__(256) void mask4_kernel() { mask_up_body(g_m3, g_mt1, 3, 4); }
__global__ __launch_bounds__(256) void mask5_kernel() { mask_up_body(g_mt1, g_mt2, 4, 5); }

// ---------------------------------------------------------------------------
// bf16 MFMA implicit-GEMM (verified round-7)
// ---------------------------------------------------------------------------
template<int MODE, int MT, int NT, int CIN, int COUT, int LOGDI, int LOGDO, int SPLITK>
DEV void mfma_gemm_body(const ushort* __restrict__ xb, const ushort* __restrict__ wb,
                        float* __restrict__ y) {
    constexpr int KT = 32;
    constexpr int K  = (MODE == 1) ? CIN * 8 : CIN * 64;
    constexpr int KSEG = K / SPLITK;
    constexpr int LDA = 40;
    constexpr int MTW = MT / 32, NTW = NT / 32;
    constexpr int AR = MT * 4 / 256, BR = NT * 4 / 256;
    constexpr int LCIN = (CIN == 32) ? 5 : ((CIN == 64) ? 6 : 7);
    constexpr int Din = 1 << LOGDI, Do = 1 << LOGDO;
    constexpr int DvoxI = 1 << (3 * LOGDI), DvoxO = 1 << (3 * LOGDO);

    __shared__ __align__(16) ushort As[MT * LDA];
    __shared__ __align__(16) ushort Bs[NT * LDA];

    const int tid = threadIdx.x;
    const int bx = blockIdx.x;
    int pd = 0, ph = 0, pw = 0, ks = 0;
    const ushort* wp = wb;
    if constexpr (MODE == 1) {
        int z = blockIdx.z;
        pd = (z >> 2) & 1; ph = (z >> 1) & 1; pw = z & 1; ks = z >> 3;
        wp = wb + (size_t)(z & 7) * COUT * CIN * 8;
    } else {
        ks = blockIdx.z;
    }

    const int wv = tid >> 6, lane = tid & 63;
    const int mw = wv & 1, nw = wv >> 1;
    const int lr = lane & 15, quad = lane >> 4;

    accv acc[MTW][NTW];
#pragma unroll
    for (int mt = 0; mt < MTW; mt++)
#pragma unroll
        for (int nt = 0; nt < NTW; nt++) acc[mt][nt] = (accv){0.f, 0.f, 0.f, 0.f};

    const int kbeg = ks * KSEG, kend = kbeg + KSEG;
    for (int kt = kbeg; kt < kend; kt += KT) {
        __syncthreads();
#pragma unroll
        for (int r = 0; r < AR; r++) {
            int slot = r * 256 + tid;
            int m = slot >> 2, oct = slot & 3;
            int kg0 = kt + oct * 8;
            *(ushort8*)&As[m * LDA + oct * 8] =
                *(const ushort8*)&wp[(size_t)m * K + kg0];
        }
#pragma unroll
        for (int r = 0; r < BR; r++) {
            int slot = r * 256 + tid;
            int n = slot >> 2, oct = slot & 3;
            int vg = bx * NT + n;
            int kg0 = kt + oct * 8;
            int tap = kg0 >> LCIN, ci0 = kg0 & (CIN - 1);
            ushort8 v = (ushort8){0, 0, 0, 0, 0, 0, 0, 0};
            int b, id, ih, iw;
            if constexpr (MODE == 0) {
                b = vg >> (3 * LOGDO);
                int vv = vg & (DvoxO - 1);
                int od = vv >> (2 * LOGDO), oh = (vv >> LOGDO) & (Do - 1), ow = vv & (Do - 1);
                id = 2 * od - 1 + (tap >> 4);
                ih = 2 * oh - 1 + ((tap >> 2) & 3);
                iw = 2 * ow - 1 + (tap & 3);
            } else {
                b = vg >> (3 * LOGDI);
                int vv = vg & (DvoxI - 1);
                int odp = vv >> (2 * LOGDI), ohp = (vv >> LOGDI) & (Din - 1), owp = vv & (Din - 1);
                id = odp + pd + ((tap >> 2) & 1) - 1;
                ih = ohp + ph + ((tap >> 1) & 1) - 1;
                iw = owp + pw + (tap & 1) - 1;
            }
            if ((unsigned)id < (unsigned)Din && (unsigned)ih < (unsigned)Din &&
                (unsigned)iw < (unsigned)Din)
                v = *(const ushort8*)&xb[((size_t)b * DvoxI +
                                          (id << (2 * LOGDI)) + (ih << LOGDI) + iw) * CIN + ci0];
            *(ushort8*)&Bs[n * LDA + oct * 8] = v;
        }
        __syncthreads();
        short8 af[MTW], bfr[NTW];
#pragma unroll
        for (int mt = 0; mt < MTW; mt++)
            af[mt] = *(const short8*)&As[((mw * MTW + mt) * 16 + lr) * LDA + quad * 8];
#pragma unroll
        for (int nt = 0; nt < NTW; nt++)
            bfr[nt] = *(const short8*)&Bs[((nw * NTW + nt) * 16 + lr) * LDA + quad * 8];
#pragma unroll
        for (int mt = 0; mt < MTW; mt++)
#pragma unroll
            for (int nt = 0; nt < NTW; nt++)
                acc[mt][nt] = __builtin_amdgcn_mfma_f32_16x16x32_bf16(
                    af[mt], bfr[nt], acc[mt][nt], 0, 0, 0);
    }

    float* yp = y + (size_t)ks * (2 * COUT * DvoxO);
#pragma unroll
    for (int mt = 0; mt < MTW; mt++) {
#pragma unroll
        for (int nt = 0; nt < NTW; nt++) {
#pragma unroll
            for (int r = 0; r < 4; r++) {
                int co = (mw * MTW + mt) * 16 + quad * 4 + r;
                int vg = bx * NT + (nw * NTW + nt) * 16 + lr;
                size_t idx;
                if constexpr (MODE == 1) {
                    int b = vg >> (3 * LOGDI);
                    int vv = vg & (DvoxI - 1);
                    int odp = vv >> (2 * LOGDI), ohp = (vv >> LOGDI) & (Din - 1), owp = vv & (Din - 1);
                    int od = 2 * odp + pd, oh = 2 * ohp + ph, ow = 2 * owp + pw;
                    idx = (((size_t)(b * COUT + co)) << (3 * LOGDO)) +
                          (od << (2 * LOGDO)) + (oh << LOGDO) + ow;
                } else {
                    int b = vg >> (3 * LOGDO);
                    int off = vg & (DvoxO - 1);
                    idx = (((size_t)(b * COUT + co)) << (3 * LOGDO)) + off;
                }
                yp[idx] = acc[mt][nt][r];
            }
        }
    }
}

__global__ __launch_bounds__(256)
void conv2_kernel() { mfma_gemm_body<0, 64, 128, 32, 64, 5, 4, 4>(g_y1b, g_wb2, g_p2); }
__global__ __launch_bounds__(256)
void conv3_kernel() { mfma_gemm_body<0, 128, 64, 64, 128, 4, 3, 16>(g_y2b, g_wb3, g_p3); }
__global__ __launch_bounds__(256)
void conv4_kernel() { mfma_gemm_body<1, 128, 128, 128, 128, 3, 4, 4>(g_y3b, g_wb4, g_p4); }
__global__ __launch_bounds__(256)
void conv5_kernel() { mfma_gemm_body<1, 64, 128, 128, 64, 4, 5, 1>(g_t1b, g_wb5, g_t2); }

// ---------------------------------------------------------------------------
// fp32 implicit-GEMM: MODE 3 = conv1 (fused prep, NO stats),
//                     MODE 2 = final 1x1x1 with fused BN on load
// ---------------------------------------------------------------------------
template<int MODE, int MT, int NT, int CIN, int COUT, int LOGDI, int LOGDO>
DEV void gemm_body(const float* __restrict__ x, const float* __restrict__ rawm,
                   const float* __restrict__ w, const float* __restrict__ bias,
                   const float* __restrict__ m2, float* __restrict__ y) {
    constexpr int KT = 32;
    constexpr int K  = (MODE == 2) ? CIN : CIN * 64;
    constexpr int MR = MT / 16, VR = NT / 16;
    constexpr int EA = KT * MT / 256, EB = KT * NT / 256;
    constexpr int LMT = (MT == 64) ? 6 : 5, LNT = (NT == 64) ? 6 : 5;
    constexpr int Din = 1 << LOGDI, Do = 1 << LOGDO;

    __shared__ float As[KT * MT];
    __shared__ float Bs[KT * NT];

    const int tid = threadIdx.x, tc = tid & 15, tv = tid >> 4;
    const int bx = blockIdx.x, by = blockIdx.y;

    float acc[MR][VR];
#pragma unroll
    for (int r = 0; r < MR; r++)
#pragma unroll
        for (int c = 0; c < VR; c++) acc[r][c] = 0.f;

    for (int kt = 0; kt < K; kt += KT) {
        __syncthreads();
#pragma unroll
        for (int e = 0; e < EA; e++) {
            int j = tid * EA + e;
            int kk = j >> LMT, m = j & (MT - 1);
            int kg = kt + kk;
            int co = by * MT + m;
            float val;
            if constexpr (MODE == 2) val = w[co * CIN + kg];
            else val = w[(size_t)co * (CIN * 64) + kg];
            As[kk * MT + m] = val;
        }
#pragma unroll
        for (int e = 0; e < EB; e++) {
            int j = tid * EB + e;
            int kk = j >> LNT, n = j & (NT - 1);
            int kg = kt + kk;
            int vg = bx * NT + n;
            float val = 0.f;
            if constexpr (MODE == 2) {
                int b = vg >> 15, v = vg & 32767;
                float raw = x[(((size_t)(b * CIN + kg)) << 15) + v];
                float mv = g_mt2[((size_t)b << 15) + v];
                val = (raw * g_stats[2048 + 256 + kg] + g_stats[2048 + 384 + kg]) * mv;
            } else {
                int b = vg >> (3 * LOGDO), v = vg & ((1 << (3 * LOGDO)) - 1);
                int od = v >> (2 * LOGDO), oh = (v >> LOGDO) & (Do - 1), ow = v & (Do - 1);
                int ci = kg >> 6;
                int id = 2 * od - 1 + ((kg >> 4) & 3);
                int ih = 2 * oh - 1 + ((kg >> 2) & 3);
                int iw = 2 * ow - 1 + (kg & 3);
                if ((unsigned)id < (unsigned)Din && (unsigned)ih < (unsigned)Din &&
                    (unsigned)iw < (unsigned)Din) {
                    int off = (id << (2 * LOGDI)) + (ih << LOGDI) + iw;
                    if (rawm[((size_t)b << (3 * LOGDI)) + off] > 0.5f)
                        val = x[(((size_t)(b * CIN + ci)) << (3 * LOGDI)) + off];
                }
            }
            Bs[kk * NT + n] = val;
        }
        __syncthreads();
#pragma unroll
        for (int kk = 0; kk < KT; kk++) {
            float a[MR], bb[VR];
            if constexpr (MR == 4) {
                float4 t4 = *(const float4*)&As[kk * MT + tc * 4];
                a[0] = t4.x; a[1] = t4.y; a[2] = t4.z; a[3] = t4.w;
            } else {
                float2 t2 = *(const float2*)&As[kk * MT + tc * 2];
                a[0] = t2.x; a[1] = t2.y;
            }
            if constexpr (VR == 4) {
                float4 t4 = *(const float4*)&Bs[kk * NT + tv * 4];
                bb[0] = t4.x; bb[1] = t4.y; bb[2] = t4.z; bb[3] = t4.w;
            } else {
                float2 t2 = *(const float2*)&Bs[kk * NT + tv * 2];
                bb[0] = t2.x; bb[1] = t2.y;
            }
#pragma unroll
            for (int r = 0; r < MR; r++)
#pragma unroll
                for (int c = 0; c < VR; c++) acc[r][c] = fmaf(a[r], bb[c], acc[r][c]);
        }
    }

    if constexpr (MODE == 2) {
#pragma unroll
        for (int r = 0; r < MR; r++) {
            int co = by * MT + tc * MR + r;
            float bv = bias[co];
#pragma unroll
            for (int c = 0; c < VR; c++) {
                int vg = bx * NT + tv * VR + c;
                int b = vg >> 15, v = vg & 32767;
                y[(((size_t)(b * COUT + co)) << 15) + v] = acc[r][c] + bv;
            }
        }
    } else {
#pragma unroll
        for (int r = 0; r < MR; r++) {
            int co = by * MT + tc * MR + r;
            float bv = bias[co];
#pragma unroll
            for (int c = 0; c < VR; c++) {
                int vg = bx * NT + tv * VR + c;
                int b = vg >> (3 * LOGDO), off = vg & ((1 << (3 * LOGDO)) - 1);
                float mv = m2[((size_t)b << (3 * LOGDO)) + off];
                float yv = (acc[r][c] + bv) * mv;
                yv = yv >= 0.f ? yv : 0.01f * yv;
                y[(((size_t)(b * COUT + co)) << (3 * LOGDO)) + off] = yv;
            }
        }
    }
}

__global__ __launch_bounds__(256)
void conv1_kernel(const float* feat, const float* mask, const float* w, const float* b)
{ gemm_body<3, 32, 64, 4, 32, 6, 5>(feat, mask, w, b, g_m1, g_y1); }

__global__ __launch_bounds__(256)
void final_kernel(const float* fw, const float* fb, float* out)
{ gemm_body<2, 32, 64, 64, 32, 5, 5>(g_t2, nullptr, fw, fb, nullptr, out); }

// ---------------------------------------------------------------------------
// wave+block reduce helper: 3 atomics per block to padded sred lines
// ---------------------------------------------------------------------------
DEV void red3_and_atomic(float s, float s2, float sm, float* sred, int co) {
#pragma unroll
    for (int off = 32; off; off >>= 1) {
        s  += __shfl_down(s, off, 64);
        s2 += __shfl_down(s2, off, 64);
        sm += __shfl_down(sm, off, 64);
    }
    __shared__ float red[12];
    int lane = threadIdx.x & 63, wvi = threadIdx.x >> 6;
    if (!lane) { red[wvi] = s; red[4 + wvi] = s2; red[8 + wvi] = sm; }
    __syncthreads();
    if (!threadIdx.x) {
        atomicAdd(&sred[co * 32 + 0], red[0] + red[1] + red[2] + red[3]);
        atomicAdd(&sred[co * 32 + 1], red[4] + red[5] + red[6] + red[7]);
        atomicAdd(&sred[co * 32 + 2], red[8] + red[9] + red[10] + red[11]);
    }
}

// ---------------------------------------------------------------------------
// post: grid-stride sum of SPLITK partials + bias + mask + LeakyReLU + stats.
// Each block covers ITERS*256 consecutive elements (one (b,co) chunk).
// ---------------------------------------------------------------------------
template<int COUT, int LOGDO, int SPLITK, int ITERS>
DEV void post_body(const float* __restrict__ bias, const float* __restrict__ m2,
                   const float* p, float* y, float* sred) {
    constexpr int Dvox = 1 << (3 * LOGDO);
    constexpr size_t STR = (size_t)2 * COUT * Dvox;
    constexpr int LOGC = (COUT == 128) ? 7 : ((COUT == 64) ? 6 : 5);
    int base = blockIdx.x * (ITERS * 256);
    int co = (base >> (3 * LOGDO)) & (COUT - 1);
    float s = 0.f, s2 = 0.f, sm = 0.f;
#pragma unroll
    for (int it = 0; it < ITERS; it++) {
        int idx = base + it * 256 + threadIdx.x;
        int v = idx & (Dvox - 1);
        int b = idx >> (3 * LOGDO + LOGC);
        float sum = 0.f;
#pragma unroll
        for (int k = 0; k < SPLITK; k++) sum += p[k * STR + idx];
        float mv = m2[((size_t)b << (3 * LOGDO)) + v];
        float yv = (sum + bias[co]) * mv;
        yv = yv >= 0.f ? yv : 0.01f * yv;
        y[idx] = yv;
        s += yv; s2 += yv * yv; sm += mv;
    }
    red3_and_atomic(s, s2, sm, sred, co);
}

__global__ __launch_bounds__(256) void post2_kernel(const float* b) { post_body<64, 4, 4, 1>(b, g_m2, g_p2, g_y2, g_sred + 4096); }
__global__ __launch_bounds__(256) void post3_kernel(const float* b) { post_body<128, 3, 16, 1>(b, g_m3, g_p3, g_y3, g_sred + 8192); }
__global__ __launch_bounds__(256) void post4_kernel(const float* b) { post_body<128, 4, 4, 2>(b, g_mt1, g_p4, g_t1, g_sred + 12288); }
__global__ __launch_bounds__(256) void post5_kernel(const float* b) { post_body<64, 5, 1, 8>(b, g_mt2, g_t2, g_t2, g_sred + 16384); }

// stats pass over y1 (already bias/mask/leaky applied by conv1)
__global__ __launch_bounds__(256)
void stats1_kernel() {                                 // grid 2048, 4 iters
    int base = blockIdx.x * 1024;
    int co = (base >> 15) & 31;
    float s = 0.f, s2 = 0.f, sm = 0.f;
#pragma unroll
    for (int it = 0; it < 4; it++) {
        int idx = base + it * 256 + threadIdx.x;
        int v = idx & 32767;
        int b = idx >> 20;
        float yv = g_y1[idx];
        float mv = g_m1[((size_t)b << 15) + v];
        s += yv; s2 += yv * yv; sm += mv;
    }
    red3_and_atomic(s, s2, sm, g_sred, co);
}

// ---------------------------------------------------------------------------
// stats finalize + BN apply
// ---------------------------------------------------------------------------
DEV void finalize_body(float* stats, const float* sred,
                       const float* g, const float* be, int C) {
    int c = threadIdx.x;
    if (c >= C) return;
    float n = fmaxf(sred[c * 32 + 2], 1.f);
    float mean = sred[c * 32] / n;
    float var = fmaxf(sred[c * 32 + 1] / n - mean * mean, 0.f);
    float rstd = rsqrtf(var + 1e-5f);
    float sc = g[c] * rstd;
    stats[256 + c] = sc;
    stats[384 + c] = be[c] - mean * sc;
}

__global__ void fin1_kernel(const float* g, const float* be) { finalize_body(g_stats + 0,    g_sred + 0,     g, be, 32); }
__global__ void fin2_kernel(const float* g, const float* be) { finalize_body(g_stats + 512,  g_sred + 4096,  g, be, 64); }
__global__ void fin3_kernel(const float* g, const float* be) { finalize_body(g_stats + 1024, g_sred + 8192,  g, be, 128); }
__global__ void fin4_kernel(const float* g, const float* be) { finalize_body(g_stats + 1536, g_sred + 12288, g, be, 128); }
__global__ void fin5_kernel(const float* g, const float* be) { finalize_body(g_stats + 2048, g_sred + 16384, g, be, 64); }

// BN apply fp32 NCV -> bf16 channel-last [b][vox][c]
DEV void bn_cl_body(const float* y, ushort* out, const float* stats,
                    const float* m2, int logC, int logDvox) {
    int idx = blockIdx.x * 256 + threadIdx.x;
    int c = idx & ((1 << logC) - 1);
    int vox = (idx >> logC) & ((1 << logDvox) - 1);
    int b = idx >> (logC + logDvox);
    float mv = m2[((size_t)b << logDvox) + vox];
    float val = y[(((size_t)(b << logC) + c) << logDvox) + vox];
    out[idx] = f2bf((val * stats[256 + c] + stats[384 + c]) * mv);
}

__global__ __launch_bounds__(256) void bn1_kernel() { bn_cl_body(g_y1, g_y1b, g_stats + 0,    g_m1, 5, 15); }
__global__ __launch_bounds__(256) void bn2_kernel() { bn_cl_body(g_y2, g_y2b, g_stats + 512,  g_m2, 6, 12); }
__global__ __launch_bounds__(256) void bn3_kernel() { bn_cl_body(g_y3, g_y3b, g_stats + 1024, g_m3, 7, 9); }
__global__ __launch_bounds__(256) void bn4_kernel() { bn_cl_body(g_t1, g_t1b, g_stats + 1536, g_mt1, 7, 12); }

// ---------------------------------------------------------------------------

extern "C" void kernel_launch(void* const* d_in, const int* in_sizes, int n_in,
                              void* d_out, int out_size, void* d_ws, size_t ws_size,
                              hipStream_t stream) {
    (void)in_sizes; (void)n_in; (void)out_size; (void)d_ws; (void)ws_size;
    const float* feat = (const float*)d_in[0];
    const float* mask = (const float*)d_in[1];
    const float* w1  = (const float*)d_in[2];
    const float* b1  = (const float*)d_in[3];
    const float* g1  = (const float*)d_in[4];
    const float* be1 = (const float*)d_in[5];
    const float* w2  = (const float*)d_in[6];
    const float* b2  = (const float*)d_in[7];
    const float* g2  = (const float*)d_in[8];
    const float* be2 = (const float*)d_in[9];
    const float* w3  = (const float*)d_in[10];
    const float* b3  = (const float*)d_in[11];
    const float* g3  = (const float*)d_in[12];
    const float* be3 = (const float*)d_in[13];
    const float* tw1 = (const float*)d_in[14];
    const float* tb1 = (const float*)d_in[15];
    const float* tg1 = (const float*)d_in[16];
    const float* tbe1= (const float*)d_in[17];
    const float* tw2 = (const float*)d_in[18];
    const float* tb2 = (const float*)d_in[19];
    const float* tg2 = (const float*)d_in[20];
    const float* tbe2= (const float*)d_in[21];
    const float* fw  = (const float*)d_in[22];
    const float* fb  = (const float*)d_in[23];

    zero_red_kernel<<<80, 256, 0, stream>>>();
    prep2_kernel<<<512, 256, 0, stream>>>(w2);
    prep3_kernel<<<2048, 256, 0, stream>>>(w3);
    prep4_kernel<<<4096, 256, 0, stream>>>(tw1);
    prep5_kernel<<<2048, 256, 0, stream>>>(tw2);

    // block 1 (fp32): 4->32, 64^3 -> 32^3
    mask1_kernel<<<256, 256, 0, stream>>>(mask);
    conv1_kernel<<<dim3(1024, 1), 256, 0, stream>>>(feat, mask, w1, b1);
    stats1_kernel<<<2048, 256, 0, stream>>>();
    fin1_kernel<<<1, 128, 0, stream>>>(g1, be1);
    bn1_kernel<<<8192, 256, 0, stream>>>();

    // block 2 (MFMA): 32->64, 32^3 -> 16^3, K=2048 split 4
    mask2_kernel<<<32, 256, 0, stream>>>();
    conv2_kernel<<<dim3(64, 1, 4), 256, 0, stream>>>();
    post2_kernel<<<2048, 256, 0, stream>>>(b2);
    fin2_kernel<<<1, 128, 0, stream>>>(g2, be2);
    bn2_kernel<<<2048, 256, 0, stream>>>();

    // block 3 (MFMA): 64->128, 16^3 -> 8^3, K=4096 split 16
    mask3_kernel<<<4, 256, 0, stream>>>();
    conv3_kernel<<<dim3(16, 1, 16), 256, 0, stream>>>();
    post3_kernel<<<512, 256, 0, stream>>>(b3);
    fin3_kernel<<<1, 128, 0, stream>>>(g3, be3);
    bn3_kernel<<<512, 256, 0, stream>>>();

    // up block 1 (MFMA): 128->128, 8^3 -> 16^3, parity 8 x split 4
    mask4_kernel<<<32, 256, 0, stream>>>();
    conv4_kernel<<<dim3(8, 1, 32), 256, 0, stream>>>();
    post4_kernel<<<2048, 256, 0, stream>>>(tb1);
    fin4_kernel<<<1, 128, 0, stream>>>(tg1, tbe1);
    bn4_kernel<<<4096, 256, 0, stream>>>();

    // up block 2 (MFMA): 128->64, 16^3 -> 32^3, parity 8
    mask5_kernel<<<256, 256, 0, stream>>>();
    conv5_kernel<<<dim3(64, 1, 8), 256, 0, stream>>>();
    post5_kernel<<<2048, 256, 0, stream>>>(tb2);
    fin5_kernel<<<1, 128, 0, stream>>>(tg2, tbe2);

    // final dense 1x1x1 conv 64->32 @ 32^3 (fp32, fused BN on load)
    final_kernel<<<dim3(1024, 1), 256, 0, stream>>>(fw, fb, (float*)d_out);
}

// Round 9
// 336.585 us; speedup vs baseline: 2.9520x; 1.0425x over previous
//
#include <hip/hip_runtime.h>
#include <hip/hip_bf16.h>

#define DEV static __device__ __forceinline__

typedef unsigned short ushort;
typedef __attribute__((ext_vector_type(8))) short short8;
typedef __attribute__((ext_vector_type(8))) ushort ushort8;
typedef __attribute__((ext_vector_type(4))) float accv;

DEV ushort f2bf(float f) {
    __hip_bfloat16 h = __float2bfloat16(f);   // RNE
    return reinterpret_cast<ushort&>(h);
}

// ---------------------------------------------------------------------------
// Static device workspace
// ---------------------------------------------------------------------------
__device__ float    g_sred[5 * 128 * 32];             // [l][co][32]: 0=sum 1=sumsq 2=maskcnt
__device__ float    g_y1[2097152];                    // (2,32,32^3) fp32 NCV
__device__ __align__(16) ushort g_y1b[2097152];       // (2,32^3,32) bf16 VC
__device__ float    g_m1[65536];
__device__ float    g_y2[524288];
__device__ __align__(16) ushort g_y2b[524288];        // (2,16^3,64) bf16 VC
__device__ float    g_m2[8192];
__device__ float    g_y3[131072];
__device__ __align__(16) ushort g_y3b[131072];        // (2,8^3,128) bf16 VC
__device__ float    g_m3[1024];
__device__ float    g_t1[1048576];
__device__ __align__(16) ushort g_t1b[1048576];       // (2,16^3,128) bf16 VC
__device__ float    g_mt1[8192];
__device__ float    g_mt2[65536];
__device__ float    g_t2[4194304];                    // x0 early; conv5 out late
// split-K partial buffers
__device__ float    g_p2[2097152];
__device__ float    g_p3[2097152];
__device__ float    g_p4[4194304];
// K-major weights
__device__ __align__(16) ushort g_wb2[131072];
__device__ __align__(16) ushort g_wb3[524288];
__device__ __align__(16) ushort g_wb4[1048576];
__device__ __align__(16) ushort g_wb5[524288];
__device__ float    g_w1t[8192];                      // [k=256][co=32] fp32
__device__ float    g_fwt[2048];                      // [k=64][co=32] fp32

// ---------------------------------------------------------------------------
// setup: zero sred + transpose w1/fw to K-major fp32. grid 96.
// ---------------------------------------------------------------------------
__global__ __launch_bounds__(256)
void setup_kernel(const float* __restrict__ w1, const float* __restrict__ fw) {
    int idx = blockIdx.x * 256 + threadIdx.x;
    if (idx < 20480) g_sred[idx] = 0.f;
    if (idx < 8192) { int co = idx >> 8, kg = idx & 255; g_w1t[kg * 32 + co] = w1[idx]; }
    if (idx < 2048) { int co = idx >> 6, kg = idx & 63; g_fwt[kg * 32 + co] = fw[idx]; }
}

// prep x0 = feat * (mask>0.5), fp32 NCV, into g_t2 (dead until conv5). grid 2048.
__global__ __launch_bounds__(256)
void prep1x_kernel(const float* __restrict__ feat, const float* __restrict__ mask) {
    int idx = blockIdx.x * 256 + threadIdx.x;          // 524288
    int b = idx >> 18, v = idx & 0x3FFFF;
    float mv = mask[idx] > 0.5f ? 1.f : 0.f;
#pragma unroll
    for (int c = 0; c < 4; c++) {
        int o = ((b * 4 + c) << 18) + v;
        g_t2[o] = feat[o] * mv;
    }
}

// ---------------------------------------------------------------------------
// weight pre-transpose for MFMA convs: K-major bf16 (verified round-7)
// ---------------------------------------------------------------------------
template<int CIN, int COUT>
DEV void prep_down(const float* w, ushort* wb) {
    int idx = blockIdx.x * 256 + threadIdx.x;
    int co = idx / (CIN * 64), r = idx % (CIN * 64);
    int ci = r >> 6, tap = r & 63;
    wb[(size_t)co * (CIN * 64) + tap * CIN + ci] = f2bf(w[idx]);
}
template<int CIN, int COUT>
DEV void prep_up(const float* w, ushort* wb) {
    int idx = blockIdx.x * 256 + threadIdx.x;
    int co = idx / (CIN * 64), r = idx % (CIN * 64);
    int ci = r >> 6, t64 = r & 63;
    int kd = t64 >> 4, kh = (t64 >> 2) & 3, kw = t64 & 3;
    int pd = (3 - kd) & 1, td = (3 - kd) >> 1;
    int ph = (3 - kh) & 1, th = (3 - kh) >> 1;
    int pw = (3 - kw) & 1, tw = (3 - kw) >> 1;
    int parity = pd * 4 + ph * 2 + pw, t = td * 4 + th * 2 + tw;
    wb[(((size_t)parity * COUT + co) * 8 + t) * CIN + ci] = f2bf(w[idx]);
}

__global__ __launch_bounds__(256) void prep2_kernel(const float* w) { prep_down<32, 64>(w, g_wb2); }
__global__ __launch_bounds__(256) void prep3_kernel(const float* w) { prep_down<64, 128>(w, g_wb3); }
__global__ __launch_bounds__(256) void prep4_kernel(const float* w) { prep_up<128, 128>(w, g_wb4); }
__global__ __launch_bounds__(256) void prep5_kernel(const float* w) { prep_up<128, 64>(w, g_wb5); }

// ---------------------------------------------------------------------------
// mask dilation kernels
// ---------------------------------------------------------------------------
DEV void mask_down_body(const float* mprev, float* mout, int logDin, int logDo) {
    int Din = 1 << logDin, Do = 1 << logDo;
    int idx = blockIdx.x * 256 + threadIdx.x;
    int b = idx >> (3 * logDo), v = idx & ((1 << (3 * logDo)) - 1);
    int od = v >> (2 * logDo), rem = v & ((1 << (2 * logDo)) - 1);
    int oh = rem >> logDo, ow = rem & (Do - 1);
    const float* mp = mprev + ((size_t)b << (3 * logDin));
    float acc = 0.f;
    for (int kd = 0; kd < 4; kd++) {
        int id = 2 * od - 1 + kd;
        if ((unsigned)id >= (unsigned)Din) continue;
        for (int kh = 0; kh < 4; kh++) {
            int ih = 2 * oh - 1 + kh;
            if ((unsigned)ih >= (unsigned)Din) continue;
            const float* row = mp + ((size_t)id * Din + ih) * Din;
            for (int kw = 0; kw < 4; kw++) {
                int iw = 2 * ow - 1 + kw;
                if ((unsigned)iw < (unsigned)Din) acc += row[iw];
            }
        }
    }
    mout[idx] = acc > 0.f ? 1.f : 0.f;
}

DEV void mask_up_body(const float* mprev, float* mout, int logDin, int logDo) {
    int Din = 1 << logDin, Do = 1 << logDo;
    int idx = blockIdx.x * 256 + threadIdx.x;
    int b = idx >> (3 * logDo), v = idx & ((1 << (3 * logDo)) - 1);
    int od = v >> (2 * logDo), rem = v & ((1 << (2 * logDo)) - 1);
    int oh = rem >> logDo, ow = rem & (Do - 1);
    const float* mp = mprev + ((size_t)b << (3 * logDin));
    float acc = 0.f;
    for (int kd = 0; kd < 4; kd++) {
        int u = od + kd - 2; if (u < 0 || (u & 1)) continue;
        int id = u >> 1; if (id >= Din) continue;
        for (int kh = 0; kh < 4; kh++) {
            int uh = oh + kh - 2; if (uh < 0 || (uh & 1)) continue;
            int ih = uh >> 1; if (ih >= Din) continue;
            const float* row = mp + ((size_t)id * Din + ih) * Din;
            for (int kw = 0; kw < 4; kw++) {
                int uw = ow + kw - 2; if (uw < 0 || (uw & 1)) continue;
                int iw = uw >> 1; if (iw >= Din) continue;
                acc += row[iw];
            }
        }
    }
    mout[idx] = acc > 0.f ? 1.f : 0.f;
}

__global__ __launch_bounds__(256)
void mask1_kernel(const float* __restrict__ mask) {
    int idx = blockIdx.x * 256 + threadIdx.x;
    int b = idx >> 15, v = idx & 0x7FFF;
    int od = v >> 10, rem = v & 1023;
    int oh = rem >> 5, ow = rem & 31;
    const float* mp = mask + ((size_t)b << 18);
    float acc = 0.f;
    for (int kd = 0; kd < 4; kd++) {
        int id = 2 * od - 1 + kd;
        if ((unsigned)id >= 64u) continue;
        for (int kh = 0; kh < 4; kh++) {
            int ih = 2 * oh - 1 + kh;
            if ((unsigned)ih >= 64u) continue;
            const float* row = mp + ((size_t)id * 64 + ih) * 64;
            for (int kw = 0; kw < 4; kw++) {
                int iw = 2 * ow - 1 + kw;
                if ((unsigned)iw < 64u && row[iw] > 0.5f) acc += 1.f;
            }
        }
    }
    g_m1[idx] = acc > 0.f ? 1.f : 0.f;
}

__global__ __launch_bounds__(256) void mask2_kernel() { mask_down_body(g_m1, g_m2, 5, 4); }
__global__ __launch_bounds__(256) void mask3_kernel() { mask_down_body(g_m2, g_m3, 4, 3); }
__global__ __launch_bounds__(256) void mask4_kernel() { mask_up_body(g_m3, g_mt1, 3, 4); }
__global__ __launch_bounds__(256) void mask5_kernel() { mask_up_body(g_mt1, g_mt2, 4, 5); }

// ---------------------------------------------------------------------------
// bf16 MFMA implicit-GEMM (verified round-7/8)
// ---------------------------------------------------------------------------
template<int MODE, int MT, int NT, int CIN, int COUT, int LOGDI, int LOGDO, int SPLITK>
DEV void mfma_gemm_body(const ushort* __restrict__ xb, const ushort* __restrict__ wb,
                        float* __restrict__ y) {
    constexpr int KT = 32;
    constexpr int K  = (MODE == 1) ? CIN * 8 : CIN * 64;
    constexpr int KSEG = K / SPLITK;
    constexpr int LDA = 40;
    constexpr int MTW = MT / 32, NTW = NT / 32;
    constexpr int AR = MT * 4 / 256, BR = NT * 4 / 256;
    constexpr int LCIN = (CIN == 32) ? 5 : ((CIN == 64) ? 6 : 7);
    constexpr int Din = 1 << LOGDI, Do = 1 << LOGDO;
    constexpr int DvoxI = 1 << (3 * LOGDI), DvoxO = 1 << (3 * LOGDO);

    __shared__ __align__(16) ushort As[MT * LDA];
    __shared__ __align__(16) ushort Bs[NT * LDA];

    const int tid = threadIdx.x;
    const int bx = blockIdx.x;
    int pd = 0, ph = 0, pw = 0, ks = 0;
    const ushort* wp = wb;
    if constexpr (MODE == 1) {
        int z = blockIdx.z;
        pd = (z >> 2) & 1; ph = (z >> 1) & 1; pw = z & 1; ks = z >> 3;
        wp = wb + (size_t)(z & 7) * COUT * CIN * 8;
    } else {
        ks = blockIdx.z;
    }

    const int wv = tid >> 6, lane = tid & 63;
    const int mw = wv & 1, nw = wv >> 1;
    const int lr = lane & 15, quad = lane >> 4;

    accv acc[MTW][NTW];
#pragma unroll
    for (int mt = 0; mt < MTW; mt++)
#pragma unroll
        for (int nt = 0; nt < NTW; nt++) acc[mt][nt] = (accv){0.f, 0.f, 0.f, 0.f};

    const int kbeg = ks * KSEG, kend = kbeg + KSEG;
    for (int kt = kbeg; kt < kend; kt += KT) {
        __syncthreads();
#pragma unroll
        for (int r = 0; r < AR; r++) {
            int slot = r * 256 + tid;
            int m = slot >> 2, oct = slot & 3;
            int kg0 = kt + oct * 8;
            *(ushort8*)&As[m * LDA + oct * 8] =
                *(const ushort8*)&wp[(size_t)m * K + kg0];
        }
#pragma unroll
        for (int r = 0; r < BR; r++) {
            int slot = r * 256 + tid;
            int n = slot >> 2, oct = slot & 3;
            int vg = bx * NT + n;
            int kg0 = kt + oct * 8;
            int tap = kg0 >> LCIN, ci0 = kg0 & (CIN - 1);
            ushort8 v = (ushort8){0, 0, 0, 0, 0, 0, 0, 0};
            int b, id, ih, iw;
            if constexpr (MODE == 0) {
                b = vg >> (3 * LOGDO);
                int vv = vg & (DvoxO - 1);
                int od = vv >> (2 * LOGDO), oh = (vv >> LOGDO) & (Do - 1), ow = vv & (Do - 1);
                id = 2 * od - 1 + (tap >> 4);
                ih = 2 * oh - 1 + ((tap >> 2) & 3);
                iw = 2 * ow - 1 + (tap & 3);
            } else {
                b = vg >> (3 * LOGDI);
                int vv = vg & (DvoxI - 1);
                int odp = vv >> (2 * LOGDI), ohp = (vv >> LOGDI) & (Din - 1), owp = vv & (Din - 1);
                id = odp + pd + ((tap >> 2) & 1) - 1;
                ih = ohp + ph + ((tap >> 1) & 1) - 1;
                iw = owp + pw + (tap & 1) - 1;
            }
            if ((unsigned)id < (unsigned)Din && (unsigned)ih < (unsigned)Din &&
                (unsigned)iw < (unsigned)Din)
                v = *(const ushort8*)&xb[((size_t)b * DvoxI +
                                          (id << (2 * LOGDI)) + (ih << LOGDI) + iw) * CIN + ci0];
            *(ushort8*)&Bs[n * LDA + oct * 8] = v;
        }
        __syncthreads();
        short8 af[MTW], bfr[NTW];
#pragma unroll
        for (int mt = 0; mt < MTW; mt++)
            af[mt] = *(const short8*)&As[((mw * MTW + mt) * 16 + lr) * LDA + quad * 8];
#pragma unroll
        for (int nt = 0; nt < NTW; nt++)
            bfr[nt] = *(const short8*)&Bs[((nw * NTW + nt) * 16 + lr) * LDA + quad * 8];
#pragma unroll
        for (int mt = 0; mt < MTW; mt++)
#pragma unroll
            for (int nt = 0; nt < NTW; nt++)
                acc[mt][nt] = __builtin_amdgcn_mfma_f32_16x16x32_bf16(
                    af[mt], bfr[nt], acc[mt][nt], 0, 0, 0);
    }

    float* yp = y + (size_t)ks * (2 * COUT * DvoxO);
#pragma unroll
    for (int mt = 0; mt < MTW; mt++) {
#pragma unroll
        for (int nt = 0; nt < NTW; nt++) {
#pragma unroll
            for (int r = 0; r < 4; r++) {
                int co = (mw * MTW + mt) * 16 + quad * 4 + r;
                int vg = bx * NT + (nw * NTW + nt) * 16 + lr;
                size_t idx;
                if constexpr (MODE == 1) {
                    int b = vg >> (3 * LOGDI);
                    int vv = vg & (DvoxI - 1);
                    int odp = vv >> (2 * LOGDI), ohp = (vv >> LOGDI) & (Din - 1), owp = vv & (Din - 1);
                    int od = 2 * odp + pd, oh = 2 * ohp + ph, ow = 2 * owp + pw;
                    idx = (((size_t)(b * COUT + co)) << (3 * LOGDO)) +
                          (od << (2 * LOGDO)) + (oh << LOGDO) + ow;
                } else {
                    int b = vg >> (3 * LOGDO);
                    int off = vg & (DvoxO - 1);
                    idx = (((size_t)(b * COUT + co)) << (3 * LOGDO)) + off;
                }
                yp[idx] = acc[mt][nt][r];
            }
        }
    }
}

__global__ __launch_bounds__(256)
void conv2_kernel() { mfma_gemm_body<0, 64, 128, 32, 64, 5, 4, 4>(g_y1b, g_wb2, g_p2); }
__global__ __launch_bounds__(256)
void conv3_kernel() { mfma_gemm_body<0, 128, 64, 64, 128, 4, 3, 16>(g_y2b, g_wb3, g_p3); }
__global__ __launch_bounds__(256)
void conv4_kernel() { mfma_gemm_body<1, 128, 128, 128, 128, 3, 4, 4>(g_y3b, g_wb4, g_p4); }
__global__ __launch_bounds__(256)
void conv5_kernel() { mfma_gemm_body<1, 64, 128, 128, 64, 4, 5, 1>(g_t1b, g_wb5, g_t2); }

// ---------------------------------------------------------------------------
// conv1: fp32 implicit-GEMM, K-major weights, conflict-free staging.
// M=32 N=65536 K=256, MT=32 NT=64 KT=32. grid 1024.
// ---------------------------------------------------------------------------
__global__ __launch_bounds__(256)
void conv1_kernel(const float* __restrict__ bias) {
    const float* x0 = g_t2;
    __shared__ float As[1024];
    __shared__ float Bs[2048];
    const int tid = threadIdx.x, tc = tid & 15, tv = tid >> 4;
    const int bx = blockIdx.x;

    float acc[2][4] = {{0.f}};
    for (int kt = 0; kt < 256; kt += 32) {
        __syncthreads();
#pragma unroll
        for (int e = 0; e < 4; e++) As[e * 256 + tid] = g_w1t[kt * 32 + e * 256 + tid];
#pragma unroll
        for (int e = 0; e < 8; e++) {
            int j = e * 256 + tid;
            int kk = j >> 6, n = j & 63;
            int kg = kt + kk;
            int vg = bx * 64 + n;
            int b = vg >> 15, v = vg & 32767;
            int od = v >> 10, oh = (v >> 5) & 31, ow = v & 31;
            int ci = kg >> 6;
            int id = 2 * od - 1 + ((kg >> 4) & 3);
            int ih = 2 * oh - 1 + ((kg >> 2) & 3);
            int iw = 2 * ow - 1 + (kg & 3);
            float val = 0.f;
            if ((unsigned)id < 64u && (unsigned)ih < 64u && (unsigned)iw < 64u)
                val = x0[(((size_t)(b * 4 + ci)) << 18) + (id << 12) + (ih << 6) + iw];
            Bs[kk * 64 + n] = val;
        }
        __syncthreads();
#pragma unroll
        for (int kk = 0; kk < 32; kk++) {
            float2 a2 = *(const float2*)&As[kk * 32 + tc * 2];
            float4 b4 = *(const float4*)&Bs[kk * 64 + tv * 4];
            float a[2] = {a2.x, a2.y};
            float bb[4] = {b4.x, b4.y, b4.z, b4.w};
#pragma unroll
            for (int r = 0; r < 2; r++)
#pragma unroll
                for (int c = 0; c < 4; c++) acc[r][c] = fmaf(a[r], bb[c], acc[r][c]);
        }
    }
#pragma unroll
    for (int r = 0; r < 2; r++) {
        int co = tc * 2 + r;
        float bv = bias[co];
#pragma unroll
        for (int c = 0; c < 4; c++) {
            int vg = bx * 64 + tv * 4 + c;
            int b = vg >> 15, off = vg & 32767;
            float mv = g_m1[((size_t)b << 15) + off];
            float yv = (acc[r][c] + bv) * mv;
            yv = yv >= 0.f ? yv : 0.01f * yv;
            g_y1[(((size_t)(b * 32 + co)) << 15) + off] = yv;
        }
    }
}

// ---------------------------------------------------------------------------
// final: fp32 1x1x1, fused BN-on-load (finalize in preamble from sred).
// M=32 N=65536 K=64. grid 1024.
// ---------------------------------------------------------------------------
__global__ __launch_bounds__(256)
void final_kernel(const float* __restrict__ fb, const float* __restrict__ tg2,
                  const float* __restrict__ tbe2, float* __restrict__ out) {
    __shared__ float As[1024];
    __shared__ float Bs[2048];
    __shared__ float sc5[64], sh5[64];
    const int tid = threadIdx.x, tc = tid & 15, tv = tid >> 4;
    const int bx = blockIdx.x;

    if (tid < 64) {
        const float* sred = g_sred + 16384;
        float n = fmaxf(sred[tid * 32 + 2], 1.f);
        float mean = sred[tid * 32] / n;
        float var = fmaxf(sred[tid * 32 + 1] / n - mean * mean, 0.f);
        float rstd = rsqrtf(var + 1e-5f);
        float s = tg2[tid] * rstd;
        sc5[tid] = s; sh5[tid] = tbe2[tid] - mean * s;
    }

    float acc[2][4] = {{0.f}};
    for (int kt = 0; kt < 64; kt += 32) {
        __syncthreads();
#pragma unroll
        for (int e = 0; e < 4; e++) As[e * 256 + tid] = g_fwt[kt * 32 + e * 256 + tid];
#pragma unroll
        for (int e = 0; e < 8; e++) {
            int j = e * 256 + tid;
            int kk = j >> 6, n = j & 63;
            int kg = kt + kk;
            int vg = bx * 64 + n;
            int b = vg >> 15, v = vg & 32767;
            float raw = g_t2[(((size_t)(b * 64 + kg)) << 15) + v];
            float mv = g_mt2[((size_t)b << 15) + v];
            Bs[kk * 64 + n] = (raw * sc5[kg] + sh5[kg]) * mv;
        }
        __syncthreads();
#pragma unroll
        for (int kk = 0; kk < 32; kk++) {
            float2 a2 = *(const float2*)&As[kk * 32 + tc * 2];
            float4 b4 = *(const float4*)&Bs[kk * 64 + tv * 4];
            float a[2] = {a2.x, a2.y};
            float bb[4] = {b4.x, b4.y, b4.z, b4.w};
#pragma unroll
            for (int r = 0; r < 2; r++)
#pragma unroll
                for (int c = 0; c < 4; c++) acc[r][c] = fmaf(a[r], bb[c], acc[r][c]);
        }
    }
#pragma unroll
    for (int r = 0; r < 2; r++) {
        int co = tc * 2 + r;
        float bv = fb[co];
#pragma unroll
        for (int c = 0; c < 4; c++) {
            int vg = bx * 64 + tv * 4 + c;
            int b = vg >> 15, v = vg & 32767;
            out[(((size_t)(b * 32 + co)) << 15) + v] = acc[r][c] + bv;
        }
    }
}

// ---------------------------------------------------------------------------
// wave+block reduce helper: 3 atomics per block to padded sred lines
// ---------------------------------------------------------------------------
DEV void red3_and_atomic(float s, float s2, float sm, float* sred, int co) {
#pragma unroll
    for (int off = 32; off; off >>= 1) {
        s  += __shfl_down(s, off, 64);
        s2 += __shfl_down(s2, off, 64);
        sm += __shfl_down(sm, off, 64);
    }
    __shared__ float red[12];
    int lane = threadIdx.x & 63, wvi = threadIdx.x >> 6;
    if (!lane) { red[wvi] = s; red[4 + wvi] = s2; red[8 + wvi] = sm; }
    __syncthreads();
    if (!threadIdx.x) {
        atomicAdd(&sred[co * 32 + 0], red[0] + red[1] + red[2] + red[3]);
        atomicAdd(&sred[co * 32 + 1], red[4] + red[5] + red[6] + red[7]);
        atomicAdd(&sred[co * 32 + 2], red[8] + red[9] + red[10] + red[11]);
    }
}

// ---------------------------------------------------------------------------
// post: sum SPLITK partials + bias + mask + LeakyReLU + stats
// ---------------------------------------------------------------------------
template<int COUT, int LOGDO, int SPLITK, int ITERS>
DEV void post_body(const float* __restrict__ bias, const float* __restrict__ m2,
                   const float* p, float* y, float* sred) {
    constexpr int Dvox = 1 << (3 * LOGDO);
    constexpr size_t STR = (size_t)2 * COUT * Dvox;
    constexpr int LOGC = (COUT == 128) ? 7 : ((COUT == 64) ? 6 : 5);
    int base = blockIdx.x * (ITERS * 256);
    int co = (base >> (3 * LOGDO)) & (COUT - 1);
    float s = 0.f, s2 = 0.f, sm = 0.f;
#pragma unroll
    for (int it = 0; it < ITERS; it++) {
        int idx = base + it * 256 + threadIdx.x;
        int v = idx & (Dvox - 1);
        int b = idx >> (3 * LOGDO + LOGC);
        float sum = 0.f;
#pragma unroll
        for (int k = 0; k < SPLITK; k++) sum += p[k * STR + idx];
        float mv = m2[((size_t)b << (3 * LOGDO)) + v];
        float yv = (sum + bias[co]) * mv;
        yv = yv >= 0.f ? yv : 0.01f * yv;
        y[idx] = yv;
        s += yv; s2 += yv * yv; sm += mv;
    }
    red3_and_atomic(s, s2, sm, sred, co);
}

__global__ __launch_bounds__(256) void post2_kernel(const float* b) { post_body<64, 4, 4, 1>(b, g_m2, g_p2, g_y2, g_sred + 4096); }
__global__ __launch_bounds__(256) void post3_kernel(const float* b) { post_body<128, 3, 16, 1>(b, g_m3, g_p3, g_y3, g_sred + 8192); }
__global__ __launch_bounds__(256) void post4_kernel(const float* b) { post_body<128, 4, 4, 2>(b, g_mt1, g_p4, g_t1, g_sred + 12288); }
__global__ __launch_bounds__(256) void post5_kernel(const float* b) { post_body<64, 5, 1, 8>(b, g_mt2, g_t2, g_t2, g_sred + 16384); }

// stats pass over y1. grid 2048.
__global__ __launch_bounds__(256)
void stats1_kernel() {
    int base = blockIdx.x * 1024;
    int co = (base >> 15) & 31;
    float s = 0.f, s2 = 0.f, sm = 0.f;
#pragma unroll
    for (int it = 0; it < 4; it++) {
        int idx = base + it * 256 + threadIdx.x;
        int v = idx & 32767;
        int b = idx >> 20;
        float yv = g_y1[idx];
        float mv = g_m1[((size_t)b << 15) + v];
        s += yv; s2 += yv * yv; sm += mv;
    }
    red3_and_atomic(s, s2, sm, g_sred, co);
}

// ---------------------------------------------------------------------------
// bn fused with finalize: per-block preamble computes scale/shift from sred,
// then voxel-per-thread apply: coalesced fp32 reads, ushort8 VC stores.
// ---------------------------------------------------------------------------
template<int LOGC, int LOGD>
DEV void bn_fused_body(const float* __restrict__ y, ushort* __restrict__ out,
                       const float* __restrict__ sred, const float* __restrict__ gm,
                       const float* __restrict__ be, const float* __restrict__ m2) {
    constexpr int C = 1 << LOGC, Dvox = 1 << LOGD;
    __shared__ float sc[C], sh[C];
    int tid = threadIdx.x;
    if (tid < C) {
        float n = fmaxf(sred[tid * 32 + 2], 1.f);
        float mean = sred[tid * 32] / n;
        float var = fmaxf(sred[tid * 32 + 1] / n - mean * mean, 0.f);
        float rstd = rsqrtf(var + 1e-5f);
        float s = gm[tid] * rstd;
        sc[tid] = s; sh[tid] = be[tid] - mean * s;
    }
    __syncthreads();
    int gv = blockIdx.x * 256 + tid;
    int b = gv >> LOGD, vox = gv & (Dvox - 1);
    float mv = m2[gv];
    const float* yp = y + (((size_t)b << LOGC) << LOGD) + vox;
    ushort* op = out + (size_t)gv * C;
#pragma unroll
    for (int c0 = 0; c0 < C; c0 += 8) {
        ushort pk[8];
#pragma unroll
        for (int j = 0; j < 8; j++) {
            int c = c0 + j;
            float val = yp[(size_t)c << LOGD];
            pk[j] = f2bf((val * sc[c] + sh[c]) * mv);
        }
        *(ushort8*)&op[c0] = (ushort8){pk[0], pk[1], pk[2], pk[3], pk[4], pk[5], pk[6], pk[7]};
    }
}

__global__ __launch_bounds__(256)
void bn1_kernel(const float* g, const float* be) { bn_fused_body<5, 15>(g_y1, g_y1b, g_sred + 0, g, be, g_m1); }
__global__ __launch_bounds__(256)
void bn2_kernel(const float* g, const float* be) { bn_fused_body<6, 12>(g_y2, g_y2b, g_sred + 4096, g, be, g_m2); }
__global__ __launch_bounds__(256)
void bn3_kernel(const float* g, const float* be) { bn_fused_body<7, 9>(g_y3, g_y3b, g_sred + 8192, g, be, g_m3); }
__global__ __launch_bounds__(256)
void bn4_kernel(const float* g, const float* be) { bn_fused_body<7, 12>(g_t1, g_t1b, g_sred + 12288, g, be, g_mt1); }

// ---------------------------------------------------------------------------

extern "C" void kernel_launch(void* const* d_in, const int* in_sizes, int n_in,
                              void* d_out, int out_size, void* d_ws, size_t ws_size,
                              hipStream_t stream) {
    (void)in_sizes; (void)n_in; (void)out_size; (void)d_ws; (void)ws_size;
    const float* feat = (const float*)d_in[0];
    const float* mask = (const float*)d_in[1];
    const float* w1  = (const float*)d_in[2];
    const float* b1  = (const float*)d_in[3];
    const float* g1  = (const float*)d_in[4];
    const float* be1 = (const float*)d_in[5];
    const float* w2  = (const float*)d_in[6];
    const float* b2  = (const float*)d_in[7];
    const float* g2  = (const float*)d_in[8];
    const float* be2 = (const float*)d_in[9];
    const float* w3  = (const float*)d_in[10];
    const float* b3  = (const float*)d_in[11];
    const float* g3  = (const float*)d_in[12];
    const float* be3 = (const float*)d_in[13];
    const float* tw1 = (const float*)d_in[14];
    const float* tb1 = (const float*)d_in[15];
    const float* tg1 = (const float*)d_in[16];
    const float* tbe1= (const float*)d_in[17];
    const float* tw2 = (const float*)d_in[18];
    const float* tb2 = (const float*)d_in[19];
    const float* tg2 = (const float*)d_in[20];
    const float* tbe2= (const float*)d_in[21];
    const float* fw  = (const float*)d_in[22];
    const float* fb  = (const float*)d_in[23];

    setup_kernel<<<96, 256, 0, stream>>>(w1, fw);
    prep2_kernel<<<512, 256, 0, stream>>>(w2);
    prep3_kernel<<<2048, 256, 0, stream>>>(w3);
    prep4_kernel<<<4096, 256, 0, stream>>>(tw1);
    prep5_kernel<<<2048, 256, 0, stream>>>(tw2);
    prep1x_kernel<<<2048, 256, 0, stream>>>(feat, mask);

    // block 1 (fp32): 4->32, 64^3 -> 32^3
    mask1_kernel<<<256, 256, 0, stream>>>(mask);
    conv1_kernel<<<1024, 256, 0, stream>>>(b1);
    stats1_kernel<<<2048, 256, 0, stream>>>();
    bn1_kernel<<<256, 256, 0, stream>>>(g1, be1);

    // block 2 (MFMA): 32->64, 32^3 -> 16^3, K=2048 split 4
    mask2_kernel<<<32, 256, 0, stream>>>();
    conv2_kernel<<<dim3(64, 1, 4), 256, 0, stream>>>();
    post2_kernel<<<2048, 256, 0, stream>>>(b2);
    bn2_kernel<<<32, 256, 0, stream>>>(g2, be2);

    // block 3 (MFMA): 64->128, 16^3 -> 8^3, K=4096 split 16
    mask3_kernel<<<4, 256, 0, stream>>>();
    conv3_kernel<<<dim3(16, 1, 16), 256, 0, stream>>>();
    post3_kernel<<<512, 256, 0, stream>>>(b3);
    bn3_kernel<<<4, 256, 0, stream>>>(g3, be3);

    // up block 1 (MFMA): 128->128, 8^3 -> 16^3, parity 8 x split 4
    mask4_kernel<<<32, 256, 0, stream>>>();
    conv4_kernel<<<dim3(8, 1, 32), 256, 0, stream>>>();
    post4_kernel<<<2048, 256, 0, stream>>>(tb1);
    bn4_kernel<<<32, 256, 0, stream>>>(tg1, tbe1);

    // up block 2 (MFMA): 128->64, 16^3 -> 32^3, parity 8
    mask5_kernel<<<256, 256, 0, stream>>>();
    conv5_kernel<<<dim3(64, 1, 8), 256, 0, stream>>>();
    post5_kernel<<<2048, 256, 0, stream>>>(tb2);

    // final dense 1x1x1 conv 64->32 @ 32^3 (fp32, fused BN finalize + apply)
    final_kernel<<<1024, 256, 0, stream>>>(fb, tg2, tbe2, (float*)d_out);
}

// Round 10
// 334.366 us; speedup vs baseline: 2.9716x; 1.0066x over previous
//
#include <hip/hip_runtime.h>
#include <hip/hip_bf16.h>

#define DEV static __device__ __forceinline__

typedef unsigned short ushort;
typedef __attribute__((ext_vector_type(8))) short short8;
typedef __attribute__((ext_vector_type(8))) ushort ushort8;
typedef __attribute__((ext_vector_type(4))) float accv;

DEV ushort f2bf(float f) {
    __hip_bfloat16 h = __float2bfloat16(f);   // RNE
    return reinterpret_cast<ushort&>(h);
}

// ---------------------------------------------------------------------------
// Static device workspace
// ---------------------------------------------------------------------------
__device__ float    g_sred[5 * 128 * 32];             // [l][co][32]: 0=sum 1=sumsq 2=maskcnt
__device__ float    g_y1[2097152];                    // (2,32,32^3) fp32 NCV
__device__ __align__(16) ushort g_y1b[2097152];       // (2,32^3,32) bf16 VC
__device__ float    g_m1[65536];
__device__ float    g_y2[524288];
__device__ __align__(16) ushort g_y2b[524288];        // (2,16^3,64) bf16 VC
__device__ float    g_m2[8192];
__device__ float    g_y3[131072];
__device__ __align__(16) ushort g_y3b[131072];        // (2,8^3,128) bf16 VC
__device__ float    g_m3[1024];
__device__ float    g_t1[1048576];
__device__ __align__(16) ushort g_t1b[1048576];       // (2,16^3,128) bf16 VC
__device__ float    g_mt1[8192];
__device__ float    g_mt2[65536];
__device__ float    g_t2[4194304];                    // x0 early; conv5 final out late
// split-K partial buffers
__device__ float    g_p2[4194304];                    // 8  x 524288
__device__ float    g_p3[4194304];                    // 32 x 131072
__device__ float    g_p4[8388608];                    // 8  x 1048576
__device__ float    g_p5[8388608];                    // 2  x 4194304
// K-major weights
__device__ __align__(16) ushort g_wb2[131072];
__device__ __align__(16) ushort g_wb3[524288];
__device__ __align__(16) ushort g_wb4[1048576];
__device__ __align__(16) ushort g_wb5[524288];
__device__ float    g_w1t[8192];                      // [k=256][co=32] fp32
__device__ float    g_fwt[2048];                      // [k=64][co=32] fp32

// ---------------------------------------------------------------------------
__global__ __launch_bounds__(256)
void setup_kernel(const float* __restrict__ w1, const float* __restrict__ fw) {
    int idx = blockIdx.x * 256 + threadIdx.x;
    if (idx < 20480) g_sred[idx] = 0.f;
    if (idx < 8192) { int co = idx >> 8, kg = idx & 255; g_w1t[kg * 32 + co] = w1[idx]; }
    if (idx < 2048) { int co = idx >> 6, kg = idx & 63; g_fwt[kg * 32 + co] = fw[idx]; }
}

// x0 = feat * (mask>0.5), fp32 NCV, into g_t2 (dead until post5). grid 2048.
__global__ __launch_bounds__(256)
void prep1x_kernel(const float* __restrict__ feat, const float* __restrict__ mask) {
    int idx = blockIdx.x * 256 + threadIdx.x;
    int b = idx >> 18, v = idx & 0x3FFFF;
    float mv = mask[idx] > 0.5f ? 1.f : 0.f;
#pragma unroll
    for (int c = 0; c < 4; c++) {
        int o = ((b * 4 + c) << 18) + v;
        g_t2[o] = feat[o] * mv;
    }
}

// ---------------------------------------------------------------------------
// weight pre-transpose (verified round-7)
// ---------------------------------------------------------------------------
template<int CIN, int COUT>
DEV void prep_down(const float* w, ushort* wb) {
    int idx = blockIdx.x * 256 + threadIdx.x;
    int co = idx / (CIN * 64), r = idx % (CIN * 64);
    int ci = r >> 6, tap = r & 63;
    wb[(size_t)co * (CIN * 64) + tap * CIN + ci] = f2bf(w[idx]);
}
template<int CIN, int COUT>
DEV void prep_up(const float* w, ushort* wb) {
    int idx = blockIdx.x * 256 + threadIdx.x;
    int co = idx / (CIN * 64), r = idx % (CIN * 64);
    int ci = r >> 6, t64 = r & 63;
    int kd = t64 >> 4, kh = (t64 >> 2) & 3, kw = t64 & 3;
    int pd = (3 - kd) & 1, td = (3 - kd) >> 1;
    int ph = (3 - kh) & 1, th = (3 - kh) >> 1;
    int pw = (3 - kw) & 1, tw = (3 - kw) >> 1;
    int parity = pd * 4 + ph * 2 + pw, t = td * 4 + th * 2 + tw;
    wb[(((size_t)parity * COUT + co) * 8 + t) * CIN + ci] = f2bf(w[idx]);
}

__global__ __launch_bounds__(256) void prep2_kernel(const float* w) { prep_down<32, 64>(w, g_wb2); }
__global__ __launch_bounds__(256) void prep3_kernel(const float* w) { prep_down<64, 128>(w, g_wb3); }
__global__ __launch_bounds__(256) void prep4_kernel(const float* w) { prep_up<128, 128>(w, g_wb4); }
__global__ __launch_bounds__(256) void prep5_kernel(const float* w) { prep_up<128, 64>(w, g_wb5); }

// ---------------------------------------------------------------------------
// mask dilation kernels
// ---------------------------------------------------------------------------
DEV void mask_down_body(const float* mprev, float* mout, int logDin, int logDo) {
    int Din = 1 << logDin, Do = 1 << logDo;
    int idx = blockIdx.x * 256 + threadIdx.x;
    int b = idx >> (3 * logDo), v = idx & ((1 << (3 * logDo)) - 1);
    int od = v >> (2 * logDo), rem = v & ((1 << (2 * logDo)) - 1);
    int oh = rem >> logDo, ow = rem & (Do - 1);
    const float* mp = mprev + ((size_t)b << (3 * logDin));
    float acc = 0.f;
    for (int kd = 0; kd < 4; kd++) {
        int id = 2 * od - 1 + kd;
        if ((unsigned)id >= (unsigned)Din) continue;
        for (int kh = 0; kh < 4; kh++) {
            int ih = 2 * oh - 1 + kh;
            if ((unsigned)ih >= (unsigned)Din) continue;
            const float* row = mp + ((size_t)id * Din + ih) * Din;
            for (int kw = 0; kw < 4; kw++) {
                int iw = 2 * ow - 1 + kw;
                if ((unsigned)iw < (unsigned)Din) acc += row[iw];
            }
        }
    }
    mout[idx] = acc > 0.f ? 1.f : 0.f;
}

DEV void mask_up_body(const float* mprev, float* mout, int logDin, int logDo) {
    int Din = 1 << logDin, Do = 1 << logDo;
    int idx = blockIdx.x * 256 + threadIdx.x;
    int b = idx >> (3 * logDo), v = idx & ((1 << (3 * logDo)) - 1);
    int od = v >> (2 * logDo), rem = v & ((1 << (2 * logDo)) - 1);
    int oh = rem >> logDo, ow = rem & (Do - 1);
    const float* mp = mprev + ((size_t)b << (3 * logDin));
    float acc = 0.f;
    for (int kd = 0; kd < 4; kd++) {
        int u = od + kd - 2; if (u < 0 || (u & 1)) continue;
        int id = u >> 1; if (id >= Din) continue;
        for (int kh = 0; kh < 4; kh++) {
            int uh = oh + kh - 2; if (uh < 0 || (uh & 1)) continue;
            int ih = uh >> 1; if (ih >= Din) continue;
            const float* row = mp + ((size_t)id * Din + ih) * Din;
            for (int kw = 0; kw < 4; kw++) {
                int uw = ow + kw - 2; if (uw < 0 || (uw & 1)) continue;
                int iw = uw >> 1; if (iw >= Din) continue;
                acc += row[iw];
            }
        }
    }
    mout[idx] = acc > 0.f ? 1.f : 0.f;
}

__global__ __launch_bounds__(256)
void mask1_kernel(const float* __restrict__ mask) {
    int idx = blockIdx.x * 256 + threadIdx.x;
    int b = idx >> 15, v = idx & 0x7FFF;
    int od = v >> 10, rem = v & 1023;
    int oh = rem >> 5, ow = rem & 31;
    const float* mp = mask + ((size_t)b << 18);
    float acc = 0.f;
    for (int kd = 0; kd < 4; kd++) {
        int id = 2 * od - 1 + kd;
        if ((unsigned)id >= 64u) continue;
        for (int kh = 0; kh < 4; kh++) {
            int ih = 2 * oh - 1 + kh;
            if ((unsigned)ih >= 64u) continue;
            const float* row = mp + ((size_t)id * 64 + ih) * 64;
            for (int kw = 0; kw < 4; kw++) {
                int iw = 2 * ow - 1 + kw;
                if ((unsigned)iw < 64u && row[iw] > 0.5f) acc += 1.f;
            }
        }
    }
    g_m1[idx] = acc > 0.f ? 1.f : 0.f;
}

__global__ __launch_bounds__(256) void mask2_kernel() { mask_down_body(g_m1, g_m2, 5, 4); }
__global__ __launch_bounds__(256) void mask3_kernel() { mask_down_body(g_m2, g_m3, 4, 3); }
__global__ __launch_bounds__(256) void mask4_kernel() { mask_up_body(g_m3, g_mt1, 3, 4); }
__global__ __launch_bounds__(256) void mask5_kernel() { mask_up_body(g_mt1, g_mt2, 4, 5); }

// ---------------------------------------------------------------------------
// bf16 MFMA implicit-GEMM, register-prefetch pipelined.
// ---------------------------------------------------------------------------
template<int MODE, int MT, int NT, int CIN, int COUT, int LOGDI, int LOGDO, int SPLITK>
DEV void mfma_gemm_body(const ushort* __restrict__ xb, const ushort* __restrict__ wb,
                        float* __restrict__ y) {
    constexpr int KT = 32;
    constexpr int K  = (MODE == 1) ? CIN * 8 : CIN * 64;
    constexpr int KSEG = K / SPLITK;
    constexpr int LDA = 40;
    constexpr int MTW = MT / 32, NTW = NT / 32;
    constexpr int AR = MT * 4 / 256, BR = NT * 4 / 256;
    constexpr int LCIN = (CIN == 32) ? 5 : ((CIN == 64) ? 6 : 7);
    constexpr int Din = 1 << LOGDI, Do = 1 << LOGDO;
    constexpr int DvoxI = 1 << (3 * LOGDI), DvoxO = 1 << (3 * LOGDO);

    __shared__ __align__(16) ushort As[MT * LDA];
    __shared__ __align__(16) ushort Bs[NT * LDA];

    const int tid = threadIdx.x;
    const int bx = blockIdx.x;
    int pd = 0, ph = 0, pw = 0, ks = 0;
    const ushort* wp = wb;
    if constexpr (MODE == 1) {
        int z = blockIdx.z;
        pd = (z >> 2) & 1; ph = (z >> 1) & 1; pw = z & 1; ks = z >> 3;
        wp = wb + (size_t)(z & 7) * COUT * CIN * 8;
    } else {
        ks = blockIdx.z;
    }

    const int wv = tid >> 6, lane = tid & 63;
    const int mw = wv & 1, nw = wv >> 1;
    const int lr = lane & 15, quad = lane >> 4;

    auto gatherA = [&](int kt, ushort8* pa) {
#pragma unroll
        for (int r = 0; r < AR; r++) {
            int slot = r * 256 + tid;
            int m = slot >> 2, oct = slot & 3;
            pa[r] = *(const ushort8*)&wp[(size_t)m * K + kt + oct * 8];
        }
    };
    auto gatherB = [&](int kt, ushort8* pb) {
#pragma unroll
        for (int r = 0; r < BR; r++) {
            int slot = r * 256 + tid;
            int n = slot >> 2, oct = slot & 3;
            int vg = bx * NT + n;
            int kg0 = kt + oct * 8;
            int tap = kg0 >> LCIN, ci0 = kg0 & (CIN - 1);
            ushort8 v = (ushort8){0, 0, 0, 0, 0, 0, 0, 0};
            int b, id, ih, iw;
            if constexpr (MODE == 0) {
                b = vg >> (3 * LOGDO);
                int vv = vg & (DvoxO - 1);
                int od = vv >> (2 * LOGDO), oh = (vv >> LOGDO) & (Do - 1), ow = vv & (Do - 1);
                id = 2 * od - 1 + (tap >> 4);
                ih = 2 * oh - 1 + ((tap >> 2) & 3);
                iw = 2 * ow - 1 + (tap & 3);
            } else {
                b = vg >> (3 * LOGDI);
                int vv = vg & (DvoxI - 1);
                int odp = vv >> (2 * LOGDI), ohp = (vv >> LOGDI) & (Din - 1), owp = vv & (Din - 1);
                id = odp + pd + ((tap >> 2) & 1) - 1;
                ih = ohp + ph + ((tap >> 1) & 1) - 1;
                iw = owp + pw + (tap & 1) - 1;
            }
            if ((unsigned)id < (unsigned)Din && (unsigned)ih < (unsigned)Din &&
                (unsigned)iw < (unsigned)Din)
                v = *(const ushort8*)&xb[((size_t)b * DvoxI +
                                          (id << (2 * LOGDI)) + (ih << LOGDI) + iw) * CIN + ci0];
            pb[r] = v;
        }
    };

    accv acc[MTW][NTW];
#pragma unroll
    for (int mt = 0; mt < MTW; mt++)
#pragma unroll
        for (int nt = 0; nt < NTW; nt++) acc[mt][nt] = (accv){0.f, 0.f, 0.f, 0.f};

    const int kbeg = ks * KSEG, kend = kbeg + KSEG;
    ushort8 pa[AR], pb[BR], qa[AR], qb[BR];
    gatherA(kbeg, pa);
    gatherB(kbeg, pb);

    for (int kt = kbeg; kt < kend; kt += KT) {
        __syncthreads();
#pragma unroll
        for (int r = 0; r < AR; r++) {
            int slot = r * 256 + tid;
            int m = slot >> 2, oct = slot & 3;
            *(ushort8*)&As[m * LDA + oct * 8] = pa[r];
        }
#pragma unroll
        for (int r = 0; r < BR; r++) {
            int slot = r * 256 + tid;
            int n = slot >> 2, oct = slot & 3;
            *(ushort8*)&Bs[n * LDA + oct * 8] = pb[r];
        }
        __syncthreads();
        bool more = (kt + KT) < kend;
        if (more) { gatherA(kt + KT, qa); gatherB(kt + KT, qb); }

        short8 af[MTW], bfr[NTW];
#pragma unroll
        for (int mt = 0; mt < MTW; mt++)
            af[mt] = *(const short8*)&As[((mw * MTW + mt) * 16 + lr) * LDA + quad * 8];
#pragma unroll
        for (int nt = 0; nt < NTW; nt++)
            bfr[nt] = *(const short8*)&Bs[((nw * NTW + nt) * 16 + lr) * LDA + quad * 8];
#pragma unroll
        for (int mt = 0; mt < MTW; mt++)
#pragma unroll
            for (int nt = 0; nt < NTW; nt++)
                acc[mt][nt] = __builtin_amdgcn_mfma_f32_16x16x32_bf16(
                    af[mt], bfr[nt], acc[mt][nt], 0, 0, 0);
        if (more) {
#pragma unroll
            for (int r = 0; r < AR; r++) pa[r] = qa[r];
#pragma unroll
            for (int r = 0; r < BR; r++) pb[r] = qb[r];
        }
    }

    float* yp = y + (size_t)ks * (2 * COUT * DvoxO);
#pragma unroll
    for (int mt = 0; mt < MTW; mt++) {
#pragma unroll
        for (int nt = 0; nt < NTW; nt++) {
#pragma unroll
            for (int r = 0; r < 4; r++) {
                int co = (mw * MTW + mt) * 16 + quad * 4 + r;
                int vg = bx * NT + (nw * NTW + nt) * 16 + lr;
                size_t idx;
                if constexpr (MODE == 1) {
                    int b = vg >> (3 * LOGDI);
                    int vv = vg & (DvoxI - 1);
                    int odp = vv >> (2 * LOGDI), ohp = (vv >> LOGDI) & (Din - 1), owp = vv & (Din - 1);
                    int od = 2 * odp + pd, oh = 2 * ohp + ph, ow = 2 * owp + pw;
                    idx = (((size_t)(b * COUT + co)) << (3 * LOGDO)) +
                          (od << (2 * LOGDO)) + (oh << LOGDO) + ow;
                } else {
                    int b = vg >> (3 * LOGDO);
                    int off = vg & (DvoxO - 1);
                    idx = (((size_t)(b * COUT + co)) << (3 * LOGDO)) + off;
                }
                yp[idx] = acc[mt][nt][r];
            }
        }
    }
}

__global__ __launch_bounds__(256)
void conv2_kernel() { mfma_gemm_body<0, 64, 128, 32, 64, 5, 4, 8>(g_y1b, g_wb2, g_p2); }
__global__ __launch_bounds__(256)
void conv3_kernel() { mfma_gemm_body<0, 128, 64, 64, 128, 4, 3, 32>(g_y2b, g_wb3, g_p3); }
__global__ __launch_bounds__(256)
void conv4_kernel() { mfma_gemm_body<1, 128, 128, 128, 128, 3, 4, 8>(g_y3b, g_wb4, g_p4); }
__global__ __launch_bounds__(256)
void conv5_kernel() { mfma_gemm_body<1, 64, 128, 128, 64, 4, 5, 2>(g_t1b, g_wb5, g_p5); }

// ---------------------------------------------------------------------------
// conv1: fp32 implicit-GEMM, K-major weights, prefetch-pipelined.
// M=32 N=65536 K=256. grid 1024.
// ---------------------------------------------------------------------------
__global__ __launch_bounds__(256)
void conv1_kernel(const float* __restrict__ bias) {
    const float* x0 = g_t2;
    __shared__ float As[1024];
    __shared__ float Bs[2048];
    const int tid = threadIdx.x, tc = tid & 15, tv = tid >> 4;
    const int bx = blockIdx.x;

    auto gatherA = [&](int kt, float* pa) {
#pragma unroll
        for (int e = 0; e < 4; e++) pa[e] = g_w1t[kt * 32 + e * 256 + tid];
    };
    auto gatherB = [&](int kt, float* pb) {
#pragma unroll
        for (int e = 0; e < 8; e++) {
            int j = e * 256 + tid;
            int kk = j >> 6, n = j & 63;
            int kg = kt + kk;
            int vg = bx * 64 + n;
            int b = vg >> 15, v = vg & 32767;
            int od = v >> 10, oh = (v >> 5) & 31, ow = v & 31;
            int ci = kg >> 6;
            int id = 2 * od - 1 + ((kg >> 4) & 3);
            int ih = 2 * oh - 1 + ((kg >> 2) & 3);
            int iw = 2 * ow - 1 + (kg & 3);
            float val = 0.f;
            if ((unsigned)id < 64u && (unsigned)ih < 64u && (unsigned)iw < 64u)
                val = x0[(((size_t)(b * 4 + ci)) << 18) + (id << 12) + (ih << 6) + iw];
            pb[e] = val;
        }
    };

    float acc[2][4] = {{0.f}};
    float pa[4], pb[8], qa[4], qb[8];
    gatherA(0, pa); gatherB(0, pb);
    for (int kt = 0; kt < 256; kt += 32) {
        __syncthreads();
#pragma unroll
        for (int e = 0; e < 4; e++) As[e * 256 + tid] = pa[e];
#pragma unroll
        for (int e = 0; e < 8; e++) { int j = e * 256 + tid; Bs[j] = pb[e]; }
        __syncthreads();
        bool more = kt < 224;
        if (more) { gatherA(kt + 32, qa); gatherB(kt + 32, qb); }
#pragma unroll
        for (int kk = 0; kk < 32; kk++) {
            float2 a2 = *(const float2*)&As[kk * 32 + tc * 2];
            float4 b4 = *(const float4*)&Bs[kk * 64 + tv * 4];
            float a[2] = {a2.x, a2.y};
            float bb[4] = {b4.x, b4.y, b4.z, b4.w};
#pragma unroll
            for (int r = 0; r < 2; r++)
#pragma unroll
                for (int c = 0; c < 4; c++) acc[r][c] = fmaf(a[r], bb[c], acc[r][c]);
        }
        if (more) {
#pragma unroll
            for (int e = 0; e < 4; e++) pa[e] = qa[e];
#pragma unroll
            for (int e = 0; e < 8; e++) pb[e] = qb[e];
        }
    }
#pragma unroll
    for (int r = 0; r < 2; r++) {
        int co = tc * 2 + r;
        float bv = bias[co];
#pragma unroll
        for (int c = 0; c < 4; c++) {
            int vg = bx * 64 + tv * 4 + c;
            int b = vg >> 15, off = vg & 32767;
            float mv = g_m1[((size_t)b << 15) + off];
            float yv = (acc[r][c] + bv) * mv;
            yv = yv >= 0.f ? yv : 0.01f * yv;
            g_y1[(((size_t)(b * 32 + co)) << 15) + off] = yv;
        }
    }
}

// ---------------------------------------------------------------------------
// final: fp32 1x1x1, fused BN-on-load. grid 1024.
// ---------------------------------------------------------------------------
__global__ __launch_bounds__(256)
void final_kernel(const float* __restrict__ fb, const float* __restrict__ tg2,
                  const float* __restrict__ tbe2, float* __restrict__ out) {
    __shared__ float As[1024];
    __shared__ float Bs[2048];
    __shared__ float sc5[64], sh5[64];
    const int tid = threadIdx.x, tc = tid & 15, tv = tid >> 4;
    const int bx = blockIdx.x;

    if (tid < 64) {
        const float* sred = g_sred + 16384;
        float n = fmaxf(sred[tid * 32 + 2], 1.f);
        float mean = sred[tid * 32] / n;
        float var = fmaxf(sred[tid * 32 + 1] / n - mean * mean, 0.f);
        float rstd = rsqrtf(var + 1e-5f);
        float s = tg2[tid] * rstd;
        sc5[tid] = s; sh5[tid] = tbe2[tid] - mean * s;
    }

    float acc[2][4] = {{0.f}};
    for (int kt = 0; kt < 64; kt += 32) {
        __syncthreads();
#pragma unroll
        for (int e = 0; e < 4; e++) As[e * 256 + tid] = g_fwt[kt * 32 + e * 256 + tid];
#pragma unroll
        for (int e = 0; e < 8; e++) {
            int j = e * 256 + tid;
            int kk = j >> 6, n = j & 63;
            int kg = kt + kk;
            int vg = bx * 64 + n;
            int b = vg >> 15, v = vg & 32767;
            float raw = g_t2[(((size_t)(b * 64 + kg)) << 15) + v];
            float mv = g_mt2[((size_t)b << 15) + v];
            Bs[kk * 64 + n] = (raw * sc5[kg] + sh5[kg]) * mv;
        }
        __syncthreads();
#pragma unroll
        for (int kk = 0; kk < 32; kk++) {
            float2 a2 = *(const float2*)&As[kk * 32 + tc * 2];
            float4 b4 = *(const float4*)&Bs[kk * 64 + tv * 4];
            float a[2] = {a2.x, a2.y};
            float bb[4] = {b4.x, b4.y, b4.z, b4.w};
#pragma unroll
            for (int r = 0; r < 2; r++)
#pragma unroll
                for (int c = 0; c < 4; c++) acc[r][c] = fmaf(a[r], bb[c], acc[r][c]);
        }
    }
#pragma unroll
    for (int r = 0; r < 2; r++) {
        int co = tc * 2 + r;
        float bv = fb[co];
#pragma unroll
        for (int c = 0; c < 4; c++) {
            int vg = bx * 64 + tv * 4 + c;
            int b = vg >> 15, v = vg & 32767;
            out[(((size_t)(b * 32 + co)) << 15) + v] = acc[r][c] + bv;
        }
    }
}

// ---------------------------------------------------------------------------
DEV void red3_and_atomic(float s, float s2, float sm, float* sred, int co) {
#pragma unroll
    for (int off = 32; off; off >>= 1) {
        s  += __shfl_down(s, off, 64);
        s2 += __shfl_down(s2, off, 64);
        sm += __shfl_down(sm, off, 64);
    }
    __shared__ float red[12];
    int lane = threadIdx.x & 63, wvi = threadIdx.x >> 6;
    if (!lane) { red[wvi] = s; red[4 + wvi] = s2; red[8 + wvi] = sm; }
    __syncthreads();
    if (!threadIdx.x) {
        atomicAdd(&sred[co * 32 + 0], red[0] + red[1] + red[2] + red[3]);
        atomicAdd(&sred[co * 32 + 1], red[4] + red[5] + red[6] + red[7]);
        atomicAdd(&sred[co * 32 + 2], red[8] + red[9] + red[10] + red[11]);
    }
}

// ---------------------------------------------------------------------------
// post: sum SPLITK partials + bias + mask + LeakyReLU + stats
// ---------------------------------------------------------------------------
template<int COUT, int LOGDO, int SPLITK, int ITERS>
DEV void post_body(const float* __restrict__ bias, const float* __restrict__ m2,
                   const float* p, float* y, float* sred) {
    constexpr int Dvox = 1 << (3 * LOGDO);
    constexpr size_t STR = (size_t)2 * COUT * Dvox;
    constexpr int LOGC = (COUT == 128) ? 7 : ((COUT == 64) ? 6 : 5);
    int base = blockIdx.x * (ITERS * 256);
    int co = (base >> (3 * LOGDO)) & (COUT - 1);
    float s = 0.f, s2 = 0.f, sm = 0.f;
#pragma unroll
    for (int it = 0; it < ITERS; it++) {
        int idx = base + it * 256 + threadIdx.x;
        int v = idx & (Dvox - 1);
        int b = idx >> (3 * LOGDO + LOGC);
        float sum = 0.f;
#pragma unroll
        for (int k = 0; k < SPLITK; k++) sum += p[k * STR + idx];
        float mv = m2[((size_t)b << (3 * LOGDO)) + v];
        float yv = (sum + bias[co]) * mv;
        yv = yv >= 0.f ? yv : 0.01f * yv;
        y[idx] = yv;
        s += yv; s2 += yv * yv; sm += mv;
    }
    red3_and_atomic(s, s2, sm, sred, co);
}

__global__ __launch_bounds__(256) void post2_kernel(const float* b) { post_body<64, 4, 8, 1>(b, g_m2, g_p2, g_y2, g_sred + 4096); }
__global__ __launch_bounds__(256) void post3_kernel(const float* b) { post_body<128, 3, 32, 1>(b, g_m3, g_p3, g_y3, g_sred + 8192); }
__global__ __launch_bounds__(256) void post4_kernel(const float* b) { post_body<128, 4, 8, 2>(b, g_mt1, g_p4, g_t1, g_sred + 12288); }
__global__ __launch_bounds__(256) void post5_kernel(const float* b) { post_body<64, 5, 2, 8>(b, g_mt2, g_p5, g_t2, g_sred + 16384); }

// stats pass over y1. grid 2048.
__global__ __launch_bounds__(256)
void stats1_kernel() {
    int base = blockIdx.x * 1024;
    int co = (base >> 15) & 31;
    float s = 0.f, s2 = 0.f, sm = 0.f;
#pragma unroll
    for (int it = 0; it < 4; it++) {
        int idx = base + it * 256 + threadIdx.x;
        int v = idx & 32767;
        int b = idx >> 20;
        float yv = g_y1[idx];
        float mv = g_m1[((size_t)b << 15) + v];
        s += yv; s2 += yv * yv; sm += mv;
    }
    red3_and_atomic(s, s2, sm, g_sred, co);
}

// ---------------------------------------------------------------------------
// bn fused with finalize (verified round-9)
// ---------------------------------------------------------------------------
template<int LOGC, int LOGD>
DEV void bn_fused_body(const float* __restrict__ y, ushort* __restrict__ out,
                       const float* __restrict__ sred, const float* __restrict__ gm,
                       const float* __restrict__ be, const float* __restrict__ m2) {
    constexpr int C = 1 << LOGC, Dvox = 1 << LOGD;
    __shared__ float sc[C], sh[C];
    int tid = threadIdx.x;
    if (tid < C) {
        float n = fmaxf(sred[tid * 32 + 2], 1.f);
        float mean = sred[tid * 32] / n;
        float var = fmaxf(sred[tid * 32 + 1] / n - mean * mean, 0.f);
        float rstd = rsqrtf(var + 1e-5f);
        float s = gm[tid] * rstd;
        sc[tid] = s; sh[tid] = be[tid] - mean * s;
    }
    __syncthreads();
    int gv = blockIdx.x * 256 + tid;
    int b = gv >> LOGD, vox = gv & (Dvox - 1);
    float mv = m2[gv];
    const float* yp = y + (((size_t)b << LOGC) << LOGD) + vox;
    ushort* op = out + (size_t)gv * C;
#pragma unroll
    for (int c0 = 0; c0 < C; c0 += 8) {
        ushort pk[8];
#pragma unroll
        for (int j = 0; j < 8; j++) {
            int c = c0 + j;
            float val = yp[(size_t)c << LOGD];
            pk[j] = f2bf((val * sc[c] + sh[c]) * mv);
        }
        *(ushort8*)&op[c0] = (ushort8){pk[0], pk[1], pk[2], pk[3], pk[4], pk[5], pk[6], pk[7]};
    }
}

__global__ __launch_bounds__(256)
void bn1_kernel(const float* g, const float* be) { bn_fused_body<5, 15>(g_y1, g_y1b, g_sred + 0, g, be, g_m1); }
__global__ __launch_bounds__(256)
void bn2_kernel(const float* g, const float* be) { bn_fused_body<6, 12>(g_y2, g_y2b, g_sred + 4096, g, be, g_m2); }
__global__ __launch_bounds__(256)
void bn3_kernel(const float* g, const float* be) { bn_fused_body<7, 9>(g_y3, g_y3b, g_sred + 8192, g, be, g_m3); }
__global__ __launch_bounds__(256)
void bn4_kernel(const float* g, const float* be) { bn_fused_body<7, 12>(g_t1, g_t1b, g_sred + 12288, g, be, g_mt1); }

// ---------------------------------------------------------------------------

extern "C" void kernel_launch(void* const* d_in, const int* in_sizes, int n_in,
                              void* d_out, int out_size, void* d_ws, size_t ws_size,
                              hipStream_t stream) {
    (void)in_sizes; (void)n_in; (void)out_size; (void)d_ws; (void)ws_size;
    const float* feat = (const float*)d_in[0];
    const float* mask = (const float*)d_in[1];
    const float* w1  = (const float*)d_in[2];
    const float* b1  = (const float*)d_in[3];
    const float* g1  = (const float*)d_in[4];
    const float* be1 = (const float*)d_in[5];
    const float* w2  = (const float*)d_in[6];
    const float* b2  = (const float*)d_in[7];
    const float* g2  = (const float*)d_in[8];
    const float* be2 = (const float*)d_in[9];
    const float* w3  = (const float*)d_in[10];
    const float* b3  = (const float*)d_in[11];
    const float* g3  = (const float*)d_in[12];
    const float* be3 = (const float*)d_in[13];
    const float* tw1 = (const float*)d_in[14];
    const float* tb1 = (const float*)d_in[15];
    const float* tg1 = (const float*)d_in[16];
    const float* tbe1= (const float*)d_in[17];
    const float* tw2 = (const float*)d_in[18];
    const float* tb2 = (const float*)d_in[19];
    const float* tg2 = (const float*)d_in[20];
    const float* tbe2= (const float*)d_in[21];
    const float* fw  = (const float*)d_in[22];
    const float* fb  = (const float*)d_in[23];

    setup_kernel<<<96, 256, 0, stream>>>(w1, fw);
    prep2_kernel<<<512, 256, 0, stream>>>(w2);
    prep3_kernel<<<2048, 256, 0, stream>>>(w3);
    prep4_kernel<<<4096, 256, 0, stream>>>(tw1);
    prep5_kernel<<<2048, 256, 0, stream>>>(tw2);
    prep1x_kernel<<<2048, 256, 0, stream>>>(feat, mask);

    // block 1 (fp32): 4->32, 64^3 -> 32^3
    mask1_kernel<<<256, 256, 0, stream>>>(mask);
    conv1_kernel<<<1024, 256, 0, stream>>>(b1);
    stats1_kernel<<<2048, 256, 0, stream>>>();
    bn1_kernel<<<256, 256, 0, stream>>>(g1, be1);

    // block 2 (MFMA): 32->64, 32^3 -> 16^3, K=2048 split 8 -> 512 blocks
    mask2_kernel<<<32, 256, 0, stream>>>();
    conv2_kernel<<<dim3(64, 1, 8), 256, 0, stream>>>();
    post2_kernel<<<2048, 256, 0, stream>>>(b2);
    bn2_kernel<<<32, 256, 0, stream>>>(g2, be2);

    // block 3 (MFMA): 64->128, 16^3 -> 8^3, K=4096 split 32 -> 512 blocks
    mask3_kernel<<<4, 256, 0, stream>>>();
    conv3_kernel<<<dim3(16, 1, 32), 256, 0, stream>>>();
    post3_kernel<<<512, 256, 0, stream>>>(b3);
    bn3_kernel<<<4, 256, 0, stream>>>(g3, be3);

    // up block 1 (MFMA): 128->128, 8^3 -> 16^3, parity 8 x split 8 -> 512 blocks
    mask4_kernel<<<32, 256, 0, stream>>>();
    conv4_kernel<<<dim3(8, 1, 64), 256, 0, stream>>>();
    post4_kernel<<<2048, 256, 0, stream>>>(tb1);
    bn4_kernel<<<32, 256, 0, stream>>>(tg1, tbe1);

    // up block 2 (MFMA): 128->64, 16^3 -> 32^3, parity 8 x split 2 -> 1024 blocks
    mask5_kernel<<<256, 256, 0, stream>>>();
    conv5_kernel<<<dim3(64, 1, 16), 256, 0, stream>>>();
    post5_kernel<<<2048, 256, 0, stream>>>(tb2);

    // final dense 1x1x1 conv 64->32 @ 32^3 (fp32, fused BN finalize + apply)
    final_kernel<<<1024, 256, 0, stream>>>(fb, tg2, tbe2, (float*)d_out);
}

// Round 11
// 290.753 us; speedup vs baseline: 3.4173x; 1.1500x over previous
//
#include <hip/hip_runtime.h>
#include <hip/hip_bf16.h>

#define DEV static __device__ __forceinline__

typedef unsigned short ushort;
typedef __attribute__((ext_vector_type(8))) short short8;
typedef __attribute__((ext_vector_type(8))) ushort ushort8;
typedef __attribute__((ext_vector_type(4))) ushort ushortx4;
typedef __attribute__((ext_vector_type(4))) float accv;

DEV ushort f2bf(float f) {
    __hip_bfloat16 h = __float2bfloat16(f);   // RNE
    return reinterpret_cast<ushort&>(h);
}

// ---------------------------------------------------------------------------
// Static device workspace
// ---------------------------------------------------------------------------
__device__ float    g_sred[5 * 128 * 32];             // [l][co][32]: 0=sum 1=sumsq 2=maskcnt
__device__ float    g_y1[2097152];                    // (2,32,32^3) fp32 NCV
__device__ __align__(16) ushort g_y1b[2097152];       // (2,32^3,32) bf16 VC
__device__ float    g_m1[65536];
__device__ float    g_y2[524288];
__device__ __align__(16) ushort g_y2b[524288];        // (2,16^3,64) bf16 VC
__device__ float    g_m2[8192];
__device__ float    g_y3[131072];
__device__ __align__(16) ushort g_y3b[131072];        // (2,8^3,128) bf16 VC
__device__ float    g_m3[1024];
__device__ float    g_t1[1048576];
__device__ __align__(16) ushort g_t1b[1048576];       // (2,16^3,128) bf16 VC
__device__ float    g_mt1[8192];
__device__ float    g_mt2[65536];
__device__ float    g_t2[4194304];                    // conv5 raw out (fp32 NCV)
__device__ __align__(16) ushort g_x0b[2097152];       // (2,64^3,4) bf16 VC masked feat
// split-K partial buffers
__device__ float    g_p2[4194304];                    // 8  x 524288
__device__ float    g_p3[4194304];                    // 32 x 131072
__device__ float    g_p4[8388608];                    // 8  x 1048576
// K-major weights
__device__ __align__(16) ushort g_wb1[8192];          // [32co][256k] bf16, k=tap*4+ci
__device__ __align__(16) ushort g_wb2[131072];
__device__ __align__(16) ushort g_wb3[524288];
__device__ __align__(16) ushort g_wb4[1048576];
__device__ __align__(16) ushort g_wb5[524288];
__device__ float    g_fwt[2048];                      // [k=64][co=32] fp32

// ---------------------------------------------------------------------------
// prep_all: all launch-independent setup fused into one kernel.
// ranges: [0,96) setup | [96,608) wb2 | [608,2656) wb3 | [2656,6752) wb4
//         [6752,8800) wb5 | [8800,10848) x0b | [10848,11104) mask1
// ---------------------------------------------------------------------------
__global__ __launch_bounds__(256)
void prep_all_kernel(const float* __restrict__ w1, const float* __restrict__ fw,
                     const float* __restrict__ w2, const float* __restrict__ w3,
                     const float* __restrict__ tw1, const float* __restrict__ tw2,
                     const float* __restrict__ feat, const float* __restrict__ mask) {
    int blk = blockIdx.x, tid = threadIdx.x;
    if (blk < 96) {
        int idx = blk * 256 + tid;
        if (idx < 20480) g_sred[idx] = 0.f;
        if (idx < 8192) {
            int co = idx >> 8, r = idx & 255;
            int tap = r >> 2, ci = r & 3;
            g_wb1[idx] = f2bf(w1[co * 256 + ci * 64 + tap]);
        }
        if (idx < 2048) { int co = idx >> 6, kg = idx & 63; g_fwt[kg * 32 + co] = fw[idx]; }
    } else if (blk < 608) {
        int idx = (blk - 96) * 256 + tid;               // 64*32*64
        int co = idx / 2048, r = idx % 2048;
        int ci = r >> 6, tap = r & 63;
        g_wb2[(size_t)co * 2048 + tap * 32 + ci] = f2bf(w2[idx]);
    } else if (blk < 2656) {
        int idx = (blk - 608) * 256 + tid;              // 128*64*64
        int co = idx / 4096, r = idx % 4096;
        int ci = r >> 6, tap = r & 63;
        g_wb3[(size_t)co * 4096 + tap * 64 + ci] = f2bf(w3[idx]);
    } else if (blk < 6752) {
        int idx = (blk - 2656) * 256 + tid;             // 128*128*64
        int co = idx / 8192, r = idx % 8192;
        int ci = r >> 6, t64 = r & 63;
        int kd = t64 >> 4, kh = (t64 >> 2) & 3, kw = t64 & 3;
        int pd = (3 - kd) & 1, td = (3 - kd) >> 1;
        int ph = (3 - kh) & 1, th = (3 - kh) >> 1;
        int pw = (3 - kw) & 1, tw = (3 - kw) >> 1;
        int parity = pd * 4 + ph * 2 + pw, t = td * 4 + th * 2 + tw;
        g_wb4[(((size_t)parity * 128 + co) * 8 + t) * 128 + ci] = f2bf(tw1[idx]);
    } else if (blk < 8800) {
        int idx = (blk - 6752) * 256 + tid;             // 64*128*64
        int co = idx / 8192, r = idx % 8192;
        int ci = r >> 6, t64 = r & 63;
        int kd = t64 >> 4, kh = (t64 >> 2) & 3, kw = t64 & 3;
        int pd = (3 - kd) & 1, td = (3 - kd) >> 1;
        int ph = (3 - kh) & 1, th = (3 - kh) >> 1;
        int pw = (3 - kw) & 1, tw = (3 - kw) >> 1;
        int parity = pd * 4 + ph * 2 + pw, t = td * 4 + th * 2 + tw;
        g_wb5[(((size_t)parity * 64 + co) * 8 + t) * 128 + ci] = f2bf(tw2[idx]);
    } else if (blk < 10848) {
        int idx = (blk - 8800) * 256 + tid;             // 524288 voxels
        int b = idx >> 18, v = idx & 0x3FFFF;
        float mv = mask[idx] > 0.5f ? 1.f : 0.f;
        ushort pk[4];
#pragma unroll
        for (int c = 0; c < 4; c++) pk[c] = f2bf(feat[((b * 4 + c) << 18) + v] * mv);
        *(ushortx4*)&g_x0b[(size_t)idx * 4] = (ushortx4){pk[0], pk[1], pk[2], pk[3]};
    } else {
        int idx = (blk - 10848) * 256 + tid;            // mask1: 65536
        int b = idx >> 15, v = idx & 0x7FFF;
        int od = v >> 10, rem = v & 1023;
        int oh = rem >> 5, ow = rem & 31;
        const float* mp = mask + ((size_t)b << 18);
        float acc = 0.f;
        for (int kd = 0; kd < 4; kd++) {
            int id = 2 * od - 1 + kd;
            if ((unsigned)id >= 64u) continue;
            for (int kh = 0; kh < 4; kh++) {
                int ih = 2 * oh - 1 + kh;
                if ((unsigned)ih >= 64u) continue;
                const float* row = mp + ((size_t)id * 64 + ih) * 64;
                for (int kw = 0; kw < 4; kw++) {
                    int iw = 2 * ow - 1 + kw;
                    if ((unsigned)iw < 64u && row[iw] > 0.5f) acc += 1.f;
                }
            }
        }
        g_m1[idx] = acc > 0.f ? 1.f : 0.f;
    }
}

// ---------------------------------------------------------------------------
// mask dilation kernels (verified)
// ---------------------------------------------------------------------------
DEV void mask_down_body(const float* mprev, float* mout, int logDin, int logDo) {
    int Din = 1 << logDin, Do = 1 << logDo;
    int idx = blockIdx.x * 256 + threadIdx.x;
    int b = idx >> (3 * logDo), v = idx & ((1 << (3 * logDo)) - 1);
    int od = v >> (2 * logDo), rem = v & ((1 << (2 * logDo)) - 1);
    int oh = rem >> logDo, ow = rem & (Do - 1);
    const float* mp = mprev + ((size_t)b << (3 * logDin));
    float acc = 0.f;
    for (int kd = 0; kd < 4; kd++) {
        int id = 2 * od - 1 + kd;
        if ((unsigned)id >= (unsigned)Din) continue;
        for (int kh = 0; kh < 4; kh++) {
            int ih = 2 * oh - 1 + kh;
            if ((unsigned)ih >= (unsigned)Din) continue;
            const float* row = mp + ((size_t)id * Din + ih) * Din;
            for (int kw = 0; kw < 4; kw++) {
                int iw = 2 * ow - 1 + kw;
                if ((unsigned)iw < (unsigned)Din) acc += row[iw];
            }
        }
    }
    mout[idx] = acc > 0.f ? 1.f : 0.f;
}

DEV void mask_up_body(const float* mprev, float* mout, int logDin, int logDo) {
    int Din = 1 << logDin, Do = 1 << logDo;
    int idx = blockIdx.x * 256 + threadIdx.x;
    int b = idx >> (3 * logDo), v = idx & ((1 << (3 * logDo)) - 1);
    int od = v >> (2 * logDo), rem = v & ((1 << (2 * logDo)) - 1);
    int oh = rem >> logDo, ow = rem & (Do - 1);
    const float* mp = mprev + ((size_t)b << (3 * logDin));
    float acc = 0.f;
    for (int kd = 0; kd < 4; kd++) {
        int u = od + kd - 2; if (u < 0 || (u & 1)) continue;
        int id = u >> 1; if (id >= Din) continue;
        for (int kh = 0; kh < 4; kh++) {
            int uh = oh + kh - 2; if (uh < 0 || (uh & 1)) continue;
            int ih = uh >> 1; if (ih >= Din) continue;
            const float* row = mp + ((size_t)id * Din + ih) * Din;
            for (int kw = 0; kw < 4; kw++) {
                int uw = ow + kw - 2; if (uw < 0 || (uw & 1)) continue;
                int iw = uw >> 1; if (iw >= Din) continue;
                acc += row[iw];
            }
        }
    }
    mout[idx] = acc > 0.f ? 1.f : 0.f;
}

__global__ __launch_bounds__(256) void mask2_kernel() { mask_down_body(g_m1, g_m2, 5, 4); }
__global__ __launch_bounds__(256) void mask3_kernel() { mask_down_body(g_m2, g_m3, 4, 3); }
__global__ __launch_bounds__(256) void mask4_kernel() { mask_up_body(g_m3, g_mt1, 3, 4); }
__global__ __launch_bounds__(256) void mask5_kernel() { mask_up_body(g_mt1, g_mt2, 4, 5); }

// ---------------------------------------------------------------------------
// bf16 MFMA implicit-GEMM, register-prefetch pipelined (verified round-10)
// ---------------------------------------------------------------------------
template<int MODE, int MT, int NT, int CIN, int COUT, int LOGDI, int LOGDO, int SPLITK>
DEV void mfma_gemm_body(const ushort* __restrict__ xb, const ushort* __restrict__ wb,
                        float* __restrict__ y) {
    constexpr int KT = 32;
    constexpr int K  = (MODE == 1) ? CIN * 8 : CIN * 64;
    constexpr int KSEG = K / SPLITK;
    constexpr int LDA = 40;
    constexpr int MTW = MT / 32, NTW = NT / 32;
    constexpr int AR = MT * 4 / 256, BR = NT * 4 / 256;
    constexpr int LCIN = (CIN == 32) ? 5 : ((CIN == 64) ? 6 : 7);
    constexpr int Din = 1 << LOGDI, Do = 1 << LOGDO;
    constexpr int DvoxI = 1 << (3 * LOGDI), DvoxO = 1 << (3 * LOGDO);

    __shared__ __align__(16) ushort As[MT * LDA];
    __shared__ __align__(16) ushort Bs[NT * LDA];

    const int tid = threadIdx.x;
    const int bx = blockIdx.x;
    int pd = 0, ph = 0, pw = 0, ks = 0;
    const ushort* wp = wb;
    if constexpr (MODE == 1) {
        int z = blockIdx.z;
        pd = (z >> 2) & 1; ph = (z >> 1) & 1; pw = z & 1; ks = z >> 3;
        wp = wb + (size_t)(z & 7) * COUT * CIN * 8;
    } else {
        ks = blockIdx.z;
    }

    const int wv = tid >> 6, lane = tid & 63;
    const int mw = wv & 1, nw = wv >> 1;
    const int lr = lane & 15, quad = lane >> 4;

    auto gatherA = [&](int kt, ushort8* pa) {
#pragma unroll
        for (int r = 0; r < AR; r++) {
            int slot = r * 256 + tid;
            int m = slot >> 2, oct = slot & 3;
            pa[r] = *(const ushort8*)&wp[(size_t)m * K + kt + oct * 8];
        }
    };
    auto gatherB = [&](int kt, ushort8* pb) {
#pragma unroll
        for (int r = 0; r < BR; r++) {
            int slot = r * 256 + tid;
            int n = slot >> 2, oct = slot & 3;
            int vg = bx * NT + n;
            int kg0 = kt + oct * 8;
            int tap = kg0 >> LCIN, ci0 = kg0 & (CIN - 1);
            ushort8 v = (ushort8){0, 0, 0, 0, 0, 0, 0, 0};
            int b, id, ih, iw;
            if constexpr (MODE == 0) {
                b = vg >> (3 * LOGDO);
                int vv = vg & (DvoxO - 1);
                int od = vv >> (2 * LOGDO), oh = (vv >> LOGDO) & (Do - 1), ow = vv & (Do - 1);
                id = 2 * od - 1 + (tap >> 4);
                ih = 2 * oh - 1 + ((tap >> 2) & 3);
                iw = 2 * ow - 1 + (tap & 3);
            } else {
                b = vg >> (3 * LOGDI);
                int vv = vg & (DvoxI - 1);
                int odp = vv >> (2 * LOGDI), ohp = (vv >> LOGDI) & (Din - 1), owp = vv & (Din - 1);
                id = odp + pd + ((tap >> 2) & 1) - 1;
                ih = ohp + ph + ((tap >> 1) & 1) - 1;
                iw = owp + pw + (tap & 1) - 1;
            }
            if ((unsigned)id < (unsigned)Din && (unsigned)ih < (unsigned)Din &&
                (unsigned)iw < (unsigned)Din)
                v = *(const ushort8*)&xb[((size_t)b * DvoxI +
                                          (id << (2 * LOGDI)) + (ih << LOGDI) + iw) * CIN + ci0];
            pb[r] = v;
        }
    };

    accv acc[MTW][NTW];
#pragma unroll
    for (int mt = 0; mt < MTW; mt++)
#pragma unroll
        for (int nt = 0; nt < NTW; nt++) acc[mt][nt] = (accv){0.f, 0.f, 0.f, 0.f};

    const int kbeg = ks * KSEG, kend = kbeg + KSEG;
    ushort8 pa[AR], pb[BR], qa[AR], qb[BR];
    gatherA(kbeg, pa);
    gatherB(kbeg, pb);

    for (int kt = kbeg; kt < kend; kt += KT) {
        __syncthreads();
#pragma unroll
        for (int r = 0; r < AR; r++) {
            int slot = r * 256 + tid;
            int m = slot >> 2, oct = slot & 3;
            *(ushort8*)&As[m * LDA + oct * 8] = pa[r];
        }
#pragma unroll
        for (int r = 0; r < BR; r++) {
            int slot = r * 256 + tid;
            int n = slot >> 2, oct = slot & 3;
            *(ushort8*)&Bs[n * LDA + oct * 8] = pb[r];
        }
        __syncthreads();
        bool more = (kt + KT) < kend;
        if (more) { gatherA(kt + KT, qa); gatherB(kt + KT, qb); }

        short8 af[MTW], bfr[NTW];
#pragma unroll
        for (int mt = 0; mt < MTW; mt++)
            af[mt] = *(const short8*)&As[((mw * MTW + mt) * 16 + lr) * LDA + quad * 8];
#pragma unroll
        for (int nt = 0; nt < NTW; nt++)
            bfr[nt] = *(const short8*)&Bs[((nw * NTW + nt) * 16 + lr) * LDA + quad * 8];
#pragma unroll
        for (int mt = 0; mt < MTW; mt++)
#pragma unroll
            for (int nt = 0; nt < NTW; nt++)
                acc[mt][nt] = __builtin_amdgcn_mfma_f32_16x16x32_bf16(
                    af[mt], bfr[nt], acc[mt][nt], 0, 0, 0);
        if (more) {
#pragma unroll
            for (int r = 0; r < AR; r++) pa[r] = qa[r];
#pragma unroll
            for (int r = 0; r < BR; r++) pb[r] = qb[r];
        }
    }

    float* yp = y + (size_t)ks * (2 * COUT * DvoxO);
#pragma unroll
    for (int mt = 0; mt < MTW; mt++) {
#pragma unroll
        for (int nt = 0; nt < NTW; nt++) {
#pragma unroll
            for (int r = 0; r < 4; r++) {
                int co = (mw * MTW + mt) * 16 + quad * 4 + r;
                int vg = bx * NT + (nw * NTW + nt) * 16 + lr;
                size_t idx;
                if constexpr (MODE == 1) {
                    int b = vg >> (3 * LOGDI);
                    int vv = vg & (DvoxI - 1);
                    int odp = vv >> (2 * LOGDI), ohp = (vv >> LOGDI) & (Din - 1), owp = vv & (Din - 1);
                    int od = 2 * odp + pd, oh = 2 * ohp + ph, ow = 2 * owp + pw;
                    idx = (((size_t)(b * COUT + co)) << (3 * LOGDO)) +
                          (od << (2 * LOGDO)) + (oh << LOGDO) + ow;
                } else {
                    int b = vg >> (3 * LOGDO);
                    int off = vg & (DvoxO - 1);
                    idx = (((size_t)(b * COUT + co)) << (3 * LOGDO)) + off;
                }
                yp[idx] = acc[mt][nt][r];
            }
        }
    }
}

__global__ __launch_bounds__(256)
void conv2_kernel() { mfma_gemm_body<0, 64, 128, 32, 64, 5, 4, 8>(g_y1b, g_wb2, g_p2); }
__global__ __launch_bounds__(256)
void conv3_kernel() { mfma_gemm_body<0, 128, 64, 64, 128, 4, 3, 32>(g_y2b, g_wb3, g_p3); }
__global__ __launch_bounds__(256)
void conv4_kernel() { mfma_gemm_body<1, 128, 128, 128, 128, 3, 4, 8>(g_y3b, g_wb4, g_p4); }
__global__ __launch_bounds__(256)
void conv5_kernel() { mfma_gemm_body<1, 64, 128, 128, 64, 4, 5, 1>(g_t1b, g_wb5, g_t2); }

// ---------------------------------------------------------------------------
// conv1: bf16 MFMA. M=32 N=65536 K=256 (k=tap*4+ci), x0b VC bf16.
// 4 waves: wave w owns n-cols [w*16, w*16+16), both m-frags. grid 1024.
// One B-octet = taps (t0,t0+1) = adjacent w — single 16B load off-edge-safe.
// ---------------------------------------------------------------------------
__global__ __launch_bounds__(256)
void conv1_kernel(const float* __restrict__ bias) {
    constexpr int LDA = 40;
    __shared__ __align__(16) ushort As[32 * LDA];
    __shared__ __align__(16) ushort Bs[64 * LDA];
    const int tid = threadIdx.x, bx = blockIdx.x;
    const int wv = tid >> 6, lane = tid & 63;
    const int lr = lane & 15, quad = lane >> 4;

    const int nB = tid >> 2, octB = tid & 3;
    const int vgB = bx * 64 + nB;
    const int bB = vgB >> 15, vB = vgB & 32767;
    const int odB = vB >> 10, ohB = (vB >> 5) & 31, owB = vB & 31;

    auto gatherA = [&](int kt, ushort8& pa) {
        if (tid < 128) {
            int m = tid >> 2, oct = tid & 3;
            pa = *(const ushort8*)&g_wb1[m * 256 + kt + oct * 8];
        }
    };
    auto gatherB = [&](int kt, ushort8& pb) {
        int kg0 = kt + octB * 8;
        int t0 = kg0 >> 2;                       // even tap
        int kd = t0 >> 4, kh = (t0 >> 2) & 3, kw0 = t0 & 3;
        int id = 2 * odB - 1 + kd;
        int ih = 2 * ohB - 1 + kh;
        int iw0 = 2 * owB - 1 + kw0;
        ushort8 v = (ushort8){0, 0, 0, 0, 0, 0, 0, 0};
        if ((unsigned)id < 64u && (unsigned)ih < 64u) {
            const ushort* base = g_x0b + ((((size_t)bB << 18) + (id << 12) + (ih << 6)) << 2);
            if (iw0 >= 0 && iw0 + 1 < 64) {
                v = *(const ushort8*)&base[iw0 << 2];
            } else {
                if ((unsigned)iw0 < 64u) {
                    ushortx4 h = *(const ushortx4*)&base[iw0 << 2];
                    v[0] = h[0]; v[1] = h[1]; v[2] = h[2]; v[3] = h[3];
                }
                if ((unsigned)(iw0 + 1) < 64u) {
                    ushortx4 h = *(const ushortx4*)&base[(iw0 + 1) << 2];
                    v[4] = h[0]; v[5] = h[1]; v[6] = h[2]; v[7] = h[3];
                }
            }
        }
        pb = v;
    };

    accv acc[2];
    acc[0] = (accv){0.f, 0.f, 0.f, 0.f};
    acc[1] = (accv){0.f, 0.f, 0.f, 0.f};
    ushort8 pa, pb, qa, qb;
    gatherA(0, pa); gatherB(0, pb);

    for (int kt = 0; kt < 256; kt += 32) {
        __syncthreads();
        if (tid < 128) { int m = tid >> 2, oct = tid & 3; *(ushort8*)&As[m * LDA + oct * 8] = pa; }
        *(ushort8*)&Bs[nB * LDA + octB * 8] = pb;
        __syncthreads();
        bool more = kt < 224;
        if (more) { gatherA(kt + 32, qa); gatherB(kt + 32, qb); }

        short8 b8 = *(const short8*)&Bs[(wv * 16 + lr) * LDA + quad * 8];
#pragma unroll
        for (int mt = 0; mt < 2; mt++) {
            short8 a8 = *(const short8*)&As[(mt * 16 + lr) * LDA + quad * 8];
            acc[mt] = __builtin_amdgcn_mfma_f32_16x16x32_bf16(a8, b8, acc[mt], 0, 0, 0);
        }
        if (more) { pa = qa; pb = qb; }
    }

#pragma unroll
    for (int mt = 0; mt < 2; mt++) {
#pragma unroll
        for (int r = 0; r < 4; r++) {
            int co = mt * 16 + quad * 4 + r;
            int vg = bx * 64 + wv * 16 + lr;
            int b = vg >> 15, off = vg & 32767;
            float mv = g_m1[((size_t)b << 15) + off];
            float yv = (acc[mt][r] + bias[co]) * mv;
            yv = yv >= 0.f ? yv : 0.01f * yv;
            g_y1[(((size_t)(b * 32 + co)) << 15) + off] = yv;
        }
    }
}

// ---------------------------------------------------------------------------
// final: fp32 1x1x1, fully fused load: bias5+mask+leaky+BN. grid 1024.
// ---------------------------------------------------------------------------
__global__ __launch_bounds__(256)
void final_kernel(const float* __restrict__ fb, const float* __restrict__ b5,
                  const float* __restrict__ tg2, const float* __restrict__ tbe2,
                  float* __restrict__ out) {
    __shared__ float As[1024];
    __shared__ float Bs[2048];
    __shared__ float sc5[64], sh5[64], bb5[64];
    const int tid = threadIdx.x, tc = tid & 15, tv = tid >> 4;
    const int bx = blockIdx.x;

    if (tid < 64) {
        const float* sred = g_sred + 16384;
        float n = fmaxf(sred[tid * 32 + 2], 1.f);
        float mean = sred[tid * 32] / n;
        float var = fmaxf(sred[tid * 32 + 1] / n - mean * mean, 0.f);
        float rstd = rsqrtf(var + 1e-5f);
        float s = tg2[tid] * rstd;
        sc5[tid] = s; sh5[tid] = tbe2[tid] - mean * s; bb5[tid] = b5[tid];
    }

    float acc[2][4] = {{0.f}};
    for (int kt = 0; kt < 64; kt += 32) {
        __syncthreads();
#pragma unroll
        for (int e = 0; e < 4; e++) As[e * 256 + tid] = g_fwt[kt * 32 + e * 256 + tid];
#pragma unroll
        for (int e = 0; e < 8; e++) {
            int j = e * 256 + tid;
            int kk = j >> 6, n = j & 63;
            int kg = kt + kk;
            int vg = bx * 64 + n;
            int b = vg >> 15, v = vg & 32767;
            float raw = g_t2[(((size_t)(b * 64 + kg)) << 15) + v];
            float mv = g_mt2[((size_t)b << 15) + v];
            float t = (raw + bb5[kg]) * mv;
            t = t >= 0.f ? t : 0.01f * t;
            Bs[kk * 64 + n] = (t * sc5[kg] + sh5[kg]) * mv;
        }
        __syncthreads();
#pragma unroll
        for (int kk = 0; kk < 32; kk++) {
            float2 a2 = *(const float2*)&As[kk * 32 + tc * 2];
            float4 b4 = *(const float4*)&Bs[kk * 64 + tv * 4];
            float a[2] = {a2.x, a2.y};
            float bb[4] = {b4.x, b4.y, b4.z, b4.w};
#pragma unroll
            for (int r = 0; r < 2; r++)
#pragma unroll
                for (int c = 0; c < 4; c++) acc[r][c] = fmaf(a[r], bb[c], acc[r][c]);
        }
    }
#pragma unroll
    for (int r = 0; r < 2; r++) {
        int co = tc * 2 + r;
        float bv = fb[co];
#pragma unroll
        for (int c = 0; c < 4; c++) {
            int vg = bx * 64 + tv * 4 + c;
            int b = vg >> 15, v = vg & 32767;
            out[(((size_t)(b * 32 + co)) << 15) + v] = acc[r][c] + bv;
        }
    }
}

// ---------------------------------------------------------------------------
DEV void red3_and_atomic(float s, float s2, float sm, float* sred, int co) {
#pragma unroll
    for (int off = 32; off; off >>= 1) {
        s  += __shfl_down(s, off, 64);
        s2 += __shfl_down(s2, off, 64);
        sm += __shfl_down(sm, off, 64);
    }
    __shared__ float red[12];
    int lane = threadIdx.x & 63, wvi = threadIdx.x >> 6;
    if (!lane) { red[wvi] = s; red[4 + wvi] = s2; red[8 + wvi] = sm; }
    __syncthreads();
    if (!threadIdx.x) {
        atomicAdd(&sred[co * 32 + 0], red[0] + red[1] + red[2] + red[3]);
        atomicAdd(&sred[co * 32 + 1], red[4] + red[5] + red[6] + red[7]);
        atomicAdd(&sred[co * 32 + 2], red[8] + red[9] + red[10] + red[11]);
    }
}

// ---------------------------------------------------------------------------
// post: sum SPLITK partials + bias + mask + LeakyReLU + stats (WRITE optional)
// ---------------------------------------------------------------------------
template<int COUT, int LOGDO, int SPLITK, int ITERS, bool WRITE>
DEV void post_body(const float* __restrict__ bias, const float* __restrict__ m2,
                   const float* p, float* y, float* sred) {
    constexpr int Dvox = 1 << (3 * LOGDO);
    constexpr size_t STR = (size_t)2 * COUT * Dvox;
    constexpr int LOGC = (COUT == 128) ? 7 : ((COUT == 64) ? 6 : 5);
    int base = blockIdx.x * (ITERS * 256);
    int co = (base >> (3 * LOGDO)) & (COUT - 1);
    float s = 0.f, s2 = 0.f, sm = 0.f;
#pragma unroll
    for (int it = 0; it < ITERS; it++) {
        int idx = base + it * 256 + threadIdx.x;
        int v = idx & (Dvox - 1);
        int b = idx >> (3 * LOGDO + LOGC);
        float sum = 0.f;
#pragma unroll
        for (int k = 0; k < SPLITK; k++) sum += p[k * STR + idx];
        float mv = m2[((size_t)b << (3 * LOGDO)) + v];
        float yv = (sum + bias[co]) * mv;
        yv = yv >= 0.f ? yv : 0.01f * yv;
        if constexpr (WRITE) y[idx] = yv;
        s += yv; s2 += yv * yv; sm += mv;
    }
    red3_and_atomic(s, s2, sm, sred, co);
}

__global__ __launch_bounds__(256) void post2_kernel(const float* b) { post_body<64, 4, 8, 1, true>(b, g_m2, g_p2, g_y2, g_sred + 4096); }
__global__ __launch_bounds__(256) void post3_kernel(const float* b) { post_body<128, 3, 32, 1, true>(b, g_m3, g_p3, g_y3, g_sred + 8192); }
__global__ __launch_bounds__(256) void post4_kernel(const float* b) { post_body<128, 4, 8, 2, true>(b, g_mt1, g_p4, g_t1, g_sred + 12288); }
__global__ __launch_bounds__(256) void post5_kernel(const float* b) { post_body<64, 5, 1, 8, false>(b, g_mt2, g_t2, g_t2, g_sred + 16384); }

// stats pass over y1. grid 2048.
__global__ __launch_bounds__(256)
void stats1_kernel() {
    int base = blockIdx.x * 1024;
    int co = (base >> 15) & 31;
    float s = 0.f, s2 = 0.f, sm = 0.f;
#pragma unroll
    for (int it = 0; it < 4; it++) {
        int idx = base + it * 256 + threadIdx.x;
        int v = idx & 32767;
        int b = idx >> 20;
        float yv = g_y1[idx];
        float mv = g_m1[((size_t)b << 15) + v];
        s += yv; s2 += yv * yv; sm += mv;
    }
    red3_and_atomic(s, s2, sm, g_sred, co);
}

// ---------------------------------------------------------------------------
// bn fused with finalize (verified round-9)
// ---------------------------------------------------------------------------
template<int LOGC, int LOGD>
DEV void bn_fused_body(const float* __restrict__ y, ushort* __restrict__ out,
                       const float* __restrict__ sred, const float* __restrict__ gm,
                       const float* __restrict__ be, const float* __restrict__ m2) {
    constexpr int C = 1 << LOGC, Dvox = 1 << LOGD;
    __shared__ float sc[C], sh[C];
    int tid = threadIdx.x;
    if (tid < C) {
        float n = fmaxf(sred[tid * 32 + 2], 1.f);
        float mean = sred[tid * 32] / n;
        float var = fmaxf(sred[tid * 32 + 1] / n - mean * mean, 0.f);
        float rstd = rsqrtf(var + 1e-5f);
        float s = gm[tid] * rstd;
        sc[tid] = s; sh[tid] = be[tid] - mean * s;
    }
    __syncthreads();
    int gv = blockIdx.x * 256 + tid;
    int b = gv >> LOGD, vox = gv & (Dvox - 1);
    float mv = m2[gv];
    const float* yp = y + (((size_t)b << LOGC) << LOGD) + vox;
    ushort* op = out + (size_t)gv * C;
#pragma unroll
    for (int c0 = 0; c0 < C; c0 += 8) {
        ushort pk[8];
#pragma unroll
        for (int j = 0; j < 8; j++) {
            int c = c0 + j;
            float val = yp[(size_t)c << LOGD];
            pk[j] = f2bf((val * sc[c] + sh[c]) * mv);
        }
        *(ushort8*)&op[c0] = (ushort8){pk[0], pk[1], pk[2], pk[3], pk[4], pk[5], pk[6], pk[7]};
    }
}

__global__ __launch_bounds__(256)
void bn1_kernel(const float* g, const float* be) { bn_fused_body<5, 15>(g_y1, g_y1b, g_sred + 0, g, be, g_m1); }
__global__ __launch_bounds__(256)
void bn2_kernel(const float* g, const float* be) { bn_fused_body<6, 12>(g_y2, g_y2b, g_sred + 4096, g, be, g_m2); }
__global__ __launch_bounds__(256)
void bn3_kernel(const float* g, const float* be) { bn_fused_body<7, 9>(g_y3, g_y3b, g_sred + 8192, g, be, g_m3); }
__global__ __launch_bounds__(256)
void bn4_kernel(const float* g, const float* be) { bn_fused_body<7, 12>(g_t1, g_t1b, g_sred + 12288, g, be, g_mt1); }

// ---------------------------------------------------------------------------

extern "C" void kernel_launch(void* const* d_in, const int* in_sizes, int n_in,
                              void* d_out, int out_size, void* d_ws, size_t ws_size,
                              hipStream_t stream) {
    (void)in_sizes; (void)n_in; (void)out_size; (void)d_ws; (void)ws_size;
    const float* feat = (const float*)d_in[0];
    const float* mask = (const float*)d_in[1];
    const float* w1  = (const float*)d_in[2];
    const float* b1  = (const float*)d_in[3];
    const float* g1  = (const float*)d_in[4];
    const float* be1 = (const float*)d_in[5];
    const float* w2  = (const float*)d_in[6];
    const float* b2  = (const float*)d_in[7];
    const float* g2  = (const float*)d_in[8];
    const float* be2 = (const float*)d_in[9];
    const float* w3  = (const float*)d_in[10];
    const float* b3  = (const float*)d_in[11];
    const float* g3  = (const float*)d_in[12];
    const float* be3 = (const float*)d_in[13];
    const float* tw1 = (const float*)d_in[14];
    const float* tb1 = (const float*)d_in[15];
    const float* tg1 = (const float*)d_in[16];
    const float* tbe1= (const float*)d_in[17];
    const float* tw2 = (const float*)d_in[18];
    const float* tb2 = (const float*)d_in[19];
    const float* tg2 = (const float*)d_in[20];
    const float* tbe2= (const float*)d_in[21];
    const float* fw  = (const float*)d_in[22];
    const float* fb  = (const float*)d_in[23];

    // all setup + weight transposes + x0b + mask1 in one kernel
    prep_all_kernel<<<11104, 256, 0, stream>>>(w1, fw, w2, w3, tw1, tw2, feat, mask);

    // block 1 (bf16 MFMA): 4->32, 64^3 -> 32^3
    conv1_kernel<<<1024, 256, 0, stream>>>(b1);
    stats1_kernel<<<2048, 256, 0, stream>>>();
    bn1_kernel<<<256, 256, 0, stream>>>(g1, be1);

    // block 2 (MFMA): 32->64, 32^3 -> 16^3, K=2048 split 8
    mask2_kernel<<<32, 256, 0, stream>>>();
    conv2_kernel<<<dim3(64, 1, 8), 256, 0, stream>>>();
    post2_kernel<<<2048, 256, 0, stream>>>(b2);
    bn2_kernel<<<32, 256, 0, stream>>>(g2, be2);

    // block 3 (MFMA): 64->128, 16^3 -> 8^3, K=4096 split 32
    mask3_kernel<<<4, 256, 0, stream>>>();
    conv3_kernel<<<dim3(16, 1, 32), 256, 0, stream>>>();
    post3_kernel<<<512, 256, 0, stream>>>(b3);
    bn3_kernel<<<4, 256, 0, stream>>>(g3, be3);

    // up block 1 (MFMA): 128->128, 8^3 -> 16^3, parity 8 x split 8
    mask4_kernel<<<32, 256, 0, stream>>>();
    conv4_kernel<<<dim3(8, 1, 64), 256, 0, stream>>>();
    post4_kernel<<<2048, 256, 0, stream>>>(tb1);
    bn4_kernel<<<32, 256, 0, stream>>>(tg1, tbe1);

    // up block 2 (MFMA): 128->64, 16^3 -> 32^3, parity 8, direct store
    mask5_kernel<<<256, 256, 0, stream>>>();
    conv5_kernel<<<dim3(64, 1, 8), 256, 0, stream>>>();
    post5_kernel<<<2048, 256, 0, stream>>>(tb2);         // stats only

    // final dense 1x1x1 conv 64->32 @ 32^3 (bias5+mask+leaky+BN fused on load)
    final_kernel<<<1024, 256, 0, stream>>>(fb, tb2, tg2, tbe2, (float*)d_out);
}

// Round 12
// 279.802 us; speedup vs baseline: 3.5511x; 1.0391x over previous
//
#include <hip/hip_runtime.h>
#include <hip/hip_bf16.h>

#define DEV static __device__ __forceinline__

typedef unsigned short ushort;
typedef __attribute__((ext_vector_type(8))) short short8;
typedef __attribute__((ext_vector_type(8))) ushort ushort8;
typedef __attribute__((ext_vector_type(4))) ushort ushortx4;
typedef __attribute__((ext_vector_type(4))) float accv;

DEV ushort f2bf(float f) {
    __hip_bfloat16 h = __float2bfloat16(f);   // RNE
    return reinterpret_cast<ushort&>(h);
}

// ---------------------------------------------------------------------------
// Static device workspace
// ---------------------------------------------------------------------------
__device__ float    g_sred[5 * 128 * 32];             // [l][co][32]: 0=sum 1=sumsq 2=maskcnt
__device__ float    g_y1[2097152];                    // (2,32,32^3) fp32 NCV
__device__ __align__(16) ushort g_y1b[2097152];       // (2,32^3,32) bf16 VC
__device__ float    g_m1[65536];
__device__ float    g_y2[524288];
__device__ __align__(16) ushort g_y2b[524288];        // (2,16^3,64) bf16 VC
__device__ float    g_m2[8192];
__device__ float    g_y3[131072];
__device__ __align__(16) ushort g_y3b[131072];        // (2,8^3,128) bf16 VC
__device__ float    g_m3[1024];
__device__ float    g_t1[1048576];
__device__ __align__(16) ushort g_t1b[1048576];       // (2,16^3,128) bf16 VC
__device__ float    g_mt1[8192];
__device__ float    g_mt2[65536];
__device__ float    g_t2[4194304];                    // conv5 raw out (fp32 NCV)
__device__ __align__(16) ushort g_x0b[2097152];       // (2,64^3,4) bf16 VC masked feat
// split-K partial buffers
__device__ float    g_p2[4194304];                    // 8  x 524288
__device__ float    g_p3[4194304];                    // 32 x 131072
__device__ float    g_p4[8388608];                    // 8  x 1048576
// K-major weights
__device__ __align__(16) ushort g_wb1[8192];          // [32co][256k] bf16, k=tap*4+ci
__device__ __align__(16) ushort g_wb2[131072];
__device__ __align__(16) ushort g_wb3[524288];
__device__ __align__(16) ushort g_wb4[1048576];
__device__ __align__(16) ushort g_wb5[524288];
__device__ float    g_fwt[2048];                      // [k=64][co=32] fp32

// ---------------------------------------------------------------------------
// prep_all (verified round-11)
// ---------------------------------------------------------------------------
__global__ __launch_bounds__(256)
void prep_all_kernel(const float* __restrict__ w1, const float* __restrict__ fw,
                     const float* __restrict__ w2, const float* __restrict__ w3,
                     const float* __restrict__ tw1, const float* __restrict__ tw2,
                     const float* __restrict__ feat, const float* __restrict__ mask) {
    int blk = blockIdx.x, tid = threadIdx.x;
    if (blk < 96) {
        int idx = blk * 256 + tid;
        if (idx < 20480) g_sred[idx] = 0.f;
        if (idx < 8192) {
            int co = idx >> 8, r = idx & 255;
            int tap = r >> 2, ci = r & 3;
            g_wb1[idx] = f2bf(w1[co * 256 + ci * 64 + tap]);
        }
        if (idx < 2048) { int co = idx >> 6, kg = idx & 63; g_fwt[kg * 32 + co] = fw[idx]; }
    } else if (blk < 608) {
        int idx = (blk - 96) * 256 + tid;
        int co = idx / 2048, r = idx % 2048;
        int ci = r >> 6, tap = r & 63;
        g_wb2[(size_t)co * 2048 + tap * 32 + ci] = f2bf(w2[idx]);
    } else if (blk < 2656) {
        int idx = (blk - 608) * 256 + tid;
        int co = idx / 4096, r = idx % 4096;
        int ci = r >> 6, tap = r & 63;
        g_wb3[(size_t)co * 4096 + tap * 64 + ci] = f2bf(w3[idx]);
    } else if (blk < 6752) {
        int idx = (blk - 2656) * 256 + tid;
        int co = idx / 8192, r = idx % 8192;
        int ci = r >> 6, t64 = r & 63;
        int kd = t64 >> 4, kh = (t64 >> 2) & 3, kw = t64 & 3;
        int pd = (3 - kd) & 1, td = (3 - kd) >> 1;
        int ph = (3 - kh) & 1, th = (3 - kh) >> 1;
        int pw = (3 - kw) & 1, tw = (3 - kw) >> 1;
        int parity = pd * 4 + ph * 2 + pw, t = td * 4 + th * 2 + tw;
        g_wb4[(((size_t)parity * 128 + co) * 8 + t) * 128 + ci] = f2bf(tw1[idx]);
    } else if (blk < 8800) {
        int idx = (blk - 6752) * 256 + tid;
        int co = idx / 8192, r = idx % 8192;
        int ci = r >> 6, t64 = r & 63;
        int kd = t64 >> 4, kh = (t64 >> 2) & 3, kw = t64 & 3;
        int pd = (3 - kd) & 1, td = (3 - kd) >> 1;
        int ph = (3 - kh) & 1, th = (3 - kh) >> 1;
        int pw = (3 - kw) & 1, tw = (3 - kw) >> 1;
        int parity = pd * 4 + ph * 2 + pw, t = td * 4 + th * 2 + tw;
        g_wb5[(((size_t)parity * 64 + co) * 8 + t) * 128 + ci] = f2bf(tw2[idx]);
    } else if (blk < 10848) {
        int idx = (blk - 8800) * 256 + tid;
        int b = idx >> 18, v = idx & 0x3FFFF;
        float mv = mask[idx] > 0.5f ? 1.f : 0.f;
        ushort pk[4];
#pragma unroll
        for (int c = 0; c < 4; c++) pk[c] = f2bf(feat[((b * 4 + c) << 18) + v] * mv);
        *(ushortx4*)&g_x0b[(size_t)idx * 4] = (ushortx4){pk[0], pk[1], pk[2], pk[3]};
    } else {
        int idx = (blk - 10848) * 256 + tid;            // mask1: 65536
        int b = idx >> 15, v = idx & 0x7FFF;
        int od = v >> 10, rem = v & 1023;
        int oh = rem >> 5, ow = rem & 31;
        const float* mp = mask + ((size_t)b << 18);
        float acc = 0.f;
        for (int kd = 0; kd < 4; kd++) {
            int id = 2 * od - 1 + kd;
            if ((unsigned)id >= 64u) continue;
            for (int kh = 0; kh < 4; kh++) {
                int ih = 2 * oh - 1 + kh;
                if ((unsigned)ih >= 64u) continue;
                const float* row = mp + ((size_t)id * 64 + ih) * 64;
                for (int kw = 0; kw < 4; kw++) {
                    int iw = 2 * ow - 1 + kw;
                    if ((unsigned)iw < 64u && row[iw] > 0.5f) acc += 1.f;
                }
            }
        }
        g_m1[idx] = acc > 0.f ? 1.f : 0.f;
    }
}

// ---------------------------------------------------------------------------
// mask dilation bodies with explicit block index (for fusion into bn kernels)
// ---------------------------------------------------------------------------
DEV void mask_down_blk(const float* mprev, float* mout, int logDin, int logDo, int blk) {
    int Din = 1 << logDin, Do = 1 << logDo;
    int idx = blk * 256 + threadIdx.x;
    int b = idx >> (3 * logDo), v = idx & ((1 << (3 * logDo)) - 1);
    int od = v >> (2 * logDo), rem = v & ((1 << (2 * logDo)) - 1);
    int oh = rem >> logDo, ow = rem & (Do - 1);
    const float* mp = mprev + ((size_t)b << (3 * logDin));
    float acc = 0.f;
    for (int kd = 0; kd < 4; kd++) {
        int id = 2 * od - 1 + kd;
        if ((unsigned)id >= (unsigned)Din) continue;
        for (int kh = 0; kh < 4; kh++) {
            int ih = 2 * oh - 1 + kh;
            if ((unsigned)ih >= (unsigned)Din) continue;
            const float* row = mp + ((size_t)id * Din + ih) * Din;
            for (int kw = 0; kw < 4; kw++) {
                int iw = 2 * ow - 1 + kw;
                if ((unsigned)iw < (unsigned)Din) acc += row[iw];
            }
        }
    }
    mout[idx] = acc > 0.f ? 1.f : 0.f;
}

DEV void mask_up_blk(const float* mprev, float* mout, int logDin, int logDo, int blk) {
    int Din = 1 << logDin, Do = 1 << logDo;
    int idx = blk * 256 + threadIdx.x;
    int b = idx >> (3 * logDo), v = idx & ((1 << (3 * logDo)) - 1);
    int od = v >> (2 * logDo), rem = v & ((1 << (2 * logDo)) - 1);
    int oh = rem >> logDo, ow = rem & (Do - 1);
    const float* mp = mprev + ((size_t)b << (3 * logDin));
    float acc = 0.f;
    for (int kd = 0; kd < 4; kd++) {
        int u = od + kd - 2; if (u < 0 || (u & 1)) continue;
        int id = u >> 1; if (id >= Din) continue;
        for (int kh = 0; kh < 4; kh++) {
            int uh = oh + kh - 2; if (uh < 0 || (uh & 1)) continue;
            int ih = uh >> 1; if (ih >= Din) continue;
            const float* row = mp + ((size_t)id * Din + ih) * Din;
            for (int kw = 0; kw < 4; kw++) {
                int uw = ow + kw - 2; if (uw < 0 || (uw & 1)) continue;
                int iw = uw >> 1; if (iw >= Din) continue;
                acc += row[iw];
            }
        }
    }
    mout[idx] = acc > 0.f ? 1.f : 0.f;
}

// ---------------------------------------------------------------------------
// bf16 MFMA implicit-GEMM, register-prefetch pipelined.
// K = tap*CIN + ci, KT=32 <= CIN  =>  tap is UNIFORM per K-tile (tap = kt>>LCIN)
// and the voxel decode is loop-invariant — hoisted out of the hot loop.
// ---------------------------------------------------------------------------
template<int MODE, int MT, int NT, int CIN, int COUT, int LOGDI, int LOGDO, int SPLITK>
DEV void mfma_gemm_body(const ushort* __restrict__ xb, const ushort* __restrict__ wb,
                        float* __restrict__ y) {
    constexpr int KT = 32;
    constexpr int K  = (MODE == 1) ? CIN * 8 : CIN * 64;
    constexpr int KSEG = K / SPLITK;
    constexpr int LDA = 40;
    constexpr int MTW = MT / 32, NTW = NT / 32;
    constexpr int AR = MT * 4 / 256, BR = NT * 4 / 256;
    constexpr int LCIN = (CIN == 32) ? 5 : ((CIN == 64) ? 6 : 7);
    constexpr int Din = 1 << LOGDI, Do = 1 << LOGDO;
    constexpr int DvoxI = 1 << (3 * LOGDI), DvoxO = 1 << (3 * LOGDO);

    __shared__ __align__(16) ushort As[MT * LDA];
    __shared__ __align__(16) ushort Bs[NT * LDA];

    const int tid = threadIdx.x;
    const int bx = blockIdx.x;
    int pd = 0, ph = 0, pw = 0, ks = 0;
    const ushort* wp = wb;
    if constexpr (MODE == 1) {
        int z = blockIdx.z;
        pd = (z >> 2) & 1; ph = (z >> 1) & 1; pw = z & 1; ks = z >> 3;
        wp = wb + (size_t)(z & 7) * COUT * CIN * 8;
    } else {
        ks = blockIdx.z;
    }

    const int wv = tid >> 6, lane = tid & 63;
    const int mw = wv & 1, nw = wv >> 1;
    const int lr = lane & 15, quad = lane >> 4;

    // ---- hoisted per-slot B voxel decode (loop-invariant)
    int rB[BR], dB[BR], hB[BR], wBv[BR];
#pragma unroll
    for (int r = 0; r < BR; r++) {
        int slot = r * 256 + tid;
        int n = slot >> 2;
        int vg = bx * NT + n;
        if constexpr (MODE == 0) {
            rB[r] = vg >> (3 * LOGDO);
            int vv = vg & (DvoxO - 1);
            dB[r] = 2 * (vv >> (2 * LOGDO)) - 1;
            hB[r] = 2 * ((vv >> LOGDO) & (Do - 1)) - 1;
            wBv[r] = 2 * (vv & (Do - 1)) - 1;
        } else {
            rB[r] = vg >> (3 * LOGDI);
            int vv = vg & (DvoxI - 1);
            dB[r] = (vv >> (2 * LOGDI)) + pd - 1;
            hB[r] = ((vv >> LOGDI) & (Din - 1)) + ph - 1;
            wBv[r] = (vv & (Din - 1)) + pw - 1;
        }
    }

    auto gatherA = [&](int kt, ushort8* pa) {
#pragma unroll
        for (int r = 0; r < AR; r++) {
            int slot = r * 256 + tid;
            int m = slot >> 2, oct = slot & 3;
            pa[r] = *(const ushort8*)&wp[(size_t)m * K + kt + oct * 8];
        }
    };
    auto gatherB = [&](int kt, ushort8* pb) {
        int tap = kt >> LCIN;                 // uniform per tile
        int cib = kt & (CIN - 1);
        int id_d, ih_d, iw_d;
        if constexpr (MODE == 0) { id_d = tap >> 4; ih_d = (tap >> 2) & 3; iw_d = tap & 3; }
        else                     { id_d = (tap >> 2) & 1; ih_d = (tap >> 1) & 1; iw_d = tap & 1; }
#pragma unroll
        for (int r = 0; r < BR; r++) {
            int oct = (r * 256 + tid) & 3;
            int ci0 = cib + oct * 8;
            int id = dB[r] + id_d, ih = hB[r] + ih_d, iw = wBv[r] + iw_d;
            ushort8 v = (ushort8){0, 0, 0, 0, 0, 0, 0, 0};
            if ((unsigned)id < (unsigned)Din && (unsigned)ih < (unsigned)Din &&
                (unsigned)iw < (unsigned)Din)
                v = *(const ushort8*)&xb[((size_t)rB[r] * DvoxI +
                                          (id << (2 * LOGDI)) + (ih << LOGDI) + iw) * CIN + ci0];
            pb[r] = v;
        }
    };

    accv acc[MTW][NTW];
#pragma unroll
    for (int mt = 0; mt < MTW; mt++)
#pragma unroll
        for (int nt = 0; nt < NTW; nt++) acc[mt][nt] = (accv){0.f, 0.f, 0.f, 0.f};

    const int kbeg = ks * KSEG, kend = kbeg + KSEG;
    ushort8 pa[AR], pb[BR], qa[AR], qb[BR];
    gatherA(kbeg, pa);
    gatherB(kbeg, pb);

    for (int kt = kbeg; kt < kend; kt += KT) {
        __syncthreads();
#pragma unroll
        for (int r = 0; r < AR; r++) {
            int slot = r * 256 + tid;
            int m = slot >> 2, oct = slot & 3;
            *(ushort8*)&As[m * LDA + oct * 8] = pa[r];
        }
#pragma unroll
        for (int r = 0; r < BR; r++) {
            int slot = r * 256 + tid;
            int n = slot >> 2, oct = slot & 3;
            *(ushort8*)&Bs[n * LDA + oct * 8] = pb[r];
        }
        __syncthreads();
        bool more = (kt + KT) < kend;
        if (more) { gatherA(kt + KT, qa); gatherB(kt + KT, qb); }

        short8 af[MTW], bfr[NTW];
#pragma unroll
        for (int mt = 0; mt < MTW; mt++)
            af[mt] = *(const short8*)&As[((mw * MTW + mt) * 16 + lr) * LDA + quad * 8];
#pragma unroll
        for (int nt = 0; nt < NTW; nt++)
            bfr[nt] = *(const short8*)&Bs[((nw * NTW + nt) * 16 + lr) * LDA + quad * 8];
#pragma unroll
        for (int mt = 0; mt < MTW; mt++)
#pragma unroll
            for (int nt = 0; nt < NTW; nt++)
                acc[mt][nt] = __builtin_amdgcn_mfma_f32_16x16x32_bf16(
                    af[mt], bfr[nt], acc[mt][nt], 0, 0, 0);
        if (more) {
#pragma unroll
            for (int r = 0; r < AR; r++) pa[r] = qa[r];
#pragma unroll
            for (int r = 0; r < BR; r++) pb[r] = qb[r];
        }
    }

    float* yp = y + (size_t)ks * (2 * COUT * DvoxO);
#pragma unroll
    for (int mt = 0; mt < MTW; mt++) {
#pragma unroll
        for (int nt = 0; nt < NTW; nt++) {
#pragma unroll
            for (int r = 0; r < 4; r++) {
                int co = (mw * MTW + mt) * 16 + quad * 4 + r;
                int vg = bx * NT + (nw * NTW + nt) * 16 + lr;
                size_t idx;
                if constexpr (MODE == 1) {
                    int b = vg >> (3 * LOGDI);
                    int vv = vg & (DvoxI - 1);
                    int odp = vv >> (2 * LOGDI), ohp = (vv >> LOGDI) & (Din - 1), owp = vv & (Din - 1);
                    int od = 2 * odp + pd, oh = 2 * ohp + ph, ow = 2 * owp + pw;
                    idx = (((size_t)(b * COUT + co)) << (3 * LOGDO)) +
                          (od << (2 * LOGDO)) + (oh << LOGDO) + ow;
                } else {
                    int b = vg >> (3 * LOGDO);
                    int off = vg & (DvoxO - 1);
                    idx = (((size_t)(b * COUT + co)) << (3 * LOGDO)) + off;
                }
                yp[idx] = acc[mt][nt][r];
            }
        }
    }
}

__global__ __launch_bounds__(256)
void conv2_kernel() { mfma_gemm_body<0, 64, 128, 32, 64, 5, 4, 8>(g_y1b, g_wb2, g_p2); }
__global__ __launch_bounds__(256)
void conv3_kernel() { mfma_gemm_body<0, 128, 64, 64, 128, 4, 3, 32>(g_y2b, g_wb3, g_p3); }
__global__ __launch_bounds__(256)
void conv4_kernel() { mfma_gemm_body<1, 128, 128, 128, 128, 3, 4, 8>(g_y3b, g_wb4, g_p4); }
__global__ __launch_bounds__(256)
void conv5_kernel() { mfma_gemm_body<1, 64, 128, 128, 64, 4, 5, 1>(g_t1b, g_wb5, g_t2); }

// ---------------------------------------------------------------------------
// conv1: bf16 MFMA (verified round-11)
// ---------------------------------------------------------------------------
__global__ __launch_bounds__(256)
void conv1_kernel(const float* __restrict__ bias) {
    constexpr int LDA = 40;
    __shared__ __align__(16) ushort As[32 * LDA];
    __shared__ __align__(16) ushort Bs[64 * LDA];
    const int tid = threadIdx.x, bx = blockIdx.x;
    const int wv = tid >> 6, lane = tid & 63;
    const int lr = lane & 15, quad = lane >> 4;

    const int nB = tid >> 2, octB = tid & 3;
    const int vgB = bx * 64 + nB;
    const int bB = vgB >> 15, vB = vgB & 32767;
    const int odB = vB >> 10, ohB = (vB >> 5) & 31, owB = vB & 31;

    auto gatherA = [&](int kt, ushort8& pa) {
        if (tid < 128) {
            int m = tid >> 2, oct = tid & 3;
            pa = *(const ushort8*)&g_wb1[m * 256 + kt + oct * 8];
        }
    };
    auto gatherB = [&](int kt, ushort8& pb) {
        int kg0 = kt + octB * 8;
        int t0 = kg0 >> 2;
        int kd = t0 >> 4, kh = (t0 >> 2) & 3, kw0 = t0 & 3;
        int id = 2 * odB - 1 + kd;
        int ih = 2 * ohB - 1 + kh;
        int iw0 = 2 * owB - 1 + kw0;
        ushort8 v = (ushort8){0, 0, 0, 0, 0, 0, 0, 0};
        if ((unsigned)id < 64u && (unsigned)ih < 64u) {
            const ushort* base = g_x0b + ((((size_t)bB << 18) + (id << 12) + (ih << 6)) << 2);
            if (iw0 >= 0 && iw0 + 1 < 64) {
                v = *(const ushort8*)&base[iw0 << 2];
            } else {
                if ((unsigned)iw0 < 64u) {
                    ushortx4 h = *(const ushortx4*)&base[iw0 << 2];
                    v[0] = h[0]; v[1] = h[1]; v[2] = h[2]; v[3] = h[3];
                }
                if ((unsigned)(iw0 + 1) < 64u) {
                    ushortx4 h = *(const ushortx4*)&base[(iw0 + 1) << 2];
                    v[4] = h[0]; v[5] = h[1]; v[6] = h[2]; v[7] = h[3];
                }
            }
        }
        pb = v;
    };

    accv acc[2];
    acc[0] = (accv){0.f, 0.f, 0.f, 0.f};
    acc[1] = (accv){0.f, 0.f, 0.f, 0.f};
    ushort8 pa, pb, qa, qb;
    gatherA(0, pa); gatherB(0, pb);

    for (int kt = 0; kt < 256; kt += 32) {
        __syncthreads();
        if (tid < 128) { int m = tid >> 2, oct = tid & 3; *(ushort8*)&As[m * LDA + oct * 8] = pa; }
        *(ushort8*)&Bs[nB * LDA + octB * 8] = pb;
        __syncthreads();
        bool more = kt < 224;
        if (more) { gatherA(kt + 32, qa); gatherB(kt + 32, qb); }

        short8 b8 = *(const short8*)&Bs[(wv * 16 + lr) * LDA + quad * 8];
#pragma unroll
        for (int mt = 0; mt < 2; mt++) {
            short8 a8 = *(const short8*)&As[(mt * 16 + lr) * LDA + quad * 8];
            acc[mt] = __builtin_amdgcn_mfma_f32_16x16x32_bf16(a8, b8, acc[mt], 0, 0, 0);
        }
        if (more) { pa = qa; pb = qb; }
    }

#pragma unroll
    for (int mt = 0; mt < 2; mt++) {
#pragma unroll
        for (int r = 0; r < 4; r++) {
            int co = mt * 16 + quad * 4 + r;
            int vg = bx * 64 + wv * 16 + lr;
            int b = vg >> 15, off = vg & 32767;
            float mv = g_m1[((size_t)b << 15) + off];
            float yv = (acc[mt][r] + bias[co]) * mv;
            yv = yv >= 0.f ? yv : 0.01f * yv;
            g_y1[(((size_t)(b * 32 + co)) << 15) + off] = yv;
        }
    }
}

// ---------------------------------------------------------------------------
// final: fp32 1x1x1, fully fused load: bias5+mask+leaky+BN. grid 1024.
// ---------------------------------------------------------------------------
__global__ __launch_bounds__(256)
void final_kernel(const float* __restrict__ fb, const float* __restrict__ b5,
                  const float* __restrict__ tg2, const float* __restrict__ tbe2,
                  float* __restrict__ out) {
    __shared__ float As[1024];
    __shared__ float Bs[2048];
    __shared__ float sc5[64], sh5[64], bb5[64];
    const int tid = threadIdx.x, tc = tid & 15, tv = tid >> 4;
    const int bx = blockIdx.x;

    if (tid < 64) {
        const float* sred = g_sred + 16384;
        float n = fmaxf(sred[tid * 32 + 2], 1.f);
        float mean = sred[tid * 32] / n;
        float var = fmaxf(sred[tid * 32 + 1] / n - mean * mean, 0.f);
        float rstd = rsqrtf(var + 1e-5f);
        float s = tg2[tid] * rstd;
        sc5[tid] = s; sh5[tid] = tbe2[tid] - mean * s; bb5[tid] = b5[tid];
    }

    float acc[2][4] = {{0.f}};
    for (int kt = 0; kt < 64; kt += 32) {
        __syncthreads();
#pragma unroll
        for (int e = 0; e < 4; e++) As[e * 256 + tid] = g_fwt[kt * 32 + e * 256 + tid];
#pragma unroll
        for (int e = 0; e < 8; e++) {
            int j = e * 256 + tid;
            int kk = j >> 6, n = j & 63;
            int kg = kt + kk;
            int vg = bx * 64 + n;
            int b = vg >> 15, v = vg & 32767;
            float raw = g_t2[(((size_t)(b * 64 + kg)) << 15) + v];
            float mv = g_mt2[((size_t)b << 15) + v];
            float t = (raw + bb5[kg]) * mv;
            t = t >= 0.f ? t : 0.01f * t;
            Bs[kk * 64 + n] = (t * sc5[kg] + sh5[kg]) * mv;
        }
        __syncthreads();
#pragma unroll
        for (int kk = 0; kk < 32; kk++) {
            float2 a2 = *(const float2*)&As[kk * 32 + tc * 2];
            float4 b4 = *(const float4*)&Bs[kk * 64 + tv * 4];
            float a[2] = {a2.x, a2.y};
            float bb[4] = {b4.x, b4.y, b4.z, b4.w};
#pragma unroll
            for (int r = 0; r < 2; r++)
#pragma unroll
                for (int c = 0; c < 4; c++) acc[r][c] = fmaf(a[r], bb[c], acc[r][c]);
        }
    }
#pragma unroll
    for (int r = 0; r < 2; r++) {
        int co = tc * 2 + r;
        float bv = fb[co];
#pragma unroll
        for (int c = 0; c < 4; c++) {
            int vg = bx * 64 + tv * 4 + c;
            int b = vg >> 15, v = vg & 32767;
            out[(((size_t)(b * 32 + co)) << 15) + v] = acc[r][c] + bv;
        }
    }
}

// ---------------------------------------------------------------------------
DEV void red3_and_atomic(float s, float s2, float sm, float* sred, int co) {
#pragma unroll
    for (int off = 32; off; off >>= 1) {
        s  += __shfl_down(s, off, 64);
        s2 += __shfl_down(s2, off, 64);
        sm += __shfl_down(sm, off, 64);
    }
    __shared__ float red[12];
    int lane = threadIdx.x & 63, wvi = threadIdx.x >> 6;
    if (!lane) { red[wvi] = s; red[4 + wvi] = s2; red[8 + wvi] = sm; }
    __syncthreads();
    if (!threadIdx.x) {
        atomicAdd(&sred[co * 32 + 0], red[0] + red[1] + red[2] + red[3]);
        atomicAdd(&sred[co * 32 + 1], red[4] + red[5] + red[6] + red[7]);
        atomicAdd(&sred[co * 32 + 2], red[8] + red[9] + red[10] + red[11]);
    }
}

// ---------------------------------------------------------------------------
// post: sum SPLITK partials + bias + mask + LeakyReLU + stats (WRITE optional)
// ---------------------------------------------------------------------------
template<int COUT, int LOGDO, int SPLITK, int ITERS, bool WRITE>
DEV void post_body(const float* __restrict__ bias, const float* __restrict__ m2,
                   const float* p, float* y, float* sred) {
    constexpr int Dvox = 1 << (3 * LOGDO);
    constexpr size_t STR = (size_t)2 * COUT * Dvox;
    constexpr int LOGC = (COUT == 128) ? 7 : ((COUT == 64) ? 6 : 5);
    int base = blockIdx.x * (ITERS * 256);
    int co = (base >> (3 * LOGDO)) & (COUT - 1);
    float s = 0.f, s2 = 0.f, sm = 0.f;
#pragma unroll
    for (int it = 0; it < ITERS; it++) {
        int idx = base + it * 256 + threadIdx.x;
        int v = idx & (Dvox - 1);
        int b = idx >> (3 * LOGDO + LOGC);
        float sum = 0.f;
#pragma unroll
        for (int k = 0; k < SPLITK; k++) sum += p[k * STR + idx];
        float mv = m2[((size_t)b << (3 * LOGDO)) + v];
        float yv = (sum + bias[co]) * mv;
        yv = yv >= 0.f ? yv : 0.01f * yv;
        if constexpr (WRITE) y[idx] = yv;
        s += yv; s2 += yv * yv; sm += mv;
    }
    red3_and_atomic(s, s2, sm, sred, co);
}

__global__ __launch_bounds__(256) void post2_kernel(const float* b) { post_body<64, 4, 8, 1, true>(b, g_m2, g_p2, g_y2, g_sred + 4096); }
__global__ __launch_bounds__(256) void post3_kernel(const float* b) { post_body<128, 3, 32, 1, true>(b, g_m3, g_p3, g_y3, g_sred + 8192); }
__global__ __launch_bounds__(256) void post4_kernel(const float* b) { post_body<128, 4, 8, 2, true>(b, g_mt1, g_p4, g_t1, g_sred + 12288); }
__global__ __launch_bounds__(256) void post5_kernel(const float* b) { post_body<64, 5, 1, 8, false>(b, g_mt2, g_t2, g_t2, g_sred + 16384); }

// stats pass over y1. grid 2048.
__global__ __launch_bounds__(256)
void stats1_kernel() {
    int base = blockIdx.x * 1024;
    int co = (base >> 15) & 31;
    float s = 0.f, s2 = 0.f, sm = 0.f;
#pragma unroll
    for (int it = 0; it < 4; it++) {
        int idx = base + it * 256 + threadIdx.x;
        int v = idx & 32767;
        int b = idx >> 20;
        float yv = g_y1[idx];
        float mv = g_m1[((size_t)b << 15) + v];
        s += yv; s2 += yv * yv; sm += mv;
    }
    red3_and_atomic(s, s2, sm, g_sred, co);
}

// ---------------------------------------------------------------------------
// bn fused with finalize, explicit block index
// ---------------------------------------------------------------------------
template<int LOGC, int LOGD>
DEV void bn_fused_body(const float* __restrict__ y, ushort* __restrict__ out,
                       const float* __restrict__ sred, const float* __restrict__ gm,
                       const float* __restrict__ be, const float* __restrict__ m2,
                       int blk) {
    constexpr int C = 1 << LOGC, Dvox = 1 << LOGD;
    __shared__ float sc[C], sh[C];
    int tid = threadIdx.x;
    if (tid < C) {
        float n = fmaxf(sred[tid * 32 + 2], 1.f);
        float mean = sred[tid * 32] / n;
        float var = fmaxf(sred[tid * 32 + 1] / n - mean * mean, 0.f);
        float rstd = rsqrtf(var + 1e-5f);
        float s = gm[tid] * rstd;
        sc[tid] = s; sh[tid] = be[tid] - mean * s;
    }
    __syncthreads();
    int gv = blk * 256 + tid;
    int b = gv >> LOGD, vox = gv & (Dvox - 1);
    float mv = m2[gv];
    const float* yp = y + (((size_t)b << LOGC) << LOGD) + vox;
    ushort* op = out + (size_t)gv * C;
#pragma unroll
    for (int c0 = 0; c0 < C; c0 += 8) {
        ushort pk[8];
#pragma unroll
        for (int j = 0; j < 8; j++) {
            int c = c0 + j;
            float val = yp[(size_t)c << LOGD];
            pk[j] = f2bf((val * sc[c] + sh[c]) * mv);
        }
        *(ushort8*)&op[c0] = (ushort8){pk[0], pk[1], pk[2], pk[3], pk[4], pk[5], pk[6], pk[7]};
    }
}

// bn kernels with fused next-mask blocks
__global__ __launch_bounds__(256)
void bn1_kernel(const float* g, const float* be) {          // grid 288
    if (blockIdx.x < 256) bn_fused_body<5, 15>(g_y1, g_y1b, g_sred + 0, g, be, g_m1, blockIdx.x);
    else mask_down_blk(g_m1, g_m2, 5, 4, blockIdx.x - 256); // mask2: 32 blocks
}
__global__ __launch_bounds__(256)
void bn2_kernel(const float* g, const float* be) {          // grid 36
    if (blockIdx.x < 32) bn_fused_body<6, 12>(g_y2, g_y2b, g_sred + 4096, g, be, g_m2, blockIdx.x);
    else mask_down_blk(g_m2, g_m3, 4, 3, blockIdx.x - 32);  // mask3: 4 blocks
}
__global__ __launch_bounds__(256)
void bn3_kernel(const float* g, const float* be) {          // grid 36
    if (blockIdx.x < 4) bn_fused_body<7, 9>(g_y3, g_y3b, g_sred + 8192, g, be, g_m3, blockIdx.x);
    else mask_up_blk(g_m3, g_mt1, 3, 4, blockIdx.x - 4);    // mask4: 32 blocks
}
__global__ __launch_bounds__(256)
void bn4_kernel(const float* g, const float* be) {          // grid 288
    if (blockIdx.x < 32) bn_fused_body<7, 12>(g_t1, g_t1b, g_sred + 12288, g, be, g_mt1, blockIdx.x);
    else mask_up_blk(g_mt1, g_mt2, 4, 5, blockIdx.x - 32);  // mask5: 256 blocks
}

// ---------------------------------------------------------------------------

extern "C" void kernel_launch(void* const* d_in, const int* in_sizes, int n_in,
                              void* d_out, int out_size, void* d_ws, size_t ws_size,
                              hipStream_t stream) {
    (void)in_sizes; (void)n_in; (void)out_size; (void)d_ws; (void)ws_size;
    const float* feat = (const float*)d_in[0];
    const float* mask = (const float*)d_in[1];
    const float* w1  = (const float*)d_in[2];
    const float* b1  = (const float*)d_in[3];
    const float* g1  = (const float*)d_in[4];
    const float* be1 = (const float*)d_in[5];
    const float* w2  = (const float*)d_in[6];
    const float* b2  = (const float*)d_in[7];
    const float* g2  = (const float*)d_in[8];
    const float* be2 = (const float*)d_in[9];
    const float* w3  = (const float*)d_in[10];
    const float* b3  = (const float*)d_in[11];
    const float* g3  = (const float*)d_in[12];
    const float* be3 = (const float*)d_in[13];
    const float* tw1 = (const float*)d_in[14];
    const float* tb1 = (const float*)d_in[15];
    const float* tg1 = (const float*)d_in[16];
    const float* tbe1= (const float*)d_in[17];
    const float* tw2 = (const float*)d_in[18];
    const float* tb2 = (const float*)d_in[19];
    const float* tg2 = (const float*)d_in[20];
    const float* tbe2= (const float*)d_in[21];
    const float* fw  = (const float*)d_in[22];
    const float* fb  = (const float*)d_in[23];

    prep_all_kernel<<<11104, 256, 0, stream>>>(w1, fw, w2, w3, tw1, tw2, feat, mask);

    // block 1 (bf16 MFMA): 4->32, 64^3 -> 32^3
    conv1_kernel<<<1024, 256, 0, stream>>>(b1);
    stats1_kernel<<<2048, 256, 0, stream>>>();
    bn1_kernel<<<288, 256, 0, stream>>>(g1, be1);          // + mask2

    // block 2 (MFMA): 32->64, 32^3 -> 16^3, K=2048 split 8
    conv2_kernel<<<dim3(64, 1, 8), 256, 0, stream>>>();
    post2_kernel<<<2048, 256, 0, stream>>>(b2);
    bn2_kernel<<<36, 256, 0, stream>>>(g2, be2);           // + mask3

    // block 3 (MFMA): 64->128, 16^3 -> 8^3, K=4096 split 32
    conv3_kernel<<<dim3(16, 1, 32), 256, 0, stream>>>();
    post3_kernel<<<512, 256, 0, stream>>>(b3);
    bn3_kernel<<<36, 256, 0, stream>>>(g3, be3);           // + mask4

    // up block 1 (MFMA): 128->128, 8^3 -> 16^3, parity 8 x split 8
    conv4_kernel<<<dim3(8, 1, 64), 256, 0, stream>>>();
    post4_kernel<<<2048, 256, 0, stream>>>(tb1);
    bn4_kernel<<<288, 256, 0, stream>>>(tg1, tbe1);        // + mask5

    // up block 2 (MFMA): 128->64, 16^3 -> 32^3, parity 8, direct store
    conv5_kernel<<<dim3(64, 1, 8), 256, 0, stream>>>();
    post5_kernel<<<2048, 256, 0, stream>>>(tb2);           // stats only

    // final dense 1x1x1 conv 64->32 @ 32^3 (bias5+mask+leaky+BN fused on load)
    final_kernel<<<1024, 256, 0, stream>>>(fb, tb2, tg2, tbe2, (float*)d_out);
}